// Round 2
// baseline (7076.579 us; speedup 1.0000x reference)
//
#include <hip/hip_runtime.h>
#include <cstdint>

#define CDIV(a,b) (((a)+(b)-1)/(b))

// ---------------------------------------------------------------------------
// Multi-head self-attention + mean over L, one wave (64 threads) per sequence.
// Lane j owns output column j throughout. x rows are wave-uniform -> scalar
// loads; weight columns live in VGPRs; q/k staged in LDS (stride 72 to break
// bank conflicts); (o@Wo+bo).mean(l) folded to (mean_l o)@Wo+bo.
// MODE 0: outp[seq*64+j] = result. MODE 1: atomicAdd(outp[sidx[seq]*128+64+j]).
// ---------------------------------------------------------------------------
template<int L, int MODE>
__global__ __launch_bounds__(64) void attn_kernel(
    const float* __restrict__ we, const int* __restrict__ words,
    const float* __restrict__ Wq, const float* __restrict__ bq,
    const float* __restrict__ Wk, const float* __restrict__ bk,
    const float* __restrict__ Wv, const float* __restrict__ bv,
    const float* __restrict__ Wo, const float* __restrict__ bo,
    int N, float* __restrict__ outp, const int* __restrict__ sidx)
{
    constexpr int ST = 72;  // LDS row stride in floats: 16B-aligned, 2-way banks
    __shared__ __align__(16) float q_lds[16*ST];
    __shared__ __align__(16) float k_lds[16*ST];
    __shared__ __align__(16) float p_lds[16*ST];
    __shared__ __align__(16) float mo_lds[64];

    const int seq = blockIdx.x;
    if (seq >= N) return;
    const int j = threadIdx.x;  // 0..63, output column

    // word indices for this sequence (wave-uniform -> SGPRs)
    int wid[L];
    {
        const int* wrow = words + (size_t)seq * L;
        #pragma unroll
        for (int l = 0; l < L; ++l) wid[l] = wrow[l];
    }

    // q,k,v columns j: acc[l] = bias[j] + sum_d x[l][d] * W[d][j]
    float accq[L], acck[L], accv[L];
    {
        const float bqj = bq[j], bkj = bk[j], bvj = bv[j];
        #pragma unroll
        for (int l = 0; l < L; ++l) { accq[l]=bqj; acck[l]=bkj; accv[l]=bvj; }
    }
    for (int d0 = 0; d0 < 64; d0 += 4) {
        float wq[4], wk[4], wv[4];
        #pragma unroll
        for (int i = 0; i < 4; ++i) {
            wq[i] = Wq[(d0+i)*64 + j];
            wk[i] = Wk[(d0+i)*64 + j];
            wv[i] = Wv[(d0+i)*64 + j];
        }
        #pragma unroll
        for (int l = 0; l < L; ++l) {
            float x0=0.f, x1=0.f, x2=0.f, x3=0.f;
            if (wid[l] != 0) {  // padding_idx=0 -> zero row (uniform branch)
                const float* xr = we + (size_t)wid[l]*64 + d0;
                x0 = xr[0]; x1 = xr[1]; x2 = xr[2]; x3 = xr[3];
            }
            accq[l] += x0*wq[0] + x1*wq[1] + x2*wq[2] + x3*wq[3];
            acck[l] += x0*wk[0] + x1*wk[1] + x2*wk[2] + x3*wk[3];
            accv[l] += x0*wv[0] + x1*wv[1] + x2*wv[2] + x3*wv[3];
        }
    }

    #pragma unroll
    for (int l = 0; l < L; ++l) { q_lds[l*ST + j] = accq[l]; k_lds[l*ST + j] = acck[l]; }
    __syncthreads();

    // scores + softmax: lane (h = j>>4, l = j&15) owns one (h,l) score row
    const int h = j >> 4, lr = j & 15;
    const int l = (lr < L) ? lr : 0;  // clamp for padded lanes (results unused)
    float qr[16];
    #pragma unroll
    for (int dg = 0; dg < 4; ++dg) {
        const float4 t = *(const float4*)&q_lds[l*ST + h*16 + dg*4];
        qr[dg*4+0]=t.x; qr[dg*4+1]=t.y; qr[dg*4+2]=t.z; qr[dg*4+3]=t.w;
    }
    float p[L];
    float mx = -1e30f;
    #pragma unroll
    for (int m = 0; m < L; ++m) {
        float s = 0.f;
        #pragma unroll
        for (int dg = 0; dg < 4; ++dg) {
            const float4 t = *(const float4*)&k_lds[m*ST + h*16 + dg*4];
            s += qr[dg*4+0]*t.x + qr[dg*4+1]*t.y + qr[dg*4+2]*t.z + qr[dg*4+3]*t.w;
        }
        p[m] = s * 0.25f;               // / sqrt(DH=16)
        mx = fmaxf(mx, p[m]);
    }
    float sum = 0.f;
    #pragma unroll
    for (int m = 0; m < L; ++m) { p[m] = expf(p[m] - mx); sum += p[m]; }
    const float rs = 1.0f / sum;
    #pragma unroll
    for (int m = 0; m < L; ++m) p_lds[lr*ST + h*16 + m] = p[m] * rs;
    __syncthreads();

    // o[l][j] = sum_m a[h][l][m] * v[m][j]; fold mean over l
    float macc = 0.f;
    #pragma unroll
    for (int ll = 0; ll < L; ++ll) {
        float o = 0.f;
        #pragma unroll
        for (int m = 0; m < L; ++m) o += p_lds[ll*ST + h*16 + m] * accv[m];
        macc += o;
    }
    mo_lds[j] = macc * (1.0f / (float)L);
    __syncthreads();

    // out[j] = bo[j] + sum_n mean_o[n] * Wo[n][j]
    float res = bo[j];
    #pragma unroll 8
    for (int n = 0; n < 64; ++n) res += mo_lds[n] * Wo[n*64 + j];

    if (MODE == 0) {
        outp[(size_t)seq*64 + j] = res;
    } else {
        atomicAdd(&outp[(size_t)sidx[seq]*128 + 64 + j], res);
    }
}

// ---------------------------------------------------------------------------
// e[v][0:64] = entity_emb[v]; e[v][64:128] = 0  (32 threads x float4 per row)
// ---------------------------------------------------------------------------
__global__ __launch_bounds__(256) void init_e_kernel(
    float* __restrict__ e, const float* __restrict__ entity_emb, int NE)
{
    const int t = blockIdx.x*256 + threadIdx.x;
    const int v = t >> 5;
    if (v >= NE) return;
    const int c = (t & 31) * 4;
    float4 val;
    if (c < 64) val = *(const float4*)&entity_emb[(size_t)v*64 + c];
    else        val = make_float4(0.f, 0.f, 0.f, 0.f);
    *(float4*)&e[(size_t)v*128 + c] = val;
}

__global__ __launch_bounds__(256) void count_profile_kernel(
    const int* __restrict__ dst, unsigned* __restrict__ deg, int NR)
{
    const int t = blockIdx.x*256 + threadIdx.x;
    if (t < NR) atomicAdd(&deg[dst[t]], 1u);
}

__global__ __launch_bounds__(256) void count_deg_kernel(
    const int* __restrict__ src, const int* __restrict__ dst,
    unsigned* __restrict__ deg, int EP)
{
    const int t = blockIdx.x*256 + threadIdx.x;
    if (t < EP) { atomicAdd(&deg[src[t]], 1u); atomicAdd(&deg[dst[t]], 1u); }
}

// prof /= max(deg_p,1); inv = 1/sqrt(max(deg_i,1))
__global__ __launch_bounds__(256) void finalize_kernel(
    float* __restrict__ e, float* __restrict__ inv,
    const unsigned* __restrict__ deg_p, const unsigned* __restrict__ deg_i, int NE)
{
    const int t = blockIdx.x*256 + threadIdx.x;
    const int v = t >> 5;
    if (v >= NE) return;
    const int c = (t & 31) * 4;
    const size_t o = (size_t)v*128 + c;
    if (c >= 64) {
        float4 ev = *(const float4*)&e[o];
        const unsigned dp = deg_p[v];
        const float r = 1.0f / (float)(dp > 1u ? dp : 1u);
        ev.x *= r; ev.y *= r; ev.z *= r; ev.w *= r;
        *(float4*)&e[o] = ev;
    }
    if (c == 0) {
        const unsigned di = deg_i[v];
        inv[v] = 1.0f / sqrtf((float)(di > 1u ? di : 1u));
    }
}

// acc[r] += e[sel[r]] for the 3*B scoring rows (users|items|negs)
__global__ __launch_bounds__(256) void gather_acc_kernel(
    const float* __restrict__ e, const int* __restrict__ users,
    const int* __restrict__ items, const int* __restrict__ negs,
    float* __restrict__ acc, int B)
{
    const int t = blockIdx.x*256 + threadIdx.x;
    const int r = t >> 5;
    if (r >= 3*B) return;
    const int c = (t & 31) * 4;
    const int which = r / B, b = r - which*B;
    const int idx = (which == 0) ? users[b] : (which == 1) ? items[b] : negs[b];
    const float4 ev = *(const float4*)&e[(size_t)idx*128 + c];
    float4 a = *(const float4*)&acc[(size_t)r*128 + c];
    a.x += ev.x; a.y += ev.y; a.z += ev.z; a.w += ev.w;
    *(float4*)&acc[(size_t)r*128 + c] = a;
}

// nxt[dst] += e[src] + [0|q_h[qid]]*inv[src];  nxt[src] += e[dst]*inv[dst]
// 32 threads per edge, float4 per thread.
__global__ __launch_bounds__(256) void edge_kernel(
    const float* __restrict__ e, const float* __restrict__ q_h,
    const float* __restrict__ inv, const int* __restrict__ src,
    const int* __restrict__ dst, const int* __restrict__ qid,
    float* __restrict__ nxt, int EP)
{
    const int t = blockIdx.x*256 + threadIdx.x;
    const int edge = t >> 5;
    if (edge >= EP) return;
    const int c = (t & 31) * 4;
    const int s = src[edge], d = dst[edge];
    const float invs = inv[s];
    const float4 es = *(const float4*)&e[(size_t)s*128 + c];
    const float4 ed = *(const float4*)&e[(size_t)d*128 + c];
    float ax = es.x, ay = es.y, az = es.z, aw = es.w;
    if (c >= 64) {
        const int q = qid[edge];
        const float4 qh = *(const float4*)&q_h[(size_t)q*64 + (c - 64)];
        ax += qh.x*invs; ay += qh.y*invs; az += qh.z*invs; aw += qh.w*invs;
    }
    float* nd = &nxt[(size_t)d*128 + c];
    atomicAdd(nd+0, ax); atomicAdd(nd+1, ay); atomicAdd(nd+2, az); atomicAdd(nd+3, aw);
    const float invd = inv[d];
    float* ns = &nxt[(size_t)s*128 + c];
    atomicAdd(ns+0, ed.x*invd); atomicAdd(ns+1, ed.y*invd);
    atomicAdd(ns+2, ed.z*invd); atomicAdd(ns+3, ed.w*invd);
}

// e = nxt*inv; nxt = 0 (ready for next iteration)
__global__ __launch_bounds__(256) void combine_kernel(
    float* __restrict__ e, float* __restrict__ nxt,
    const float* __restrict__ inv, int NE)
{
    const int t = blockIdx.x*256 + threadIdx.x;
    const int v = t >> 5;
    if (v >= NE) return;
    const int c = (t & 31) * 4;
    const float iv = inv[v];
    const size_t o = (size_t)v*128 + c;
    const float4 nx = *(const float4*)&nxt[o];
    float4 en; en.x = nx.x*iv; en.y = nx.y*iv; en.z = nx.z*iv; en.w = nx.w*iv;
    *(float4*)&e[o] = en;
    *(float4*)&nxt[o] = make_float4(0.f, 0.f, 0.f, 0.f);
}

// BPR loss: one block (128 threads) per batch element.
// acc holds 4*efin at rows [users | items | negs].
__global__ __launch_bounds__(128) void loss_kernel(
    const float* __restrict__ acc, const float* __restrict__ qb,
    float* __restrict__ out, int B, float invB)
{
    const int b = blockIdx.x, d = threadIdx.x;
    const float u = acc[(size_t)b*128 + d] * 0.25f;
    const float p = u + (d >= 64 ? qb[(size_t)b*64 + (d - 64)] : 0.f);
    const float ei = acc[(size_t)(B + b)*128 + d];
    const float en = acc[(size_t)(2*B + b)*128 + d];
    float x = p * (ei - en) * 0.25f;
    #pragma unroll
    for (int off = 1; off < 64; off <<= 1) x += __shfl_xor(x, off, 64);
    __shared__ float wred[2];
    if ((threadIdx.x & 63) == 0) wred[threadIdx.x >> 6] = x;
    __syncthreads();
    if (threadIdx.x == 0) {
        const float xx = wred[0] + wred[1];
        const float ls = fminf(xx, 0.f) - log1pf(expf(-fabsf(xx)));  // log_sigmoid
        atomicAdd(out, -ls * invB);
    }
}

extern "C" void kernel_launch(void* const* d_in, const int* in_sizes, int n_in,
                              void* d_out, int out_size, void* d_ws, size_t ws_size,
                              hipStream_t stream)
{
    const float* word_emb        = (const float*)d_in[0];
    const float* entity_emb      = (const float*)d_in[1];
    const float* Wq = (const float*)d_in[2];  const float* bq = (const float*)d_in[3];
    const float* Wk = (const float*)d_in[4];  const float* bk = (const float*)d_in[5];
    const float* Wv = (const float*)d_in[6];  const float* bv = (const float*)d_in[7];
    const float* Wo = (const float*)d_in[8];  const float* bo = (const float*)d_in[9];
    const int* review_words      = (const int*)d_in[10];
    const int* query_words_graph = (const int*)d_in[11];
    const int* profile_dst       = (const int*)d_in[12];
    const int* pur_src           = (const int*)d_in[13];
    const int* pur_dst           = (const int*)d_in[14];
    const int* pur_qid           = (const int*)d_in[15];
    const int* users             = (const int*)d_in[16];
    const int* items             = (const int*)d_in[17];
    const int* negs              = (const int*)d_in[18];
    const int* query_words       = (const int*)d_in[19];

    const int NE = in_sizes[1]  / 64;
    const int NR = in_sizes[10] / 16;
    const int NQ = in_sizes[11] / 8;
    const int EP = in_sizes[13];
    const int B  = in_sizes[16];

    char* ws = (char*)d_ws;
    size_t off = 0;
    auto alloc = [&](size_t bytes) -> char* {
        char* q = ws + off; off += (bytes + 255) & ~(size_t)255; return q;
    };
    float*    e     = (float*)   alloc((size_t)NE*128*4);
    float*    nxt   = (float*)   alloc((size_t)NE*128*4);
    float*    q_h   = (float*)   alloc((size_t)NQ*64*4);
    float*    qb    = (float*)   alloc((size_t)B*64*4);
    float*    acc   = (float*)   alloc((size_t)3*B*128*4);
    unsigned* deg_p = (unsigned*)alloc((size_t)NE*4);
    unsigned* deg_i = (unsigned*)alloc((size_t)NE*4);
    float*    inv   = (float*)   alloc((size_t)NE*4);

    // If the workspace can't hold even the reduced footprint, bail out
    // (clean absmax failure instead of a GPU memory-fault abort).
    if (off > ws_size) return;

    hipMemsetAsync(deg_p, 0, (size_t)NE*4, stream);
    hipMemsetAsync(deg_i, 0, (size_t)NE*4, stream);
    hipMemsetAsync(nxt,   0, (size_t)NE*128*4, stream);
    hipMemsetAsync(acc,   0, (size_t)3*B*128*4, stream);
    hipMemsetAsync(d_out, 0, (size_t)out_size*4, stream);

    init_e_kernel<<<CDIV(NE*32, 256), 256, 0, stream>>>(e, entity_emb, NE);
    count_profile_kernel<<<CDIV(NR, 256), 256, 0, stream>>>(profile_dst, deg_p, NR);
    count_deg_kernel<<<CDIV(EP, 256), 256, 0, stream>>>(pur_src, pur_dst, deg_i, EP);

    // review attention, scatter into e[:,64:128]
    attn_kernel<16,1><<<NR, 64, 0, stream>>>(word_emb, review_words,
        Wq,bq,Wk,bk,Wv,bv,Wo,bo, NR, e, profile_dst);
    // graph-query attention -> q_h
    attn_kernel<8,0><<<NQ, 64, 0, stream>>>(word_emb, query_words_graph,
        Wq,bq,Wk,bk,Wv,bv,Wo,bo, NQ, q_h, nullptr);
    // batch-query attention -> qb
    attn_kernel<8,0><<<B, 64, 0, stream>>>(word_emb, query_words,
        Wq,bq,Wk,bk,Wv,bv,Wo,bo, B, qb, nullptr);

    finalize_kernel<<<CDIV(NE*32, 256), 256, 0, stream>>>(e, inv, deg_p, deg_i, NE);
    gather_acc_kernel<<<CDIV(3*B*32, 256), 256, 0, stream>>>(e, users, items, negs, acc, B);

    for (int k = 0; k < 3; ++k) {
        edge_kernel<<<CDIV(EP*32, 256), 256, 0, stream>>>(e, q_h, inv,
            pur_src, pur_dst, pur_qid, nxt, EP);
        combine_kernel<<<CDIV(NE*32, 256), 256, 0, stream>>>(e, nxt, inv, NE);
        gather_acc_kernel<<<CDIV(3*B*32, 256), 256, 0, stream>>>(e, users, items, negs, acc, B);
    }

    loss_kernel<<<B, 128, 0, stream>>>(acc, qb, (float*)d_out, B, 1.0f / (float)B);
}

// Round 3
// 3170.997 us; speedup vs baseline: 2.2317x; 2.2317x over previous
//
#include <hip/hip_runtime.h>
#include <cstdint>

#define CDIV(a,b) (((a)+(b)-1)/(b))

// ---------------------------------------------------------------------------
// Multi-head self-attention + mean over L, one wave (64 threads) per sequence.
// Lane j owns output column j throughout. x rows are wave-uniform -> scalar
// loads; weight columns live in VGPRs; q/k staged in LDS (stride 72 to break
// bank conflicts); (o@Wo+bo).mean(l) folded to (mean_l o)@Wo+bo.
// MODE 0: outp[seq*64+j] = result. MODE 1: atomicAdd(outp[sidx[seq]*128+64+j]).
// ---------------------------------------------------------------------------
template<int L, int MODE>
__global__ __launch_bounds__(64) void attn_kernel(
    const float* __restrict__ we, const int* __restrict__ words,
    const float* __restrict__ Wq, const float* __restrict__ bq,
    const float* __restrict__ Wk, const float* __restrict__ bk,
    const float* __restrict__ Wv, const float* __restrict__ bv,
    const float* __restrict__ Wo, const float* __restrict__ bo,
    int N, float* __restrict__ outp, const int* __restrict__ sidx)
{
    constexpr int ST = 72;  // LDS row stride in floats: 16B-aligned, 2-way banks
    __shared__ __align__(16) float q_lds[16*ST];
    __shared__ __align__(16) float k_lds[16*ST];
    __shared__ __align__(16) float p_lds[16*ST];
    __shared__ __align__(16) float mo_lds[64];

    const int seq = blockIdx.x;
    if (seq >= N) return;
    const int j = threadIdx.x;  // 0..63, output column

    // word indices for this sequence (wave-uniform -> SGPRs)
    int wid[L];
    {
        const int* wrow = words + (size_t)seq * L;
        #pragma unroll
        for (int l = 0; l < L; ++l) wid[l] = wrow[l];
    }

    // q,k,v columns j: acc[l] = bias[j] + sum_d x[l][d] * W[d][j]
    float accq[L], acck[L], accv[L];
    {
        const float bqj = bq[j], bkj = bk[j], bvj = bv[j];
        #pragma unroll
        for (int l = 0; l < L; ++l) { accq[l]=bqj; acck[l]=bkj; accv[l]=bvj; }
    }
    for (int d0 = 0; d0 < 64; d0 += 4) {
        float wq[4], wk[4], wv[4];
        #pragma unroll
        for (int i = 0; i < 4; ++i) {
            wq[i] = Wq[(d0+i)*64 + j];
            wk[i] = Wk[(d0+i)*64 + j];
            wv[i] = Wv[(d0+i)*64 + j];
        }
        #pragma unroll
        for (int l = 0; l < L; ++l) {
            float x0=0.f, x1=0.f, x2=0.f, x3=0.f;
            if (wid[l] != 0) {  // padding_idx=0 -> zero row (uniform branch)
                const float* xr = we + (size_t)wid[l]*64 + d0;
                x0 = xr[0]; x1 = xr[1]; x2 = xr[2]; x3 = xr[3];
            }
            accq[l] += x0*wq[0] + x1*wq[1] + x2*wq[2] + x3*wq[3];
            acck[l] += x0*wk[0] + x1*wk[1] + x2*wk[2] + x3*wk[3];
            accv[l] += x0*wv[0] + x1*wv[1] + x2*wv[2] + x3*wv[3];
        }
    }

    #pragma unroll
    for (int l = 0; l < L; ++l) { q_lds[l*ST + j] = accq[l]; k_lds[l*ST + j] = acck[l]; }
    __syncthreads();

    // scores + softmax: lane (h = j>>4, l = j&15) owns one (h,l) score row
    const int h = j >> 4, lr = j & 15;
    const int l = (lr < L) ? lr : 0;  // clamp for padded lanes (results unused)
    float qr[16];
    #pragma unroll
    for (int dg = 0; dg < 4; ++dg) {
        const float4 t = *(const float4*)&q_lds[l*ST + h*16 + dg*4];
        qr[dg*4+0]=t.x; qr[dg*4+1]=t.y; qr[dg*4+2]=t.z; qr[dg*4+3]=t.w;
    }
    float p[L];
    float mx = -1e30f;
    #pragma unroll
    for (int m = 0; m < L; ++m) {
        float s = 0.f;
        #pragma unroll
        for (int dg = 0; dg < 4; ++dg) {
            const float4 t = *(const float4*)&k_lds[m*ST + h*16 + dg*4];
            s += qr[dg*4+0]*t.x + qr[dg*4+1]*t.y + qr[dg*4+2]*t.z + qr[dg*4+3]*t.w;
        }
        p[m] = s * 0.25f;               // / sqrt(DH=16)
        mx = fmaxf(mx, p[m]);
    }
    float sum = 0.f;
    #pragma unroll
    for (int m = 0; m < L; ++m) { p[m] = expf(p[m] - mx); sum += p[m]; }
    const float rs = 1.0f / sum;
    #pragma unroll
    for (int m = 0; m < L; ++m) p_lds[lr*ST + h*16 + m] = p[m] * rs;
    __syncthreads();

    // o[l][j] = sum_m a[h][l][m] * v[m][j]; fold mean over l
    float macc = 0.f;
    #pragma unroll
    for (int ll = 0; ll < L; ++ll) {
        float o = 0.f;
        #pragma unroll
        for (int m = 0; m < L; ++m) o += p_lds[ll*ST + h*16 + m] * accv[m];
        macc += o;
    }
    mo_lds[j] = macc * (1.0f / (float)L);
    __syncthreads();

    // out[j] = bo[j] + sum_n mean_o[n] * Wo[n][j]
    float res = bo[j];
    #pragma unroll 8
    for (int n = 0; n < 64; ++n) res += mo_lds[n] * Wo[n*64 + j];

    if (MODE == 0) {
        outp[(size_t)seq*64 + j] = res;
    } else {
        atomicAdd(&outp[(size_t)sidx[seq]*128 + 64 + j], res);
    }
}

// ---------------------------------------------------------------------------
// e[v][0:64] = entity_emb[v]; e[v][64:128] = 0  (32 threads x float4 per row)
// ---------------------------------------------------------------------------
__global__ __launch_bounds__(256) void init_e_kernel(
    float* __restrict__ e, const float* __restrict__ entity_emb, int NE)
{
    const int t = blockIdx.x*256 + threadIdx.x;
    const int v = t >> 5;
    if (v >= NE) return;
    const int c = (t & 31) * 4;
    float4 val;
    if (c < 64) val = *(const float4*)&entity_emb[(size_t)v*64 + c];
    else        val = make_float4(0.f, 0.f, 0.f, 0.f);
    *(float4*)&e[(size_t)v*128 + c] = val;
}

__global__ __launch_bounds__(256) void count_profile_kernel(
    const int* __restrict__ dst, unsigned* __restrict__ deg, int NR)
{
    const int t = blockIdx.x*256 + threadIdx.x;
    if (t < NR) atomicAdd(&deg[dst[t]], 1u);
}

// cntF[v] = #edges with dst==v (forward msgs into v)
// cntR[v] = #edges with src==v (reverse msgs into v)
__global__ __launch_bounds__(256) void count_edges_kernel(
    const int* __restrict__ src, const int* __restrict__ dst,
    unsigned* __restrict__ cntF, unsigned* __restrict__ cntR, int EP)
{
    const int t = blockIdx.x*256 + threadIdx.x;
    if (t < EP) { atomicAdd(&cntF[dst[t]], 1u); atomicAdd(&cntR[src[t]], 1u); }
}

// Single-block exclusive scan: off[i] = cur[i] = sum(cnt[0..i)).
__global__ __launch_bounds__(1024) void scan_kernel(
    const unsigned* __restrict__ cnt, int* __restrict__ off,
    int* __restrict__ cur, int n)
{
    __shared__ unsigned tsum[1024];
    const int t = threadIdx.x;
    const int chunk = CDIV(n, 1024);
    const int lo = t * chunk;
    const int hi = (lo + chunk < n) ? lo + chunk : n;
    unsigned s = 0;
    for (int i = lo; i < hi; ++i) s += cnt[i];
    tsum[t] = s;
    __syncthreads();
    #pragma unroll
    for (int d = 1; d < 1024; d <<= 1) {
        unsigned x = (t >= d) ? tsum[t - d] : 0u;
        __syncthreads();
        tsum[t] += x;
        __syncthreads();
    }
    unsigned run = (t > 0) ? tsum[t - 1] : 0u;
    for (int i = lo; i < hi; ++i) {
        off[i] = (int)run; cur[i] = (int)run;
        run += cnt[i];
    }
}

// Scatter edges into CSR lists. After this, cur[v] == end offset of v's list.
__global__ __launch_bounds__(256) void fill_csr_kernel(
    const int* __restrict__ src, const int* __restrict__ dst,
    const int* __restrict__ qid,
    int* __restrict__ curF, int* __restrict__ curR,
    int* __restrict__ fwd_src, int* __restrict__ fwd_qid,
    int* __restrict__ rev_dst, int EP)
{
    const int t = blockIdx.x*256 + threadIdx.x;
    if (t >= EP) return;
    const int s = src[t], d = dst[t];
    const int pF = atomicAdd(&curF[d], 1);
    fwd_src[pF] = s;
    fwd_qid[pF] = qid[t];
    const int pR = atomicAdd(&curR[s], 1);
    rev_dst[pR] = d;
}

// prof /= max(deg_p,1); inv = 1/sqrt(max(cntF+cntR,1))
__global__ __launch_bounds__(256) void finalize_kernel(
    float* __restrict__ e, float* __restrict__ inv,
    const unsigned* __restrict__ deg_p,
    const unsigned* __restrict__ cntF, const unsigned* __restrict__ cntR, int NE)
{
    const int t = blockIdx.x*256 + threadIdx.x;
    const int v = t >> 5;
    if (v >= NE) return;
    const int c = (t & 31) * 4;
    const size_t o = (size_t)v*128 + c;
    if (c >= 64) {
        float4 ev = *(const float4*)&e[o];
        const unsigned dp = deg_p[v];
        const float r = 1.0f / (float)(dp > 1u ? dp : 1u);
        ev.x *= r; ev.y *= r; ev.z *= r; ev.w *= r;
        *(float4*)&e[o] = ev;
    }
    if (c == 0) {
        const unsigned di = cntF[v] + cntR[v];
        inv[v] = 1.0f / sqrtf((float)(di > 1u ? di : 1u));
    }
}

// acc[r] += e[sel[r]] for the 3*B scoring rows (users|items|negs)
__global__ __launch_bounds__(256) void gather_acc_kernel(
    const float* __restrict__ e, const int* __restrict__ users,
    const int* __restrict__ items, const int* __restrict__ negs,
    float* __restrict__ acc, int B)
{
    const int t = blockIdx.x*256 + threadIdx.x;
    const int r = t >> 5;
    if (r >= 3*B) return;
    const int c = (t & 31) * 4;
    const int which = r / B, b = r - which*B;
    const int idx = (which == 0) ? users[b] : (which == 1) ? items[b] : negs[b];
    const float4 ev = *(const float4*)&e[(size_t)idx*128 + c];
    float4 a = *(const float4*)&acc[(size_t)r*128 + c];
    a.x += ev.x; a.y += ev.y; a.z += ev.z; a.w += ev.w;
    *(float4*)&acc[(size_t)r*128 + c] = a;
}

// ---------------------------------------------------------------------------
// Fused propagate+combine, gather form (NO float atomics):
//   e_nxt[v] = inv[v] * ( sum_{fwd in v} (e[src] + [0|q_h[qid]]*inv[src])
//                       + sum_{rev in v} e[dst]*inv[dst] )
// 32 threads per entity row, float4 per thread.
// ---------------------------------------------------------------------------
__global__ __launch_bounds__(256) void prop_kernel(
    const float* __restrict__ e_cur, const float* __restrict__ q_h,
    const float* __restrict__ inv,
    const int* __restrict__ offF, const int* __restrict__ endF,
    const int* __restrict__ fwd_src, const int* __restrict__ fwd_qid,
    const int* __restrict__ offR, const int* __restrict__ endR,
    const int* __restrict__ rev_dst,
    float* __restrict__ e_nxt, int NE)
{
    const int t = blockIdx.x*256 + threadIdx.x;
    const int v = t >> 5;
    if (v >= NE) return;
    const int c = (t & 31) * 4;
    float ax = 0.f, ay = 0.f, az = 0.f, aw = 0.f;

    const int bF = offF[v], eF = endF[v];
    for (int i = bF; i < eF; ++i) {
        const int s = fwd_src[i];
        const float4 es = *(const float4*)&e_cur[(size_t)s*128 + c];
        ax += es.x; ay += es.y; az += es.z; aw += es.w;
        if (c >= 64) {
            const int q = fwd_qid[i];
            const float invs = inv[s];
            const float4 qh = *(const float4*)&q_h[(size_t)q*64 + (c - 64)];
            ax += qh.x*invs; ay += qh.y*invs; az += qh.z*invs; aw += qh.w*invs;
        }
    }
    const int bR = offR[v], eR = endR[v];
    for (int i = bR; i < eR; ++i) {
        const int d = rev_dst[i];
        const float invd = inv[d];
        const float4 ed = *(const float4*)&e_cur[(size_t)d*128 + c];
        ax += ed.x*invd; ay += ed.y*invd; az += ed.z*invd; aw += ed.w*invd;
    }
    const float iv = inv[v];
    float4 r; r.x = ax*iv; r.y = ay*iv; r.z = az*iv; r.w = aw*iv;
    *(float4*)&e_nxt[(size_t)v*128 + c] = r;
}

// BPR loss: one block (128 threads) per batch element.
// acc holds 4*efin at rows [users | items | negs].
__global__ __launch_bounds__(128) void loss_kernel(
    const float* __restrict__ acc, const float* __restrict__ qb,
    float* __restrict__ out, int B, float invB)
{
    const int b = blockIdx.x, d = threadIdx.x;
    const float u = acc[(size_t)b*128 + d] * 0.25f;
    const float p = u + (d >= 64 ? qb[(size_t)b*64 + (d - 64)] : 0.f);
    const float ei = acc[(size_t)(B + b)*128 + d];
    const float en = acc[(size_t)(2*B + b)*128 + d];
    float x = p * (ei - en) * 0.25f;
    #pragma unroll
    for (int off = 1; off < 64; off <<= 1) x += __shfl_xor(x, off, 64);
    __shared__ float wred[2];
    if ((threadIdx.x & 63) == 0) wred[threadIdx.x >> 6] = x;
    __syncthreads();
    if (threadIdx.x == 0) {
        const float xx = wred[0] + wred[1];
        const float ls = fminf(xx, 0.f) - log1pf(expf(-fabsf(xx)));  // log_sigmoid
        atomicAdd(out, -ls * invB);
    }
}

extern "C" void kernel_launch(void* const* d_in, const int* in_sizes, int n_in,
                              void* d_out, int out_size, void* d_ws, size_t ws_size,
                              hipStream_t stream)
{
    const float* word_emb        = (const float*)d_in[0];
    const float* entity_emb      = (const float*)d_in[1];
    const float* Wq = (const float*)d_in[2];  const float* bq = (const float*)d_in[3];
    const float* Wk = (const float*)d_in[4];  const float* bk = (const float*)d_in[5];
    const float* Wv = (const float*)d_in[6];  const float* bv = (const float*)d_in[7];
    const float* Wo = (const float*)d_in[8];  const float* bo = (const float*)d_in[9];
    const int* review_words      = (const int*)d_in[10];
    const int* query_words_graph = (const int*)d_in[11];
    const int* profile_dst       = (const int*)d_in[12];
    const int* pur_src           = (const int*)d_in[13];
    const int* pur_dst           = (const int*)d_in[14];
    const int* pur_qid           = (const int*)d_in[15];
    const int* users             = (const int*)d_in[16];
    const int* items             = (const int*)d_in[17];
    const int* negs              = (const int*)d_in[18];
    const int* query_words       = (const int*)d_in[19];

    const int NE = in_sizes[1]  / 64;
    const int NR = in_sizes[10] / 16;
    const int NQ = in_sizes[11] / 8;
    const int EP = in_sizes[13];
    const int B  = in_sizes[16];

    char* ws = (char*)d_ws;
    size_t off = 0;
    auto alloc = [&](size_t bytes) -> char* {
        char* q = ws + off; off += (bytes + 255) & ~(size_t)255; return q;
    };
    float*    eA      = (float*)   alloc((size_t)NE*128*4);
    float*    eB      = (float*)   alloc((size_t)NE*128*4);
    float*    q_h     = (float*)   alloc((size_t)NQ*64*4);
    float*    qb      = (float*)   alloc((size_t)B*64*4);
    float*    acc     = (float*)   alloc((size_t)3*B*128*4);
    unsigned* deg_p   = (unsigned*)alloc((size_t)NE*4);
    unsigned* cntF    = (unsigned*)alloc((size_t)NE*4);
    unsigned* cntR    = (unsigned*)alloc((size_t)NE*4);
    int*      offF    = (int*)     alloc((size_t)NE*4);
    int*      offR    = (int*)     alloc((size_t)NE*4);
    int*      curF    = (int*)     alloc((size_t)NE*4);
    int*      curR    = (int*)     alloc((size_t)NE*4);
    int*      fwd_src = (int*)     alloc((size_t)EP*4);
    int*      fwd_qid = (int*)     alloc((size_t)EP*4);
    int*      rev_dst = (int*)     alloc((size_t)EP*4);
    float*    inv     = (float*)   alloc((size_t)NE*4);

    // If the workspace can't hold the footprint, bail out cleanly.
    if (off > ws_size) return;

    hipMemsetAsync(deg_p, 0, (size_t)NE*4, stream);
    hipMemsetAsync(cntF,  0, (size_t)NE*4, stream);
    hipMemsetAsync(cntR,  0, (size_t)NE*4, stream);
    hipMemsetAsync(acc,   0, (size_t)3*B*128*4, stream);
    hipMemsetAsync(d_out, 0, (size_t)out_size*4, stream);

    // --- CSR build -------------------------------------------------------
    count_edges_kernel<<<CDIV(EP, 256), 256, 0, stream>>>(pur_src, pur_dst, cntF, cntR, EP);
    count_profile_kernel<<<CDIV(NR, 256), 256, 0, stream>>>(profile_dst, deg_p, NR);
    scan_kernel<<<1, 1024, 0, stream>>>(cntF, offF, curF, NE);
    scan_kernel<<<1, 1024, 0, stream>>>(cntR, offR, curR, NE);
    fill_csr_kernel<<<CDIV(EP, 256), 256, 0, stream>>>(pur_src, pur_dst, pur_qid,
        curF, curR, fwd_src, fwd_qid, rev_dst, EP);

    // --- attention -------------------------------------------------------
    init_e_kernel<<<CDIV(NE*32, 256), 256, 0, stream>>>(eA, entity_emb, NE);
    attn_kernel<16,1><<<NR, 64, 0, stream>>>(word_emb, review_words,
        Wq,bq,Wk,bk,Wv,bv,Wo,bo, NR, eA, profile_dst);
    attn_kernel<8,0><<<NQ, 64, 0, stream>>>(word_emb, query_words_graph,
        Wq,bq,Wk,bk,Wv,bv,Wo,bo, NQ, q_h, nullptr);
    attn_kernel<8,0><<<B, 64, 0, stream>>>(word_emb, query_words,
        Wq,bq,Wk,bk,Wv,bv,Wo,bo, B, qb, nullptr);

    finalize_kernel<<<CDIV(NE*32, 256), 256, 0, stream>>>(eA, inv, deg_p, cntF, cntR, NE);
    gather_acc_kernel<<<CDIV(3*B*32, 256), 256, 0, stream>>>(eA, users, items, negs, acc, B);

    // --- K=3 propagation, ping-pong eA/eB, no float atomics --------------
    float* cur = eA; float* nxt = eB;
    for (int k = 0; k < 3; ++k) {
        prop_kernel<<<CDIV(NE*32, 256), 256, 0, stream>>>(cur, q_h, inv,
            offF, curF, fwd_src, fwd_qid, offR, curR, rev_dst, nxt, NE);
        gather_acc_kernel<<<CDIV(3*B*32, 256), 256, 0, stream>>>(nxt, users, items, negs, acc, B);
        float* tmp = cur; cur = nxt; nxt = tmp;
    }

    loss_kernel<<<B, 128, 0, stream>>>(acc, qb, (float*)d_out, B, 1.0f / (float)B);
}

// Round 4
// 1659.780 us; speedup vs baseline: 4.2636x; 1.9105x over previous
//
#include <hip/hip_runtime.h>
#include <cstdint>

#define CDIV(a,b) (((a)+(b)-1)/(b))

typedef __attribute__((ext_vector_type(8))) short bf16x8;   // 8 bf16 = 4 VGPRs
typedef __attribute__((ext_vector_type(4))) float f32x4;    // MFMA accumulator

__device__ __forceinline__ short f2bf(float f) {
    return (short)(__builtin_bit_cast(unsigned, f) >> 16);  // truncate (cheap)
}
__device__ __forceinline__ float bf2f(short s) {
    return __builtin_bit_cast(float, ((unsigned)(unsigned short)s) << 16);
}
__device__ __forceinline__ unsigned pack2(float lo, float hi) {
    return (__builtin_bit_cast(unsigned, lo) >> 16) |
           (__builtin_bit_cast(unsigned, hi) & 0xffff0000u);
}

// A-fragment for mfma 16x16x32: lane m=lane&15 (token row), k=quad*8+j.
// 8 consecutive floats of the word-embedding row -> 8 bf16.
__device__ __forceinline__ bf16x8 load_x_frag(const float* __restrict__ we,
                                              int wid, int kbase) {
    const float4 f0 = *(const float4*)(we + (size_t)wid*64 + kbase);
    const float4 f1 = *(const float4*)(we + (size_t)wid*64 + kbase + 4);
    union { unsigned u[4]; bf16x8 v; } c;
    c.u[0] = pack2(f0.x, f0.y); c.u[1] = pack2(f0.z, f0.w);
    c.u[2] = pack2(f1.x, f1.y); c.u[3] = pack2(f1.z, f1.w);
    if (wid == 0) { c.u[0]=0u; c.u[1]=0u; c.u[2]=0u; c.u[3]=0u; }  // padding_idx
    return c.v;
}

// ---------------------------------------------------------------------------
// MFMA attention. Block = 256 thr = 4 waves; wave handles 4 tiles of 16 tokens
// (16/L sequences per tile). QKV via mfma_f32_16x16x32_bf16 (A from global
// word rows, B from pre-transposed bf16 Wt). Scores per head: one MFMA with
// K padded 16->32 (upper quads zeroed). Softmax in registers (16-lane shfl).
// mean_l folded: pbar[m]=mean_l P[l][m]; o = pbar@V (VALU). out = bo + o@Wo.
// MODE 0: outp[seq*64+j]=res. MODE 1: atomicAdd(outp[sidx[seq]*128+64+j]).
// ---------------------------------------------------------------------------
template<int L, int MODE>
__global__ __launch_bounds__(256) void attn_mfma(
    const float* __restrict__ we, const int* __restrict__ words,
    const short* __restrict__ Wt,
    const float* __restrict__ bq, const float* __restrict__ bk,
    const float* __restrict__ bv,
    const float* __restrict__ Wo, const float* __restrict__ bo,
    int N, float* __restrict__ outp, const int* __restrict__ sidx)
{
    constexpr int SPT = 16 / L;      // seqs per 16-token tile (1 or 2)
    constexpr int SB  = 16 * SPT;    // seqs per block
    __shared__ short q_s[4][16*72];  // per-wave [16 tok][64+8 dims] bf16
    __shared__ short k_s[4][16*72];
    __shared__ short v_s[4][16*72];
    __shared__ float pbar_s[4][SPT][64];   // [wave][seq][head*16+m]
    __shared__ float mo_s[SB][64];         // mean-attn output per seq

    const int wave = threadIdx.x >> 6;
    const int lane = threadIdx.x & 63;
    const int quad = lane >> 4;
    const int lm   = lane & 15;
    const int tok_total = N * L;

    for (int ti = 0; ti < 4; ++ti) {
        const int tile = blockIdx.x*16 + wave*4 + ti;
        int tg = tile*16 + lm;
        if (tg >= tok_total) tg = tok_total - 1;      // clamp (grids divide evenly)
        const int wid = words[tg];

        const bf16x8 a0 = load_x_frag(we, wid, quad*8);        // k 0..31
        const bf16x8 a1 = load_x_frag(we, wid, 32 + quad*8);   // k 32..63

        // --- QKV: acc[n-tile] starts at bias, 2 MFMA per (part, n-tile) ----
        f32x4 qa[4], ka[4], va[4];
        #pragma unroll
        for (int nt = 0; nt < 4; ++nt) {
            const int col = nt*16 + lm;
            float b;
            b = bq[col]; qa[nt] = (f32x4){b,b,b,b};
            b = bk[col]; ka[nt] = (f32x4){b,b,b,b};
            b = bv[col]; va[nt] = (f32x4){b,b,b,b};
        }
        #pragma unroll
        for (int nt = 0; nt < 4; ++nt) {
            const short* wq = Wt + ((0*64 + nt*16 + lm)*64) + quad*8;
            const short* wk = Wt + ((1*64 + nt*16 + lm)*64) + quad*8;
            const short* wv = Wt + ((2*64 + nt*16 + lm)*64) + quad*8;
            qa[nt] = __builtin_amdgcn_mfma_f32_16x16x32_bf16(a0, *(const bf16x8*)wq,      qa[nt],0,0,0);
            qa[nt] = __builtin_amdgcn_mfma_f32_16x16x32_bf16(a1, *(const bf16x8*)(wq+32), qa[nt],0,0,0);
            ka[nt] = __builtin_amdgcn_mfma_f32_16x16x32_bf16(a0, *(const bf16x8*)wk,      ka[nt],0,0,0);
            ka[nt] = __builtin_amdgcn_mfma_f32_16x16x32_bf16(a1, *(const bf16x8*)(wk+32), ka[nt],0,0,0);
            va[nt] = __builtin_amdgcn_mfma_f32_16x16x32_bf16(a0, *(const bf16x8*)wv,      va[nt],0,0,0);
            va[nt] = __builtin_amdgcn_mfma_f32_16x16x32_bf16(a1, *(const bf16x8*)(wv+32), va[nt],0,0,0);
        }
        // C-layout: row tok = quad*4+r, col = nt*16+lm -> LDS [tok][dim] bf16
        #pragma unroll
        for (int nt = 0; nt < 4; ++nt)
            #pragma unroll
            for (int r = 0; r < 4; ++r) {
                const int idx = (quad*4 + r)*72 + nt*16 + lm;
                q_s[wave][idx] = f2bf(qa[nt][r]);
                k_s[wave][idx] = f2bf(ka[nt][r]);
                v_s[wave][idx] = f2bf(va[nt][r]);
            }
        __syncthreads();

        // --- scores + softmax + pbar per head ------------------------------
        // row l = quad*4+r; col m = lane&15; for L=8 valid iff same seq half
        const bool mvalid = (SPT==1) ? true : (((lane>>3)&1) == ((lane>>5)&1));
        #pragma unroll
        for (int h = 0; h < 4; ++h) {
            bf16x8 af = {0,0,0,0,0,0,0,0}, bfr = {0,0,0,0,0,0,0,0};
            if (quad < 2) {   // K=16 padded to 32: upper quads stay zero
                af  = *(const bf16x8*)&q_s[wave][lm*72 + h*16 + quad*8];
                bfr = *(const bf16x8*)&k_s[wave][lm*72 + h*16 + quad*8];
            }
            f32x4 s4 = __builtin_amdgcn_mfma_f32_16x16x32_bf16(
                af, bfr, (f32x4){0.f,0.f,0.f,0.f},0,0,0);
            float pbsum = 0.f;
            #pragma unroll
            for (int r = 0; r < 4; ++r) {
                float s = s4[r] * 0.25f;            // / sqrt(DH=16)
                if (!mvalid) s = -3.0e38f;
                float m = s;
                m = fmaxf(m, __shfl_xor(m,1,64));
                m = fmaxf(m, __shfl_xor(m,2,64));
                m = fmaxf(m, __shfl_xor(m,4,64));
                m = fmaxf(m, __shfl_xor(m,8,64));
                const float pe = __expf(s - m);
                float rs = pe;
                rs += __shfl_xor(rs,1,64);
                rs += __shfl_xor(rs,2,64);
                rs += __shfl_xor(rs,4,64);
                rs += __shfl_xor(rs,8,64);
                pbsum += pe / rs;                   // P[l][m] summed over rows
            }
            float v = pbsum + __shfl_xor(pbsum,16,64);  // quads 0+1 / 2+3
            if (SPT == 1) v += __shfl_xor(v,32,64);     // all 16 rows
            v *= (1.0f / (float)L);                     // mean over l
            if ((quad & (SPT==1 ? 3 : 1)) == 0)
                pbar_s[wave][quad>>1][h*16+lm] = v;     // invalid m -> 0
        }
        __syncthreads();

        // --- o[dh] = sum_m pbar[head(dh)][m] * V[m][dh] --------------------
        #pragma unroll
        for (int s = 0; s < SPT; ++s) {
            const float* pb = &pbar_s[wave][s][(lane>>4)*16];
            float o = 0.f;
            #pragma unroll
            for (int m = 0; m < 16; ++m)
                o += pb[m] * bf2f(v_s[wave][m*72 + lane]);
            mo_s[(wave*4+ti)*SPT + s][lane] = o;
        }
        __syncthreads();
    }

    // --- final: out = bo + mo @ Wo (fp32) ---------------------------------
    for (int s2 = 0; s2 < 4*SPT; ++s2) {
        const int sb  = wave*4*SPT + s2;
        const int seq = blockIdx.x*SB + sb;
        if (seq >= N) break;
        float res = bo[lane];
        #pragma unroll 8
        for (int n = 0; n < 64; ++n)
            res += mo_s[sb][n] * Wo[n*64 + lane];
        if (MODE == 0) outp[(size_t)seq*64 + lane] = res;
        else atomicAdd(&outp[(size_t)sidx[seq]*128 + 64 + lane], res);
    }
}

// Wt[part][n][k] = W_part[k][n] as bf16 (RTNE), parts q,k,v. 3*64*64 entries.
__global__ __launch_bounds__(256) void prep_wt_kernel(
    const float* __restrict__ Wq, const float* __restrict__ Wk,
    const float* __restrict__ Wv, short* __restrict__ Wt)
{
    const int t = blockIdx.x*256 + threadIdx.x;
    const int p = t >> 12, n = (t >> 6) & 63, k = t & 63;
    const float* W = (p==0) ? Wq : (p==1) ? Wk : Wv;
    const unsigned u = __builtin_bit_cast(unsigned, W[k*64 + n]);
    Wt[t] = (short)((u + 0x7fffu + ((u>>16)&1u)) >> 16);
}

// ---------------------------------------------------------------------------
__global__ __launch_bounds__(256) void init_e_kernel(
    float* __restrict__ e, const float* __restrict__ entity_emb, int NE)
{
    const int t = blockIdx.x*256 + threadIdx.x;
    const int v = t >> 5;
    if (v >= NE) return;
    const int c = (t & 31) * 4;
    float4 val;
    if (c < 64) val = *(const float4*)&entity_emb[(size_t)v*64 + c];
    else        val = make_float4(0.f, 0.f, 0.f, 0.f);
    *(float4*)&e[(size_t)v*128 + c] = val;
}

__global__ __launch_bounds__(256) void count_profile_kernel(
    const int* __restrict__ dst, unsigned* __restrict__ deg, int NR)
{
    const int t = blockIdx.x*256 + threadIdx.x;
    if (t < NR) atomicAdd(&deg[dst[t]], 1u);
}

__global__ __launch_bounds__(256) void count_edges_kernel(
    const int* __restrict__ src, const int* __restrict__ dst,
    unsigned* __restrict__ cntF, unsigned* __restrict__ cntR, int EP)
{
    const int t = blockIdx.x*256 + threadIdx.x;
    if (t < EP) { atomicAdd(&cntF[dst[t]], 1u); atomicAdd(&cntR[src[t]], 1u); }
}

// Two independent single-block scans in one launch (block 0: F, block 1: R).
__global__ __launch_bounds__(1024) void scan2_kernel(
    const unsigned* __restrict__ cntF, int* __restrict__ offF, int* __restrict__ curF,
    const unsigned* __restrict__ cntR, int* __restrict__ offR, int* __restrict__ curR,
    int n)
{
    const unsigned* cnt = blockIdx.x ? cntR : cntF;
    int* off = blockIdx.x ? offR : offF;
    int* cur = blockIdx.x ? curR : curF;
    __shared__ unsigned tsum[1024];
    const int t = threadIdx.x;
    const int chunk = CDIV(n, 1024);
    const int lo = t * chunk;
    const int hi = (lo + chunk < n) ? lo + chunk : n;
    unsigned s = 0;
    for (int i = lo; i < hi; ++i) s += cnt[i];
    tsum[t] = s;
    __syncthreads();
    #pragma unroll
    for (int d = 1; d < 1024; d <<= 1) {
        unsigned x = (t >= d) ? tsum[t - d] : 0u;
        __syncthreads();
        tsum[t] += x;
        __syncthreads();
    }
    unsigned run = (t > 0) ? tsum[t - 1] : 0u;
    for (int i = lo; i < hi; ++i) {
        off[i] = (int)run; cur[i] = (int)run;
        run += cnt[i];
    }
}

__global__ __launch_bounds__(256) void fill_csr_kernel(
    const int* __restrict__ src, const int* __restrict__ dst,
    const int* __restrict__ qid,
    int* __restrict__ curF, int* __restrict__ curR,
    int* __restrict__ fwd_src, int* __restrict__ fwd_qid,
    int* __restrict__ rev_dst, int EP)
{
    const int t = blockIdx.x*256 + threadIdx.x;
    if (t >= EP) return;
    const int s = src[t], d = dst[t];
    const int pF = atomicAdd(&curF[d], 1);
    fwd_src[pF] = s;
    fwd_qid[pF] = qid[t];
    const int pR = atomicAdd(&curR[s], 1);
    rev_dst[pR] = d;
}

__global__ __launch_bounds__(256) void finalize_kernel(
    float* __restrict__ e, float* __restrict__ inv,
    const unsigned* __restrict__ deg_p,
    const unsigned* __restrict__ cntF, const unsigned* __restrict__ cntR, int NE)
{
    const int t = blockIdx.x*256 + threadIdx.x;
    const int v = t >> 5;
    if (v >= NE) return;
    const int c = (t & 31) * 4;
    const size_t o = (size_t)v*128 + c;
    if (c >= 64) {
        float4 ev = *(const float4*)&e[o];
        const unsigned dp = deg_p[v];
        const float r = 1.0f / (float)(dp > 1u ? dp : 1u);
        ev.x *= r; ev.y *= r; ev.z *= r; ev.w *= r;
        *(float4*)&e[o] = ev;
    }
    if (c == 0) {
        const unsigned di = cntF[v] + cntR[v];
        inv[v] = 1.0f / sqrtf((float)(di > 1u ? di : 1u));
    }
}

__global__ __launch_bounds__(256) void gather_acc_kernel(
    const float* __restrict__ e, const int* __restrict__ users,
    const int* __restrict__ items, const int* __restrict__ negs,
    float* __restrict__ acc, int B)
{
    const int t = blockIdx.x*256 + threadIdx.x;
    const int r = t >> 5;
    if (r >= 3*B) return;
    const int c = (t & 31) * 4;
    const int which = r / B, b = r - which*B;
    const int idx = (which == 0) ? users[b] : (which == 1) ? items[b] : negs[b];
    const float4 ev = *(const float4*)&e[(size_t)idx*128 + c];
    float4 a = *(const float4*)&acc[(size_t)r*128 + c];
    a.x += ev.x; a.y += ev.y; a.z += ev.z; a.w += ev.w;
    *(float4*)&acc[(size_t)r*128 + c] = a;
}

// Fused propagate+combine, gather form (no float atomics).
__global__ __launch_bounds__(256) void prop_kernel(
    const float* __restrict__ e_cur, const float* __restrict__ q_h,
    const float* __restrict__ inv,
    const int* __restrict__ offF, const int* __restrict__ endF,
    const int* __restrict__ fwd_src, const int* __restrict__ fwd_qid,
    const int* __restrict__ offR, const int* __restrict__ endR,
    const int* __restrict__ rev_dst,
    float* __restrict__ e_nxt, int NE)
{
    const int t = blockIdx.x*256 + threadIdx.x;
    const int v = t >> 5;
    if (v >= NE) return;
    const int c = (t & 31) * 4;
    float ax = 0.f, ay = 0.f, az = 0.f, aw = 0.f;

    const int bF = offF[v], eF = endF[v];
    for (int i = bF; i < eF; ++i) {
        const int s = fwd_src[i];
        const float4 es = *(const float4*)&e_cur[(size_t)s*128 + c];
        ax += es.x; ay += es.y; az += es.z; aw += es.w;
        if (c >= 64) {
            const int q = fwd_qid[i];
            const float invs = inv[s];
            const float4 qh = *(const float4*)&q_h[(size_t)q*64 + (c - 64)];
            ax += qh.x*invs; ay += qh.y*invs; az += qh.z*invs; aw += qh.w*invs;
        }
    }
    const int bR = offR[v], eR = endR[v];
    for (int i = bR; i < eR; ++i) {
        const int d = rev_dst[i];
        const float invd = inv[d];
        const float4 ed = *(const float4*)&e_cur[(size_t)d*128 + c];
        ax += ed.x*invd; ay += ed.y*invd; az += ed.z*invd; aw += ed.w*invd;
    }
    const float iv = inv[v];
    float4 r; r.x = ax*iv; r.y = ay*iv; r.z = az*iv; r.w = aw*iv;
    *(float4*)&e_nxt[(size_t)v*128 + c] = r;
}

__global__ __launch_bounds__(128) void loss_kernel(
    const float* __restrict__ acc, const float* __restrict__ qb,
    float* __restrict__ out, int B, float invB)
{
    const int b = blockIdx.x, d = threadIdx.x;
    const float u = acc[(size_t)b*128 + d] * 0.25f;
    const float p = u + (d >= 64 ? qb[(size_t)b*64 + (d - 64)] : 0.f);
    const float ei = acc[(size_t)(B + b)*128 + d];
    const float en = acc[(size_t)(2*B + b)*128 + d];
    float x = p * (ei - en) * 0.25f;
    #pragma unroll
    for (int off = 1; off < 64; off <<= 1) x += __shfl_xor(x, off, 64);
    __shared__ float wred[2];
    if ((threadIdx.x & 63) == 0) wred[threadIdx.x >> 6] = x;
    __syncthreads();
    if (threadIdx.x == 0) {
        const float xx = wred[0] + wred[1];
        const float ls = fminf(xx, 0.f) - log1pf(expf(-fabsf(xx)));
        atomicAdd(out, -ls * invB);
    }
}

extern "C" void kernel_launch(void* const* d_in, const int* in_sizes, int n_in,
                              void* d_out, int out_size, void* d_ws, size_t ws_size,
                              hipStream_t stream)
{
    const float* word_emb        = (const float*)d_in[0];
    const float* entity_emb      = (const float*)d_in[1];
    const float* Wq = (const float*)d_in[2];  const float* bq = (const float*)d_in[3];
    const float* Wk = (const float*)d_in[4];  const float* bk = (const float*)d_in[5];
    const float* Wv = (const float*)d_in[6];  const float* bv = (const float*)d_in[7];
    const float* Wo = (const float*)d_in[8];  const float* bo = (const float*)d_in[9];
    const int* review_words      = (const int*)d_in[10];
    const int* query_words_graph = (const int*)d_in[11];
    const int* profile_dst       = (const int*)d_in[12];
    const int* pur_src           = (const int*)d_in[13];
    const int* pur_dst           = (const int*)d_in[14];
    const int* pur_qid           = (const int*)d_in[15];
    const int* users             = (const int*)d_in[16];
    const int* items             = (const int*)d_in[17];
    const int* negs              = (const int*)d_in[18];
    const int* query_words       = (const int*)d_in[19];

    const int NE = in_sizes[1]  / 64;
    const int NR = in_sizes[10] / 16;
    const int NQ = in_sizes[11] / 8;
    const int EP = in_sizes[13];
    const int B  = in_sizes[16];

    char* ws = (char*)d_ws;
    size_t off = 0;
    auto alloc = [&](size_t bytes) -> char* {
        char* q = ws + off; off += (bytes + 255) & ~(size_t)255; return q;
    };
    float*    eA      = (float*)   alloc((size_t)NE*128*4);
    float*    eB      = (float*)   alloc((size_t)NE*128*4);
    float*    q_h     = (float*)   alloc((size_t)NQ*64*4);
    float*    qb      = (float*)   alloc((size_t)B*64*4);
    float*    acc     = (float*)   alloc((size_t)3*B*128*4);
    unsigned* deg_p   = (unsigned*)alloc((size_t)NE*4);
    unsigned* cntF    = (unsigned*)alloc((size_t)NE*4);
    unsigned* cntR    = (unsigned*)alloc((size_t)NE*4);
    int*      offF    = (int*)     alloc((size_t)NE*4);
    int*      offR    = (int*)     alloc((size_t)NE*4);
    int*      curF    = (int*)     alloc((size_t)NE*4);
    int*      curR    = (int*)     alloc((size_t)NE*4);
    int*      fwd_src = (int*)     alloc((size_t)EP*4);
    int*      fwd_qid = (int*)     alloc((size_t)EP*4);
    int*      rev_dst = (int*)     alloc((size_t)EP*4);
    float*    inv     = (float*)   alloc((size_t)NE*4);
    short*    Wt      = (short*)   alloc((size_t)3*64*64*2);

    if (off > ws_size) return;  // clean bail instead of OOB fault

    hipMemsetAsync(deg_p, 0, (size_t)NE*4, stream);
    hipMemsetAsync(cntF,  0, (size_t)NE*4, stream);
    hipMemsetAsync(cntR,  0, (size_t)NE*4, stream);
    hipMemsetAsync(acc,   0, (size_t)3*B*128*4, stream);
    hipMemsetAsync(d_out, 0, (size_t)out_size*4, stream);

    // --- CSR build -------------------------------------------------------
    count_edges_kernel<<<CDIV(EP, 256), 256, 0, stream>>>(pur_src, pur_dst, cntF, cntR, EP);
    count_profile_kernel<<<CDIV(NR, 256), 256, 0, stream>>>(profile_dst, deg_p, NR);
    scan2_kernel<<<2, 1024, 0, stream>>>(cntF, offF, curF, cntR, offR, curR, NE);
    fill_csr_kernel<<<CDIV(EP, 256), 256, 0, stream>>>(pur_src, pur_dst, pur_qid,
        curF, curR, fwd_src, fwd_qid, rev_dst, EP);

    // --- attention (MFMA) ------------------------------------------------
    prep_wt_kernel<<<48, 256, 0, stream>>>(Wq, Wk, Wv, Wt);
    init_e_kernel<<<CDIV(NE*32, 256), 256, 0, stream>>>(eA, entity_emb, NE);
    attn_mfma<16,1><<<CDIV(NR*16, 256), 256, 0, stream>>>(word_emb, review_words, Wt,
        bq, bk, bv, Wo, bo, NR, eA, profile_dst);
    attn_mfma<8,0><<<CDIV(NQ*8, 256), 256, 0, stream>>>(word_emb, query_words_graph, Wt,
        bq, bk, bv, Wo, bo, NQ, q_h, nullptr);
    attn_mfma<8,0><<<CDIV(B*8, 256), 256, 0, stream>>>(word_emb, query_words, Wt,
        bq, bk, bv, Wo, bo, B, qb, nullptr);

    finalize_kernel<<<CDIV(NE*32, 256), 256, 0, stream>>>(eA, inv, deg_p, cntF, cntR, NE);
    gather_acc_kernel<<<CDIV(3*B*32, 256), 256, 0, stream>>>(eA, users, items, negs, acc, B);

    // --- K=3 propagation, ping-pong eA/eB --------------------------------
    float* cur = eA; float* nxt = eB;
    for (int k = 0; k < 3; ++k) {
        prop_kernel<<<CDIV(NE*32, 256), 256, 0, stream>>>(cur, q_h, inv,
            offF, curF, fwd_src, fwd_qid, offR, curR, rev_dst, nxt, NE);
        gather_acc_kernel<<<CDIV(3*B*32, 256), 256, 0, stream>>>(nxt, users, items, negs, acc, B);
        float* tmp = cur; cur = nxt; nxt = tmp;
    }

    loss_kernel<<<B, 128, 0, stream>>>(acc, qb, (float*)d_out, B, 1.0f / (float)B);
}

// Round 5
// 1016.346 us; speedup vs baseline: 6.9628x; 1.6331x over previous
//
#include <hip/hip_runtime.h>
#include <cstdint>

#define CDIV(a,b) (((a)+(b)-1)/(b))

typedef __attribute__((ext_vector_type(8))) short bf16x8;   // 8 bf16 = 4 VGPRs
typedef __attribute__((ext_vector_type(4))) float f32x4;    // MFMA accumulator

__device__ __forceinline__ float bf2f(short s) {
    return __builtin_bit_cast(float, ((unsigned)(unsigned short)s) << 16);
}
__device__ __forceinline__ short rtne(float f) {
    const unsigned u = __builtin_bit_cast(unsigned, f);
    return (short)((u + 0x7fffu + ((u >> 16) & 1u)) >> 16);
}

// ---------------------------------------------------------------------------
// WQKV[w][0:64]=x@Wq+bq, [64:128]=x@Wk+bk, [128:192]=x@Wv+bv as bf16 (RTNE).
// x = word_emb[w], zeroed for w==0 (padding_idx). One wave per word; lane j
// owns cols j / 64+j / 128+j; x rows wave-uniform -> scalar loads.
// ---------------------------------------------------------------------------
__global__ __launch_bounds__(256) void prep_wqkv_kernel(
    const float* __restrict__ we,
    const float* __restrict__ Wq, const float* __restrict__ bq,
    const float* __restrict__ Wk, const float* __restrict__ bk,
    const float* __restrict__ Wv, const float* __restrict__ bv,
    short* __restrict__ WQKV, int NW)
{
    const int w = blockIdx.x*4 + (threadIdx.x >> 6);
    if (w >= NW) return;
    const int j = threadIdx.x & 63;
    float aq = bq[j], ak = bk[j], av = bv[j];
    if (w != 0) {
        const float* xr = we + (size_t)w*64;
        for (int d0 = 0; d0 < 64; d0 += 4) {
            const float x0 = xr[d0], x1 = xr[d0+1], x2 = xr[d0+2], x3 = xr[d0+3];
            aq += x0*Wq[(d0+0)*64+j] + x1*Wq[(d0+1)*64+j]
                + x2*Wq[(d0+2)*64+j] + x3*Wq[(d0+3)*64+j];
            ak += x0*Wk[(d0+0)*64+j] + x1*Wk[(d0+1)*64+j]
                + x2*Wk[(d0+2)*64+j] + x3*Wk[(d0+3)*64+j];
            av += x0*Wv[(d0+0)*64+j] + x1*Wv[(d0+1)*64+j]
                + x2*Wv[(d0+2)*64+j] + x3*Wv[(d0+3)*64+j];
        }
    }
    short* out = WQKV + (size_t)w*192;
    out[j] = rtne(aq); out[64+j] = rtne(ak); out[128+j] = rtne(av);
}

// ---------------------------------------------------------------------------
// Gather-based MFMA attention. Block = 4 waves; wave handles 4 tiles of 16
// tokens, all LDS regions per-wave. Per tile: gather q/k frags + v row from
// WQKV (bf16); scores S^T = K.Q^T via one 16x16x32 MFMA per head (K padded,
// quads 2-3 zero); softmax reductions in-register over r + 2 quad-shfls;
// pbar[m] = mean_l P via 16-lane shfl sums; o = pbar@V (VALU);
// out = bo + o@Wo (fp32). MODE 0: store; MODE 1: atomic scatter into e.
// ---------------------------------------------------------------------------
template<int L, int MODE>
__global__ __launch_bounds__(256) void attn_mfma(
    const short* __restrict__ WQKV, const int* __restrict__ words,
    const float* __restrict__ Wo, const float* __restrict__ bo,
    int N, float* __restrict__ outp, const int* __restrict__ sidx)
{
    constexpr int SPT = 16 / L;          // seqs per 16-token tile
    __shared__ short v_s[4][16*72];      // per-wave [tok][dh], stride 72
    __shared__ float pbar_s[4][64];      // per-wave [h*16+m]
    __shared__ float mo_s[4][SPT][64];   // per-wave mean-attn out per seq

    const int wave = threadIdx.x >> 6;
    const int lane = threadIdx.x & 63;
    const int quad = lane >> 4;
    const int lm   = lane & 15;
    const int tok_total = N * L;
    const float invL = 1.0f / (float)L;

    for (int ti = 0; ti < 4; ++ti) {
        const int tile = blockIdx.x*16 + wave*4 + ti;
        int tg = tile*16 + lm;
        if (tg >= tok_total) tg = tok_total - 1;   // clamp; seq-guard below
        const int wid = words[tg];
        const short* row = WQKV + (size_t)wid * 192;

        // V gather -> LDS [tok][dh] (2x16B per lane, 16B-aligned)
        *(int4*)&v_s[wave][lm*72 + quad*16]     = *(const int4*)(row + 128 + quad*16);
        *(int4*)&v_s[wave][lm*72 + quad*16 + 8] = *(const int4*)(row + 128 + quad*16 + 8);

        // valid iff key-token seq (quad>>1) == query-token seq (lm>>3)
        const bool mvalid = (SPT == 1) ? true : ((quad >> 1) == ((lm >> 3) & 1));

        #pragma unroll
        for (int h = 0; h < 4; ++h) {
            bf16x8 af = {0,0,0,0,0,0,0,0}, bfr = {0,0,0,0,0,0,0,0};
            if (quad < 2) {   // K=16 padded to 32
                af  = *(const bf16x8*)(row + 64 + h*16 + quad*8);  // K frag
                bfr = *(const bf16x8*)(row +      h*16 + quad*8);  // Q frag
            }
            // S^T[m=quad*4+r][l=lm] = sum_k K[m][k] Q[l][k]
            const f32x4 s4 = __builtin_amdgcn_mfma_f32_16x16x32_bf16(
                af, bfr, (f32x4){0.f,0.f,0.f,0.f}, 0, 0, 0);
            float sv0 = s4[0]*0.25f, sv1 = s4[1]*0.25f,
                  sv2 = s4[2]*0.25f, sv3 = s4[3]*0.25f;   // / sqrt(DH=16)
            if (!mvalid) { sv0 = sv1 = sv2 = sv3 = -3.0e38f; }
            float mx = fmaxf(fmaxf(sv0, sv1), fmaxf(sv2, sv3));
            mx = fmaxf(mx, __shfl_xor(mx, 16, 64));
            mx = fmaxf(mx, __shfl_xor(mx, 32, 64));
            float p0 = __expf(sv0-mx), p1 = __expf(sv1-mx),
                  p2 = __expf(sv2-mx), p3 = __expf(sv3-mx);
            float sm = p0+p1+p2+p3;
            sm += __shfl_xor(sm, 16, 64);
            sm += __shfl_xor(sm, 32, 64);
            const float rinv = __builtin_amdgcn_rcpf(sm);
            p0 *= rinv; p1 *= rinv; p2 *= rinv; p3 *= rinv;
            // pbar[m] = sum_l P^T[m][l]  (invalid entries are exactly 0)
            #pragma unroll
            for (int d = 1; d < 16; d <<= 1) {
                p0 += __shfl_xor(p0, d, 64);
                p1 += __shfl_xor(p1, d, 64);
                p2 += __shfl_xor(p2, d, 64);
                p3 += __shfl_xor(p3, d, 64);
            }
            if (lm == 0) {
                pbar_s[wave][h*16 + quad*4 + 0] = p0 * invL;
                pbar_s[wave][h*16 + quad*4 + 1] = p1 * invL;
                pbar_s[wave][h*16 + quad*4 + 2] = p2 * invL;
                pbar_s[wave][h*16 + quad*4 + 3] = p3 * invL;
            }
        }
        __syncthreads();

        // o[dh=lane] = sum_m pbar[head(lane)*16+m] * V[m][lane]
        #pragma unroll
        for (int s = 0; s < SPT; ++s) {
            float o = 0.f;
            #pragma unroll
            for (int j2 = 0; j2 < L; ++j2) {
                const int m = s*L + j2;
                o += pbar_s[wave][quad*16 + m] * bf2f(v_s[wave][m*72 + lane]);
            }
            mo_s[wave][s][lane] = o;
        }
        __syncthreads();

        // out[col=lane] = bo + sum_n mo[n] * Wo[n][lane]
        #pragma unroll
        for (int s = 0; s < SPT; ++s) {
            const int seq = tile*SPT + s;
            if (seq < N) {
                float res = bo[lane];
                #pragma unroll 8
                for (int n = 0; n < 64; ++n)
                    res += mo_s[wave][s][n] * Wo[n*64 + lane];
                if (MODE == 0) outp[(size_t)seq*64 + lane] = res;
                else atomicAdd(&outp[(size_t)sidx[seq]*128 + 64 + lane], res);
            }
        }
        __syncthreads();
    }
}

// ---------------------------------------------------------------------------
__global__ __launch_bounds__(256) void init_e_kernel(
    float* __restrict__ e, const float* __restrict__ entity_emb, int NE)
{
    const int t = blockIdx.x*256 + threadIdx.x;
    const int v = t >> 5;
    if (v >= NE) return;
    const int c = (t & 31) * 4;
    float4 val;
    if (c < 64) val = *(const float4*)&entity_emb[(size_t)v*64 + c];
    else        val = make_float4(0.f, 0.f, 0.f, 0.f);
    *(float4*)&e[(size_t)v*128 + c] = val;
}

__global__ __launch_bounds__(256) void count_profile_kernel(
    const int* __restrict__ dst, unsigned* __restrict__ deg, int NR)
{
    const int t = blockIdx.x*256 + threadIdx.x;
    if (t < NR) atomicAdd(&deg[dst[t]], 1u);
}

__global__ __launch_bounds__(256) void count_edges_kernel(
    const int* __restrict__ src, const int* __restrict__ dst,
    unsigned* __restrict__ cntF, unsigned* __restrict__ cntR, int EP)
{
    const int t = blockIdx.x*256 + threadIdx.x;
    if (t < EP) { atomicAdd(&cntF[dst[t]], 1u); atomicAdd(&cntR[src[t]], 1u); }
}

// --- 3-phase parallel exclusive scan of cntF and cntR (2*NB blocks) --------
#define SCAN_CHUNK 2048

__global__ __launch_bounds__(256) void scan_reduce_kernel(
    const unsigned* __restrict__ cntF, const unsigned* __restrict__ cntR,
    unsigned* __restrict__ part, int n, int NB)
{
    const int arr = blockIdx.x / NB, b = blockIdx.x % NB;
    const unsigned* cnt = arr ? cntR : cntF;
    const int base = b * SCAN_CHUNK;
    unsigned s = 0;
    #pragma unroll
    for (int i = 0; i < 8; ++i) {
        const int idx = base + i*256 + threadIdx.x;
        if (idx < n) s += cnt[idx];
    }
    #pragma unroll
    for (int off = 1; off < 64; off <<= 1) s += __shfl_xor(s, off, 64);
    __shared__ unsigned wsum[4];
    if ((threadIdx.x & 63) == 0) wsum[threadIdx.x >> 6] = s;
    __syncthreads();
    if (threadIdx.x == 0) part[arr*NB + b] = wsum[0]+wsum[1]+wsum[2]+wsum[3];
}

__global__ __launch_bounds__(1024) void scan_part_kernel(
    unsigned* __restrict__ part, int NB)
{
    __shared__ unsigned a[1024], b2[1024];
    const int t = threadIdx.x;
    a[t]  = (t < NB) ? part[t]      : 0u;
    b2[t] = (t < NB) ? part[NB + t] : 0u;
    __syncthreads();
    for (int d = 1; d < 1024; d <<= 1) {
        const unsigned xa = (t >= d) ? a[t-d] : 0u;
        const unsigned xb = (t >= d) ? b2[t-d] : 0u;
        __syncthreads();
        a[t] += xa; b2[t] += xb;
        __syncthreads();
    }
    if (t < NB) {
        part[t]      = (t > 0) ? a[t-1]  : 0u;
        part[NB + t] = (t > 0) ? b2[t-1] : 0u;
    }
}

__global__ __launch_bounds__(256) void scan_final_kernel(
    const unsigned* __restrict__ cntF, const unsigned* __restrict__ cntR,
    const unsigned* __restrict__ part,
    int* __restrict__ offF, int* __restrict__ curF,
    int* __restrict__ offR, int* __restrict__ curR, int n, int NB)
{
    const int arr = blockIdx.x / NB, b = blockIdx.x % NB;
    const unsigned* cnt = arr ? cntR : cntF;
    int* off = arr ? offR : offF;
    int* cur = arr ? curR : curF;
    __shared__ unsigned v[SCAN_CHUNK];
    __shared__ unsigned tsum[256];
    const int base = b * SCAN_CHUNK;
    const int t = threadIdx.x;
    #pragma unroll
    for (int i = 0; i < 8; ++i) {
        const int idx = base + i*256 + t;
        v[i*256 + t] = (idx < n) ? cnt[idx] : 0u;
    }
    __syncthreads();
    unsigned s = 0;
    #pragma unroll
    for (int i = 0; i < 8; ++i) s += v[t*8 + i];
    tsum[t] = s;
    __syncthreads();
    for (int d = 1; d < 256; d <<= 1) {
        const unsigned x = (t >= d) ? tsum[t-d] : 0u;
        __syncthreads();
        tsum[t] += x;
        __syncthreads();
    }
    unsigned run = ((t > 0) ? tsum[t-1] : 0u) + part[arr*NB + b];
    #pragma unroll
    for (int i = 0; i < 8; ++i) {
        const int idx = base + t*8 + i;
        if (idx < n) { off[idx] = (int)run; cur[idx] = (int)run; run += v[t*8+i]; }
    }
}

__global__ __launch_bounds__(256) void fill_csr_kernel(
    const int* __restrict__ src, const int* __restrict__ dst,
    const int* __restrict__ qid,
    int* __restrict__ curF, int* __restrict__ curR,
    int* __restrict__ fwd_src, int* __restrict__ fwd_qid,
    int* __restrict__ rev_dst, int EP)
{
    const int t = blockIdx.x*256 + threadIdx.x;
    if (t >= EP) return;
    const int s = src[t], d = dst[t];
    const int pF = atomicAdd(&curF[d], 1);
    fwd_src[pF] = s;
    fwd_qid[pF] = qid[t];
    const int pR = atomicAdd(&curR[s], 1);
    rev_dst[pR] = d;
}

__global__ __launch_bounds__(256) void finalize_kernel(
    float* __restrict__ e, float* __restrict__ inv,
    const unsigned* __restrict__ deg_p,
    const unsigned* __restrict__ cntF, const unsigned* __restrict__ cntR, int NE)
{
    const int t = blockIdx.x*256 + threadIdx.x;
    const int v = t >> 5;
    if (v >= NE) return;
    const int c = (t & 31) * 4;
    const size_t o = (size_t)v*128 + c;
    if (c >= 64) {
        float4 ev = *(const float4*)&e[o];
        const unsigned dp = deg_p[v];
        const float r = 1.0f / (float)(dp > 1u ? dp : 1u);
        ev.x *= r; ev.y *= r; ev.z *= r; ev.w *= r;
        *(float4*)&e[o] = ev;
    }
    if (c == 0) {
        const unsigned di = cntF[v] + cntR[v];
        inv[v] = 1.0f / sqrtf((float)(di > 1u ? di : 1u));
    }
}

__global__ __launch_bounds__(256) void gather_acc_kernel(
    const float* __restrict__ e, const int* __restrict__ users,
    const int* __restrict__ items, const int* __restrict__ negs,
    float* __restrict__ acc, int B)
{
    const int t = blockIdx.x*256 + threadIdx.x;
    const int r = t >> 5;
    if (r >= 3*B) return;
    const int c = (t & 31) * 4;
    const int which = r / B, b = r - which*B;
    const int idx = (which == 0) ? users[b] : (which == 1) ? items[b] : negs[b];
    const float4 ev = *(const float4*)&e[(size_t)idx*128 + c];
    float4 a = *(const float4*)&acc[(size_t)r*128 + c];
    a.x += ev.x; a.y += ev.y; a.z += ev.z; a.w += ev.w;
    *(float4*)&acc[(size_t)r*128 + c] = a;
}

// Fused propagate+combine, gather form (no float atomics).
__global__ __launch_bounds__(256) void prop_kernel(
    const float* __restrict__ e_cur, const float* __restrict__ q_h,
    const float* __restrict__ inv,
    const int* __restrict__ offF, const int* __restrict__ endF,
    const int* __restrict__ fwd_src, const int* __restrict__ fwd_qid,
    const int* __restrict__ offR, const int* __restrict__ endR,
    const int* __restrict__ rev_dst,
    float* __restrict__ e_nxt, int NE)
{
    const int t = blockIdx.x*256 + threadIdx.x;
    const int v = t >> 5;
    if (v >= NE) return;
    const int c = (t & 31) * 4;
    float ax = 0.f, ay = 0.f, az = 0.f, aw = 0.f;

    const int bF = offF[v], eF = endF[v];
    for (int i = bF; i < eF; ++i) {
        const int s = fwd_src[i];
        const float4 es = *(const float4*)&e_cur[(size_t)s*128 + c];
        ax += es.x; ay += es.y; az += es.z; aw += es.w;
        if (c >= 64) {
            const int q = fwd_qid[i];
            const float invs = inv[s];
            const float4 qh = *(const float4*)&q_h[(size_t)q*64 + (c - 64)];
            ax += qh.x*invs; ay += qh.y*invs; az += qh.z*invs; aw += qh.w*invs;
        }
    }
    const int bR = offR[v], eR = endR[v];
    for (int i = bR; i < eR; ++i) {
        const int d = rev_dst[i];
        const float invd = inv[d];
        const float4 ed = *(const float4*)&e_cur[(size_t)d*128 + c];
        ax += ed.x*invd; ay += ed.y*invd; az += ed.z*invd; aw += ed.w*invd;
    }
    const float iv = inv[v];
    float4 r; r.x = ax*iv; r.y = ay*iv; r.z = az*iv; r.w = aw*iv;
    *(float4*)&e_nxt[(size_t)v*128 + c] = r;
}

__global__ __launch_bounds__(128) void loss_kernel(
    const float* __restrict__ acc, const float* __restrict__ qb,
    float* __restrict__ out, int B, float invB)
{
    const int b = blockIdx.x, d = threadIdx.x;
    const float u = acc[(size_t)b*128 + d] * 0.25f;
    const float p = u + (d >= 64 ? qb[(size_t)b*64 + (d - 64)] : 0.f);
    const float ei = acc[(size_t)(B + b)*128 + d];
    const float en = acc[(size_t)(2*B + b)*128 + d];
    float x = p * (ei - en) * 0.25f;
    #pragma unroll
    for (int off = 1; off < 64; off <<= 1) x += __shfl_xor(x, off, 64);
    __shared__ float wred[2];
    if ((threadIdx.x & 63) == 0) wred[threadIdx.x >> 6] = x;
    __syncthreads();
    if (threadIdx.x == 0) {
        const float xx = wred[0] + wred[1];
        const float ls = fminf(xx, 0.f) - log1pf(expf(-fabsf(xx)));
        atomicAdd(out, -ls * invB);
    }
}

extern "C" void kernel_launch(void* const* d_in, const int* in_sizes, int n_in,
                              void* d_out, int out_size, void* d_ws, size_t ws_size,
                              hipStream_t stream)
{
    const float* word_emb        = (const float*)d_in[0];
    const float* entity_emb      = (const float*)d_in[1];
    const float* Wq = (const float*)d_in[2];  const float* bq = (const float*)d_in[3];
    const float* Wk = (const float*)d_in[4];  const float* bk = (const float*)d_in[5];
    const float* Wv = (const float*)d_in[6];  const float* bv = (const float*)d_in[7];
    const float* Wo = (const float*)d_in[8];  const float* bo = (const float*)d_in[9];
    const int* review_words      = (const int*)d_in[10];
    const int* query_words_graph = (const int*)d_in[11];
    const int* profile_dst       = (const int*)d_in[12];
    const int* pur_src           = (const int*)d_in[13];
    const int* pur_dst           = (const int*)d_in[14];
    const int* pur_qid           = (const int*)d_in[15];
    const int* users             = (const int*)d_in[16];
    const int* items             = (const int*)d_in[17];
    const int* negs              = (const int*)d_in[18];
    const int* query_words       = (const int*)d_in[19];

    const int NW = in_sizes[0]  / 64;
    const int NE = in_sizes[1]  / 64;
    const int NR = in_sizes[10] / 16;
    const int NQ = in_sizes[11] / 8;
    const int EP = in_sizes[13];
    const int B  = in_sizes[16];
    const int NB = CDIV(NE, SCAN_CHUNK);

    char* ws = (char*)d_ws;
    size_t off = 0;
    auto alloc = [&](size_t bytes) -> char* {
        char* q = ws + off; off += (bytes + 255) & ~(size_t)255; return q;
    };
    float*    eA      = (float*)   alloc((size_t)NE*128*4);
    float*    eB      = (float*)   alloc((size_t)NE*128*4);
    float*    q_h     = (float*)   alloc((size_t)NQ*64*4);
    float*    qb      = (float*)   alloc((size_t)B*64*4);
    float*    acc     = (float*)   alloc((size_t)3*B*128*4);
    unsigned* deg_p   = (unsigned*)alloc((size_t)NE*4);
    unsigned* cntF    = (unsigned*)alloc((size_t)NE*4);
    unsigned* cntR    = (unsigned*)alloc((size_t)NE*4);
    int*      offF    = (int*)     alloc((size_t)NE*4);
    int*      offR    = (int*)     alloc((size_t)NE*4);
    int*      curF    = (int*)     alloc((size_t)NE*4);
    int*      curR    = (int*)     alloc((size_t)NE*4);
    int*      fwd_src = (int*)     alloc((size_t)EP*4);
    int*      fwd_qid = (int*)     alloc((size_t)EP*4);
    int*      rev_dst = (int*)     alloc((size_t)EP*4);
    float*    inv     = (float*)   alloc((size_t)NE*4);
    unsigned* part    = (unsigned*)alloc((size_t)2*NB*4);

    if (off > ws_size) return;  // clean bail instead of OOB fault

    // WQKV (19.2 MB bf16) aliases eB: eB is first written by prop #1,
    // which launches only after all attention kernels complete.
    short* WQKV = (short*)eB;

    hipMemsetAsync(deg_p, 0, (size_t)NE*4, stream);
    hipMemsetAsync(cntF,  0, (size_t)NE*4, stream);
    hipMemsetAsync(cntR,  0, (size_t)NE*4, stream);
    hipMemsetAsync(acc,   0, (size_t)3*B*128*4, stream);
    hipMemsetAsync(d_out, 0, (size_t)out_size*4, stream);

    // --- CSR build (parallel scan) ---------------------------------------
    count_edges_kernel<<<CDIV(EP, 256), 256, 0, stream>>>(pur_src, pur_dst, cntF, cntR, EP);
    count_profile_kernel<<<CDIV(NR, 256), 256, 0, stream>>>(profile_dst, deg_p, NR);
    scan_reduce_kernel<<<2*NB, 256, 0, stream>>>(cntF, cntR, part, NE, NB);
    scan_part_kernel<<<1, 1024, 0, stream>>>(part, NB);
    scan_final_kernel<<<2*NB, 256, 0, stream>>>(cntF, cntR, part,
        offF, curF, offR, curR, NE, NB);
    fill_csr_kernel<<<CDIV(EP, 256), 256, 0, stream>>>(pur_src, pur_dst, pur_qid,
        curF, curR, fwd_src, fwd_qid, rev_dst, EP);

    // --- attention (per-word QKV precompute + gather MFMA) ----------------
    prep_wqkv_kernel<<<CDIV(NW*64, 256), 256, 0, stream>>>(word_emb,
        Wq, bq, Wk, bk, Wv, bv, WQKV, NW);
    init_e_kernel<<<CDIV(NE*32, 256), 256, 0, stream>>>(eA, entity_emb, NE);
    attn_mfma<16,1><<<CDIV(NR*16, 256), 256, 0, stream>>>(WQKV, review_words,
        Wo, bo, NR, eA, profile_dst);
    attn_mfma<8,0><<<CDIV(NQ*8, 256), 256, 0, stream>>>(WQKV, query_words_graph,
        Wo, bo, NQ, q_h, nullptr);
    attn_mfma<8,0><<<CDIV(B*8, 256), 256, 0, stream>>>(WQKV, query_words,
        Wo, bo, B, qb, nullptr);

    finalize_kernel<<<CDIV(NE*32, 256), 256, 0, stream>>>(eA, inv, deg_p, cntF, cntR, NE);
    gather_acc_kernel<<<CDIV(3*B*32, 256), 256, 0, stream>>>(eA, users, items, negs, acc, B);

    // --- K=3 propagation, ping-pong eA/eB --------------------------------
    float* cur = eA; float* nxt = eB;
    for (int k = 0; k < 3; ++k) {
        prop_kernel<<<CDIV(NE*32, 256), 256, 0, stream>>>(cur, q_h, inv,
            offF, curF, fwd_src, fwd_qid, offR, curR, rev_dst, nxt, NE);
        gather_acc_kernel<<<CDIV(3*B*32, 256), 256, 0, stream>>>(nxt, users, items, negs, acc, B);
        float* tmp = cur; cur = nxt; nxt = tmp;
    }

    loss_kernel<<<B, 128, 0, stream>>>(acc, qb, (float*)d_out, B, 1.0f / (float)B);
}

// Round 6
// 935.833 us; speedup vs baseline: 7.5618x; 1.0860x over previous
//
#include <hip/hip_runtime.h>
#include <cstdint>

#define CDIV(a,b) (((a)+(b)-1)/(b))

typedef __attribute__((ext_vector_type(8))) short bf16x8;     // 8 bf16 = 4 VGPRs
typedef __attribute__((ext_vector_type(4))) float f32x4;      // MFMA accumulator
typedef __attribute__((ext_vector_type(4))) _Float16 half4;   // 8B fp16 vector

__device__ __forceinline__ float bf2f(short s) {
    return __builtin_bit_cast(float, ((unsigned)(unsigned short)s) << 16);
}
__device__ __forceinline__ short rtne(float f) {
    const unsigned u = __builtin_bit_cast(unsigned, f);
    return (short)((u + 0x7fffu + ((u >> 16) & 1u)) >> 16);
}

// ---------------------------------------------------------------------------
// WQKV[w][0:64]=x@Wq+bq, [64:128]=x@Wk+bk, [128:192]=x@Wv+bv as bf16 (RTNE).
// ---------------------------------------------------------------------------
__global__ __launch_bounds__(256) void prep_wqkv_kernel(
    const float* __restrict__ we,
    const float* __restrict__ Wq, const float* __restrict__ bq,
    const float* __restrict__ Wk, const float* __restrict__ bk,
    const float* __restrict__ Wv, const float* __restrict__ bv,
    short* __restrict__ WQKV, int NW)
{
    const int w = blockIdx.x*4 + (threadIdx.x >> 6);
    if (w >= NW) return;
    const int j = threadIdx.x & 63;
    float aq = bq[j], ak = bk[j], av = bv[j];
    if (w != 0) {
        const float* xr = we + (size_t)w*64;
        for (int d0 = 0; d0 < 64; d0 += 4) {
            const float x0 = xr[d0], x1 = xr[d0+1], x2 = xr[d0+2], x3 = xr[d0+3];
            aq += x0*Wq[(d0+0)*64+j] + x1*Wq[(d0+1)*64+j]
                + x2*Wq[(d0+2)*64+j] + x3*Wq[(d0+3)*64+j];
            ak += x0*Wk[(d0+0)*64+j] + x1*Wk[(d0+1)*64+j]
                + x2*Wk[(d0+2)*64+j] + x3*Wk[(d0+3)*64+j];
            av += x0*Wv[(d0+0)*64+j] + x1*Wv[(d0+1)*64+j]
                + x2*Wv[(d0+2)*64+j] + x3*Wv[(d0+3)*64+j];
        }
    }
    short* out = WQKV + (size_t)w*192;
    out[j] = rtne(aq); out[64+j] = rtne(ak); out[128+j] = rtne(av);
}

// ---------------------------------------------------------------------------
// Gather MFMA attention, BARRIER-FREE: all LDS regions are wave-private, so
// no __syncthreads anywhere — compiler lgkmcnt handles same-wave ordering and
// can hoist tile i+1 gathers over tile i compute (loop fully unrolled).
// ---------------------------------------------------------------------------
template<int L, int MODE>
__global__ __launch_bounds__(256) void attn_mfma(
    const short* __restrict__ WQKV, const int* __restrict__ words,
    const float* __restrict__ Wo, const float* __restrict__ bo,
    int N, float* __restrict__ outp, const int* __restrict__ sidx)
{
    constexpr int SPT = 16 / L;          // seqs per 16-token tile
    __shared__ short v_s[4][16*72];      // per-wave [tok][dh], stride 72
    __shared__ float pbar_s[4][64];      // per-wave [h*16+m]
    __shared__ float mo_s[4][SPT][64];   // per-wave mean-attn out per seq

    const int wave = threadIdx.x >> 6;
    const int lane = threadIdx.x & 63;
    const int quad = lane >> 4;
    const int lm   = lane & 15;
    const int tok_total = N * L;
    const float invL = 1.0f / (float)L;

    // preload all 4 tiles' word ids (coalesced)
    int wid[4];
    #pragma unroll
    for (int t = 0; t < 4; ++t) {
        int tg = (blockIdx.x*16 + wave*4 + t)*16 + lm;
        if (tg >= tok_total) tg = tok_total - 1;   // clamp; seq-guard below
        wid[t] = words[tg];
    }

    #pragma unroll
    for (int ti = 0; ti < 4; ++ti) {
        const int tile = blockIdx.x*16 + wave*4 + ti;
        const short* row = WQKV + (size_t)wid[ti] * 192;

        // V gather (full 128B row across 4 quads)
        const int4 v0 = *(const int4*)(row + 128 + quad*16);
        const int4 v1 = *(const int4*)(row + 128 + quad*16 + 8);
        // Q/K fragments (K=16 padded to 32: quads 2-3 zero)
        bf16x8 qf[4], kf[4];
        #pragma unroll
        for (int h = 0; h < 4; ++h) {
            if (quad < 2) {
                kf[h] = *(const bf16x8*)(row + 64 + h*16 + quad*8);
                qf[h] = *(const bf16x8*)(row +      h*16 + quad*8);
            } else {
                kf[h] = (bf16x8){0,0,0,0,0,0,0,0};
                qf[h] = (bf16x8){0,0,0,0,0,0,0,0};
            }
        }
        *(int4*)&v_s[wave][lm*72 + quad*16]     = v0;
        *(int4*)&v_s[wave][lm*72 + quad*16 + 8] = v1;

        // valid iff key-token seq (quad>>1) == query-token seq (lm>>3)
        const bool mvalid = (SPT == 1) ? true : ((quad >> 1) == ((lm >> 3) & 1));

        #pragma unroll
        for (int h = 0; h < 4; ++h) {
            // S^T[m=quad*4+r][l=lm] = sum_k K[m][k] Q[l][k]
            const f32x4 s4 = __builtin_amdgcn_mfma_f32_16x16x32_bf16(
                kf[h], qf[h], (f32x4){0.f,0.f,0.f,0.f}, 0, 0, 0);
            float sv0 = s4[0]*0.25f, sv1 = s4[1]*0.25f,
                  sv2 = s4[2]*0.25f, sv3 = s4[3]*0.25f;   // / sqrt(DH=16)
            if (!mvalid) { sv0 = sv1 = sv2 = sv3 = -3.0e38f; }
            float mx = fmaxf(fmaxf(sv0, sv1), fmaxf(sv2, sv3));
            mx = fmaxf(mx, __shfl_xor(mx, 16, 64));
            mx = fmaxf(mx, __shfl_xor(mx, 32, 64));
            float p0 = __expf(sv0-mx), p1 = __expf(sv1-mx),
                  p2 = __expf(sv2-mx), p3 = __expf(sv3-mx);
            float sm = p0+p1+p2+p3;
            sm += __shfl_xor(sm, 16, 64);
            sm += __shfl_xor(sm, 32, 64);
            const float rinv = __builtin_amdgcn_rcpf(sm);
            p0 *= rinv; p1 *= rinv; p2 *= rinv; p3 *= rinv;
            // pbar[m] = sum_l P^T[m][l]  (invalid entries are exactly 0)
            #pragma unroll
            for (int d = 1; d < 16; d <<= 1) {
                p0 += __shfl_xor(p0, d, 64);
                p1 += __shfl_xor(p1, d, 64);
                p2 += __shfl_xor(p2, d, 64);
                p3 += __shfl_xor(p3, d, 64);
            }
            if (lm == 0) {
                pbar_s[wave][h*16 + quad*4 + 0] = p0 * invL;
                pbar_s[wave][h*16 + quad*4 + 1] = p1 * invL;
                pbar_s[wave][h*16 + quad*4 + 2] = p2 * invL;
                pbar_s[wave][h*16 + quad*4 + 3] = p3 * invL;
            }
        }

        // o[dh=lane] = sum_m pbar[head(lane)*16+m] * V[m][lane]
        #pragma unroll
        for (int s = 0; s < SPT; ++s) {
            float o = 0.f;
            #pragma unroll
            for (int j2 = 0; j2 < L; ++j2) {
                const int m = s*L + j2;
                o += pbar_s[wave][quad*16 + m] * bf2f(v_s[wave][m*72 + lane]);
            }
            mo_s[wave][s][lane] = o;
        }

        // out[col=lane] = bo + sum_n mo[n] * Wo[n][lane]
        #pragma unroll
        for (int s = 0; s < SPT; ++s) {
            const int seq = tile*SPT + s;
            if (seq < N) {
                float res = bo[lane];
                #pragma unroll 8
                for (int n = 0; n < 64; ++n)
                    res += mo_s[wave][s][n] * Wo[n*64 + lane];
                if (MODE == 0) outp[(size_t)seq*64 + lane] = res;
                else atomicAdd(&outp[(size_t)sidx[seq]*128 + 64 + lane], res);
            }
        }
    }
}

// ---------------------------------------------------------------------------
__global__ __launch_bounds__(256) void init_e_kernel(
    float* __restrict__ e, const float* __restrict__ entity_emb, int NE)
{
    const int t = blockIdx.x*256 + threadIdx.x;
    const int v = t >> 5;
    if (v >= NE) return;
    const int c = (t & 31) * 4;
    float4 val;
    if (c < 64) val = *(const float4*)&entity_emb[(size_t)v*64 + c];
    else        val = make_float4(0.f, 0.f, 0.f, 0.f);
    *(float4*)&e[(size_t)v*128 + c] = val;
}

__global__ __launch_bounds__(256) void count_profile_kernel(
    const int* __restrict__ dst, unsigned* __restrict__ deg, int NR)
{
    const int t = blockIdx.x*256 + threadIdx.x;
    if (t < NR) atomicAdd(&deg[dst[t]], 1u);
}

__global__ __launch_bounds__(256) void count_edges_kernel(
    const int* __restrict__ src, const int* __restrict__ dst,
    unsigned* __restrict__ cntF, unsigned* __restrict__ cntR, int EP)
{
    const int t = blockIdx.x*256 + threadIdx.x;
    if (t < EP) { atomicAdd(&cntF[dst[t]], 1u); atomicAdd(&cntR[src[t]], 1u); }
}

// --- 3-phase parallel exclusive scan of cntF and cntR ----------------------
#define SCAN_CHUNK 2048

__global__ __launch_bounds__(256) void scan_reduce_kernel(
    const unsigned* __restrict__ cntF, const unsigned* __restrict__ cntR,
    unsigned* __restrict__ part, int n, int NB)
{
    const int arr = blockIdx.x / NB, b = blockIdx.x % NB;
    const unsigned* cnt = arr ? cntR : cntF;
    const int base = b * SCAN_CHUNK;
    unsigned s = 0;
    #pragma unroll
    for (int i = 0; i < 8; ++i) {
        const int idx = base + i*256 + threadIdx.x;
        if (idx < n) s += cnt[idx];
    }
    #pragma unroll
    for (int off = 1; off < 64; off <<= 1) s += __shfl_xor(s, off, 64);
    __shared__ unsigned wsum[4];
    if ((threadIdx.x & 63) == 0) wsum[threadIdx.x >> 6] = s;
    __syncthreads();
    if (threadIdx.x == 0) part[arr*NB + b] = wsum[0]+wsum[1]+wsum[2]+wsum[3];
}

__global__ __launch_bounds__(1024) void scan_part_kernel(
    unsigned* __restrict__ part, int NB)
{
    __shared__ unsigned a[1024], b2[1024];
    const int t = threadIdx.x;
    a[t]  = (t < NB) ? part[t]      : 0u;
    b2[t] = (t < NB) ? part[NB + t] : 0u;
    __syncthreads();
    for (int d = 1; d < 1024; d <<= 1) {
        const unsigned xa = (t >= d) ? a[t-d] : 0u;
        const unsigned xb = (t >= d) ? b2[t-d] : 0u;
        __syncthreads();
        a[t] += xa; b2[t] += xb;
        __syncthreads();
    }
    if (t < NB) {
        part[t]      = (t > 0) ? a[t-1]  : 0u;
        part[NB + t] = (t > 0) ? b2[t-1] : 0u;
    }
}

__global__ __launch_bounds__(256) void scan_final_kernel(
    const unsigned* __restrict__ cntF, const unsigned* __restrict__ cntR,
    const unsigned* __restrict__ part,
    int* __restrict__ offF, int* __restrict__ curF,
    int* __restrict__ offR, int* __restrict__ curR, int n, int NB)
{
    const int arr = blockIdx.x / NB, b = blockIdx.x % NB;
    const unsigned* cnt = arr ? cntR : cntF;
    int* off = arr ? offR : offF;
    int* cur = arr ? curR : curF;
    __shared__ unsigned v[SCAN_CHUNK];
    __shared__ unsigned tsum[256];
    const int base = b * SCAN_CHUNK;
    const int t = threadIdx.x;
    #pragma unroll
    for (int i = 0; i < 8; ++i) {
        const int idx = base + i*256 + t;
        v[i*256 + t] = (idx < n) ? cnt[idx] : 0u;
    }
    __syncthreads();
    unsigned s = 0;
    #pragma unroll
    for (int i = 0; i < 8; ++i) s += v[t*8 + i];
    tsum[t] = s;
    __syncthreads();
    for (int d = 1; d < 256; d <<= 1) {
        const unsigned x = (t >= d) ? tsum[t-d] : 0u;
        __syncthreads();
        tsum[t] += x;
        __syncthreads();
    }
    unsigned run = ((t > 0) ? tsum[t-1] : 0u) + part[arr*NB + b];
    #pragma unroll
    for (int i = 0; i < 8; ++i) {
        const int idx = base + t*8 + i;
        if (idx < n) { off[idx] = (int)run; cur[idx] = (int)run; run += v[t*8+i]; }
    }
}

__global__ __launch_bounds__(256) void fill_csr_kernel(
    const int* __restrict__ src, const int* __restrict__ dst,
    const int* __restrict__ qid,
    int* __restrict__ curF, int* __restrict__ curR,
    int* __restrict__ fwd_src, int* __restrict__ fwd_qid,
    int* __restrict__ rev_dst, int EP)
{
    const int t = blockIdx.x*256 + threadIdx.x;
    if (t >= EP) return;
    const int s = src[t], d = dst[t];
    const int pF = atomicAdd(&curF[d], 1);
    fwd_src[pF] = s;
    fwd_qid[pF] = qid[t];
    const int pR = atomicAdd(&curR[s], 1);
    rev_dst[pR] = d;
}

// e0 finalize + fp32 -> fp16 convert in one pass: e16 = [emb | prof/deg],
// inv = 1/sqrt(deg_i). eA is NOT written back (dead after this kernel).
__global__ __launch_bounds__(256) void finalize_conv_kernel(
    const float* __restrict__ eA, _Float16* __restrict__ e16,
    float* __restrict__ inv, const unsigned* __restrict__ deg_p,
    const unsigned* __restrict__ cntF, const unsigned* __restrict__ cntR, int NE)
{
    const int t = blockIdx.x*256 + threadIdx.x;
    const int v = t >> 5;
    if (v >= NE) return;
    const int c = (t & 31) * 4;
    const size_t o = (size_t)v*128 + c;
    float4 ev = *(const float4*)&eA[o];
    if (c >= 64) {
        const unsigned dp = deg_p[v];
        const float r = 1.0f / (float)(dp > 1u ? dp : 1u);
        ev.x *= r; ev.y *= r; ev.z *= r; ev.w *= r;
    }
    f32x4 f = {ev.x, ev.y, ev.z, ev.w};
    *(half4*)&e16[o] = __builtin_convertvector(f, half4);
    if (c == 0) {
        const unsigned di = cntF[v] + cntR[v];
        inv[v] = 1.0f / sqrtf((float)(di > 1u ? di : 1u));
    }
}

// qc[v] = sum_{i in F(v)} q_h[qid_i] * inv[src_i]   (upper-64 dims, fp16)
__global__ __launch_bounds__(256) void qconst_kernel(
    const float* __restrict__ q_h, const float* __restrict__ inv,
    const int* __restrict__ offF, const int* __restrict__ endF,
    const int* __restrict__ fwd_src, const int* __restrict__ fwd_qid,
    _Float16* __restrict__ qc, int NE)
{
    const int t = blockIdx.x*256 + threadIdx.x;
    const int v = t >> 4;
    if (v >= NE) return;
    const int c = (t & 15) * 4;
    f32x4 a = {0.f, 0.f, 0.f, 0.f};
    const int bF = offF[v], eF = endF[v];
    for (int i = bF; i < eF; ++i) {
        const float invs = inv[fwd_src[i]];
        const f32x4 qh = *(const f32x4*)&q_h[(size_t)fwd_qid[i]*64 + c];
        a += qh * invs;
    }
    *(half4*)&qc[(size_t)v*64 + c] = __builtin_convertvector(a, half4);
}

// acc[r] += e16[sel[r]] for the 3*B scoring rows (users|items|negs)
__global__ __launch_bounds__(256) void gather_acc_kernel(
    const _Float16* __restrict__ e16, const int* __restrict__ users,
    const int* __restrict__ items, const int* __restrict__ negs,
    float* __restrict__ acc, int B)
{
    const int t = blockIdx.x*256 + threadIdx.x;
    const int r = t >> 5;
    if (r >= 3*B) return;
    const int c = (t & 31) * 4;
    const int which = r / B, b = r - which*B;
    const int idx = (which == 0) ? users[b] : (which == 1) ? items[b] : negs[b];
    const half4 ev = *(const half4*)&e16[(size_t)idx*128 + c];
    const f32x4 f = __builtin_convertvector(ev, f32x4);
    float4 a = *(const float4*)&acc[(size_t)r*128 + c];
    a.x += f.x; a.y += f.y; a.z += f.z; a.w += f.w;
    *(float4*)&acc[(size_t)r*128 + c] = a;
}

// Fused propagate+combine, fp16 rows (256B), query term folded into qc.
// e_nxt[v] = inv[v]*( sum_F e[src] + sum_R e[dst]*inv[dst] + qc[v](upper) )
__global__ __launch_bounds__(256) void prop_kernel(
    const _Float16* __restrict__ e_cur, const _Float16* __restrict__ qc,
    const float* __restrict__ inv,
    const int* __restrict__ offF, const int* __restrict__ endF,
    const int* __restrict__ fwd_src,
    const int* __restrict__ offR, const int* __restrict__ endR,
    const int* __restrict__ rev_dst,
    _Float16* __restrict__ e_nxt, int NE)
{
    const int t = blockIdx.x*256 + threadIdx.x;
    const int v = t >> 5;
    if (v >= NE) return;
    const int c = (t & 31) * 4;
    f32x4 a = {0.f, 0.f, 0.f, 0.f};

    const int bF = offF[v], eF = endF[v];
    for (int i = bF; i < eF; ++i) {
        const half4 es = *(const half4*)&e_cur[(size_t)fwd_src[i]*128 + c];
        a += __builtin_convertvector(es, f32x4);
    }
    const int bR = offR[v], eR = endR[v];
    for (int i = bR; i < eR; ++i) {
        const int d = rev_dst[i];
        const half4 ed = *(const half4*)&e_cur[(size_t)d*128 + c];
        a += __builtin_convertvector(ed, f32x4) * inv[d];
    }
    if (c >= 64) {
        const half4 q = *(const half4*)&qc[(size_t)v*64 + (c - 64)];
        a += __builtin_convertvector(q, f32x4);
    }
    a *= inv[v];
    *(half4*)&e_nxt[(size_t)v*128 + c] = __builtin_convertvector(a, half4);
}

__global__ __launch_bounds__(128) void loss_kernel(
    const float* __restrict__ acc, const float* __restrict__ qb,
    float* __restrict__ out, int B, float invB)
{
    const int b = blockIdx.x, d = threadIdx.x;
    const float u = acc[(size_t)b*128 + d] * 0.25f;
    const float p = u + (d >= 64 ? qb[(size_t)b*64 + (d - 64)] : 0.f);
    const float ei = acc[(size_t)(B + b)*128 + d];
    const float en = acc[(size_t)(2*B + b)*128 + d];
    float x = p * (ei - en) * 0.25f;
    #pragma unroll
    for (int off = 1; off < 64; off <<= 1) x += __shfl_xor(x, off, 64);
    __shared__ float wred[2];
    if ((threadIdx.x & 63) == 0) wred[threadIdx.x >> 6] = x;
    __syncthreads();
    if (threadIdx.x == 0) {
        const float xx = wred[0] + wred[1];
        const float ls = fminf(xx, 0.f) - log1pf(expf(-fabsf(xx)));
        atomicAdd(out, -ls * invB);
    }
}

extern "C" void kernel_launch(void* const* d_in, const int* in_sizes, int n_in,
                              void* d_out, int out_size, void* d_ws, size_t ws_size,
                              hipStream_t stream)
{
    const float* word_emb        = (const float*)d_in[0];
    const float* entity_emb      = (const float*)d_in[1];
    const float* Wq = (const float*)d_in[2];  const float* bq = (const float*)d_in[3];
    const float* Wk = (const float*)d_in[4];  const float* bk = (const float*)d_in[5];
    const float* Wv = (const float*)d_in[6];  const float* bv = (const float*)d_in[7];
    const float* Wo = (const float*)d_in[8];  const float* bo = (const float*)d_in[9];
    const int* review_words      = (const int*)d_in[10];
    const int* query_words_graph = (const int*)d_in[11];
    const int* profile_dst       = (const int*)d_in[12];
    const int* pur_src           = (const int*)d_in[13];
    const int* pur_dst           = (const int*)d_in[14];
    const int* pur_qid           = (const int*)d_in[15];
    const int* users             = (const int*)d_in[16];
    const int* items             = (const int*)d_in[17];
    const int* negs              = (const int*)d_in[18];
    const int* query_words       = (const int*)d_in[19];

    const int NW = in_sizes[0]  / 64;
    const int NE = in_sizes[1]  / 64;
    const int NR = in_sizes[10] / 16;
    const int NQ = in_sizes[11] / 8;
    const int EP = in_sizes[13];
    const int B  = in_sizes[16];
    const int NB = CDIV(NE, SCAN_CHUNK);

    char* ws = (char*)d_ws;
    size_t off = 0;
    auto alloc = [&](size_t bytes) -> char* {
        char* q = ws + off; off += (bytes + 255) & ~(size_t)255; return q;
    };
    float*     eA      = (float*)    alloc((size_t)NE*128*4);  // fp32 e0 staging
    _Float16*  e16A    = (_Float16*) alloc((size_t)NE*128*2);  // fp16 ping
    _Float16*  e16B    = (_Float16*) alloc((size_t)NE*128*2);  // fp16 pong
    float*     q_h     = (float*)    alloc((size_t)NQ*64*4);
    float*     qb      = (float*)    alloc((size_t)B*64*4);
    float*     acc     = (float*)    alloc((size_t)3*B*128*4);
    unsigned*  deg_p   = (unsigned*) alloc((size_t)NE*4);
    unsigned*  cntF    = (unsigned*) alloc((size_t)NE*4);
    unsigned*  cntR    = (unsigned*) alloc((size_t)NE*4);
    int*       offF    = (int*)      alloc((size_t)NE*4);
    int*       offR    = (int*)      alloc((size_t)NE*4);
    int*       curF    = (int*)      alloc((size_t)NE*4);
    int*       curR    = (int*)      alloc((size_t)NE*4);
    int*       fwd_src = (int*)      alloc((size_t)EP*4);
    int*       fwd_qid = (int*)      alloc((size_t)EP*4);
    int*       rev_dst = (int*)      alloc((size_t)EP*4);
    float*     inv     = (float*)    alloc((size_t)NE*4);
    unsigned*  part    = (unsigned*) alloc((size_t)2*NB*4);

    if (off > ws_size) return;  // clean bail instead of OOB fault

    // Aliases (stream order makes each safe):
    // WQKV (19.2 MB) sits in e16A: attn reads it; finalize_conv writes e16A
    // only after all attn kernels completed.
    short* WQKV = (short*)e16A;
    // qc (25.6 MB) sits in eA: qconst writes it only after finalize_conv
    // (the last reader of eA) completed.
    _Float16* qc = (_Float16*)eA;

    hipMemsetAsync(deg_p, 0, (size_t)NE*4, stream);
    hipMemsetAsync(cntF,  0, (size_t)NE*4, stream);
    hipMemsetAsync(cntR,  0, (size_t)NE*4, stream);
    hipMemsetAsync(acc,   0, (size_t)3*B*128*4, stream);
    hipMemsetAsync(d_out, 0, (size_t)out_size*4, stream);

    // --- CSR build (parallel scan) ---------------------------------------
    count_edges_kernel<<<CDIV(EP, 256), 256, 0, stream>>>(pur_src, pur_dst, cntF, cntR, EP);
    count_profile_kernel<<<CDIV(NR, 256), 256, 0, stream>>>(profile_dst, deg_p, NR);
    scan_reduce_kernel<<<2*NB, 256, 0, stream>>>(cntF, cntR, part, NE, NB);
    scan_part_kernel<<<1, 1024, 0, stream>>>(part, NB);
    scan_final_kernel<<<2*NB, 256, 0, stream>>>(cntF, cntR, part,
        offF, curF, offR, curR, NE, NB);
    fill_csr_kernel<<<CDIV(EP, 256), 256, 0, stream>>>(pur_src, pur_dst, pur_qid,
        curF, curR, fwd_src, fwd_qid, rev_dst, EP);

    // --- attention (per-word QKV table + gather MFMA, barrier-free) -------
    prep_wqkv_kernel<<<CDIV(NW*64, 256), 256, 0, stream>>>(word_emb,
        Wq, bq, Wk, bk, Wv, bv, WQKV, NW);
    init_e_kernel<<<CDIV(NE*32, 256), 256, 0, stream>>>(eA, entity_emb, NE);
    attn_mfma<16,1><<<CDIV(NR*16, 256), 256, 0, stream>>>(WQKV, review_words,
        Wo, bo, NR, eA, profile_dst);
    attn_mfma<8,0><<<CDIV(NQ*8, 256), 256, 0, stream>>>(WQKV, query_words_graph,
        Wo, bo, NQ, q_h, nullptr);
    attn_mfma<8,0><<<CDIV(B*8, 256), 256, 0, stream>>>(WQKV, query_words,
        Wo, bo, B, qb, nullptr);

    // --- e0 -> fp16, inv; then iteration-invariant query term -------------
    finalize_conv_kernel<<<CDIV(NE*32, 256), 256, 0, stream>>>(eA, e16A, inv,
        deg_p, cntF, cntR, NE);
    qconst_kernel<<<CDIV(NE*16, 256), 256, 0, stream>>>(q_h, inv,
        offF, curF, fwd_src, fwd_qid, qc, NE);
    gather_acc_kernel<<<CDIV(3*B*32, 256), 256, 0, stream>>>(e16A, users, items, negs, acc, B);

    // --- K=3 propagation, ping-pong fp16 ----------------------------------
    _Float16* cur = e16A; _Float16* nxt = e16B;
    for (int k = 0; k < 3; ++k) {
        prop_kernel<<<CDIV(NE*32, 256), 256, 0, stream>>>(cur, qc, inv,
            offF, curF, fwd_src, offR, curR, rev_dst, nxt, NE);
        gather_acc_kernel<<<CDIV(3*B*32, 256), 256, 0, stream>>>(nxt, users, items, negs, acc, B);
        _Float16* tmp = cur; cur = nxt; nxt = tmp;
    }

    loss_kernel<<<B, 128, 0, stream>>>(acc, qb, (float*)d_out, B, 1.0f / (float)B);
}

// Round 7
// 792.243 us; speedup vs baseline: 8.9323x; 1.1812x over previous
//
#include <hip/hip_runtime.h>
#include <cstdint>

#define CDIV(a,b) (((a)+(b)-1)/(b))

typedef __attribute__((ext_vector_type(8))) short bf16x8;     // 8 bf16 = 4 VGPRs
typedef __attribute__((ext_vector_type(4))) float f32x4;      // MFMA accumulator
typedef __attribute__((ext_vector_type(8))) float f32x8;
typedef __attribute__((ext_vector_type(4))) _Float16 half4;
typedef __attribute__((ext_vector_type(8))) _Float16 half8;   // 16B fp16 vector

__device__ __forceinline__ float bf2f(short s) {
    return __builtin_bit_cast(float, ((unsigned)(unsigned short)s) << 16);
}
__device__ __forceinline__ short rtne(float f) {
    const unsigned u = __builtin_bit_cast(unsigned, f);
    return (short)((u + 0x7fffu + ((u >> 16) & 1u)) >> 16);
}
__device__ __forceinline__ unsigned pack2r(float lo, float hi) {
    return (unsigned)(unsigned short)rtne(lo) | ((unsigned)(unsigned short)rtne(hi) << 16);
}

// ---------------------------------------------------------------------------
// WQKV[w][0:64]=x@Wq+bq, [64:128]=x@Wk+bk, [128:192]=x@Wv+bv as bf16 (RTNE).
// ---------------------------------------------------------------------------
__global__ __launch_bounds__(256) void prep_wqkv_kernel(
    const float* __restrict__ we,
    const float* __restrict__ Wq, const float* __restrict__ bq,
    const float* __restrict__ Wk, const float* __restrict__ bk,
    const float* __restrict__ Wv, const float* __restrict__ bv,
    short* __restrict__ WQKV, int NW)
{
    const int w = blockIdx.x*4 + (threadIdx.x >> 6);
    if (w >= NW) return;
    const int j = threadIdx.x & 63;
    float aq = bq[j], ak = bk[j], av = bv[j];
    if (w != 0) {
        const float* xr = we + (size_t)w*64;
        for (int d0 = 0; d0 < 64; d0 += 4) {
            const float x0 = xr[d0], x1 = xr[d0+1], x2 = xr[d0+2], x3 = xr[d0+3];
            aq += x0*Wq[(d0+0)*64+j] + x1*Wq[(d0+1)*64+j]
                + x2*Wq[(d0+2)*64+j] + x3*Wq[(d0+3)*64+j];
            ak += x0*Wk[(d0+0)*64+j] + x1*Wk[(d0+1)*64+j]
                + x2*Wk[(d0+2)*64+j] + x3*Wk[(d0+3)*64+j];
            av += x0*Wv[(d0+0)*64+j] + x1*Wv[(d0+1)*64+j]
                + x2*Wv[(d0+2)*64+j] + x3*Wv[(d0+3)*64+j];
        }
    }
    short* out = WQKV + (size_t)w*192;
    out[j] = rtne(aq); out[64+j] = rtne(ak); out[128+j] = rtne(av);
}

// ---------------------------------------------------------------------------
// Gather MFMA attention. Tile phase is barrier-free (wave-private LDS); one
// block barrier before an MFMA epilogue that computes out = bo + mo@Wo for
// all the block's seqs at once (A = mo rows bf16 from LDS stride-68,
// B = WoT bf16 table).
// ---------------------------------------------------------------------------
template<int L, int MODE>
__global__ __launch_bounds__(256) void attn_mfma(
    const short* __restrict__ WQKV, const int* __restrict__ words,
    const short* __restrict__ WoT,   // [64][64] bf16: WoT[j][k] = Wo[k][j]
    const float* __restrict__ bo,
    int N, float* __restrict__ outp, const int* __restrict__ sidx)
{
    constexpr int SPT = 16 / L;          // seqs per 16-token tile
    constexpr int SB  = 16 * SPT;        // seqs per block
    __shared__ short v_s[4][16*72];      // per-wave [tok][dh], stride 72
    __shared__ float pbar_s[4][64];      // per-wave [h*16+m]
    __shared__ float mo_s[SB][68];       // mean-attn out; stride 68: aligned+2way

    const int wave = threadIdx.x >> 6;
    const int lane = threadIdx.x & 63;
    const int quad = lane >> 4;
    const int lm   = lane & 15;
    const int tok_total = N * L;
    const float invL = 1.0f / (float)L;

    // preload all 4 tiles' word ids (coalesced)
    int wid[4];
    #pragma unroll
    for (int t = 0; t < 4; ++t) {
        int tg = (blockIdx.x*16 + wave*4 + t)*16 + lm;
        if (tg >= tok_total) tg = tok_total - 1;   // clamp; store-guard below
        wid[t] = words[tg];
    }

    #pragma unroll
    for (int ti = 0; ti < 4; ++ti) {
        const short* row = WQKV + (size_t)wid[ti] * 192;

        // V gather (full 128B row across 4 quads)
        const int4 v0 = *(const int4*)(row + 128 + quad*16);
        const int4 v1 = *(const int4*)(row + 128 + quad*16 + 8);
        // Q/K fragments (K=16 padded to 32: quads 2-3 zero)
        bf16x8 qf[4], kf[4];
        #pragma unroll
        for (int h = 0; h < 4; ++h) {
            if (quad < 2) {
                kf[h] = *(const bf16x8*)(row + 64 + h*16 + quad*8);
                qf[h] = *(const bf16x8*)(row +      h*16 + quad*8);
            } else {
                kf[h] = (bf16x8){0,0,0,0,0,0,0,0};
                qf[h] = (bf16x8){0,0,0,0,0,0,0,0};
            }
        }
        *(int4*)&v_s[wave][lm*72 + quad*16]     = v0;
        *(int4*)&v_s[wave][lm*72 + quad*16 + 8] = v1;

        // valid iff key-token seq (quad>>1) == query-token seq (lm>>3)
        const bool mvalid = (SPT == 1) ? true : ((quad >> 1) == ((lm >> 3) & 1));

        #pragma unroll
        for (int h = 0; h < 4; ++h) {
            // S^T[m=quad*4+r][l=lm] = sum_k K[m][k] Q[l][k]
            const f32x4 s4 = __builtin_amdgcn_mfma_f32_16x16x32_bf16(
                kf[h], qf[h], (f32x4){0.f,0.f,0.f,0.f}, 0, 0, 0);
            float sv0 = s4[0]*0.25f, sv1 = s4[1]*0.25f,
                  sv2 = s4[2]*0.25f, sv3 = s4[3]*0.25f;   // / sqrt(DH=16)
            if (!mvalid) { sv0 = sv1 = sv2 = sv3 = -3.0e38f; }
            float mx = fmaxf(fmaxf(sv0, sv1), fmaxf(sv2, sv3));
            mx = fmaxf(mx, __shfl_xor(mx, 16, 64));
            mx = fmaxf(mx, __shfl_xor(mx, 32, 64));
            float p0 = __expf(sv0-mx), p1 = __expf(sv1-mx),
                  p2 = __expf(sv2-mx), p3 = __expf(sv3-mx);
            float sm = p0+p1+p2+p3;
            sm += __shfl_xor(sm, 16, 64);
            sm += __shfl_xor(sm, 32, 64);
            const float rinv = __builtin_amdgcn_rcpf(sm);
            p0 *= rinv; p1 *= rinv; p2 *= rinv; p3 *= rinv;
            // pbar[m] = sum_l P^T[m][l]  (invalid entries are exactly 0)
            #pragma unroll
            for (int d = 1; d < 16; d <<= 1) {
                p0 += __shfl_xor(p0, d, 64);
                p1 += __shfl_xor(p1, d, 64);
                p2 += __shfl_xor(p2, d, 64);
                p3 += __shfl_xor(p3, d, 64);
            }
            if (lm == 0) {
                pbar_s[wave][h*16 + quad*4 + 0] = p0 * invL;
                pbar_s[wave][h*16 + quad*4 + 1] = p1 * invL;
                pbar_s[wave][h*16 + quad*4 + 2] = p2 * invL;
                pbar_s[wave][h*16 + quad*4 + 3] = p3 * invL;
            }
        }

        // mo[dh=lane] = sum_m pbar[head(lane)*16+m] * V[m][lane]
        #pragma unroll
        for (int s = 0; s < SPT; ++s) {
            float o = 0.f;
            #pragma unroll
            for (int j2 = 0; j2 < L; ++j2) {
                const int m = s*L + j2;
                o += pbar_s[wave][quad*16 + m] * bf2f(v_s[wave][m*72 + lane]);
            }
            mo_s[(wave*4+ti)*SPT + s][lane] = o;
        }
    }
    __syncthreads();

    // --- epilogue: out[SB][64] = bo + mo@Wo via MFMA; wave owns 16 cols ----
    const int col = wave*16 + lm;
    const short* bT = WoT + col*64;
    const bf16x8 b0 = *(const bf16x8*)(bT + quad*8);
    const bf16x8 b1 = *(const bf16x8*)(bT + 32 + quad*8);
    const float boc = bo[col];
    #pragma unroll
    for (int rt = 0; rt < SPT; ++rt) {
        const float* ar = mo_s[rt*16 + lm];
        const float4 fA0 = *(const float4*)(ar + quad*8);
        const float4 fA1 = *(const float4*)(ar + quad*8 + 4);
        const float4 fA2 = *(const float4*)(ar + 32 + quad*8);
        const float4 fA3 = *(const float4*)(ar + 32 + quad*8 + 4);
        union { unsigned u[4]; bf16x8 v; } a0, a1;
        a0.u[0] = pack2r(fA0.x, fA0.y); a0.u[1] = pack2r(fA0.z, fA0.w);
        a0.u[2] = pack2r(fA1.x, fA1.y); a0.u[3] = pack2r(fA1.z, fA1.w);
        a1.u[0] = pack2r(fA2.x, fA2.y); a1.u[1] = pack2r(fA2.z, fA2.w);
        a1.u[2] = pack2r(fA3.x, fA3.y); a1.u[3] = pack2r(fA3.z, fA3.w);
        f32x4 c = {boc, boc, boc, boc};
        c = __builtin_amdgcn_mfma_f32_16x16x32_bf16(a0.v, b0, c, 0, 0, 0);
        c = __builtin_amdgcn_mfma_f32_16x16x32_bf16(a1.v, b1, c, 0, 0, 0);
        #pragma unroll
        for (int r = 0; r < 4; ++r) {
            const int seq = blockIdx.x*SB + rt*16 + quad*4 + r;
            if (seq < N) {
                if (MODE == 0) outp[(size_t)seq*64 + col] = c[r];
                else atomicAdd(&outp[(size_t)sidx[seq]*128 + 64 + col], c[r]);
            }
        }
    }
}

// ---------------------------------------------------------------------------
__global__ __launch_bounds__(256) void init_e_kernel(
    float* __restrict__ e, const float* __restrict__ entity_emb, int NE)
{
    const int t = blockIdx.x*256 + threadIdx.x;
    const int v = t >> 5;
    if (v >= NE) return;
    const int c = (t & 31) * 4;
    float4 val;
    if (c < 64) val = *(const float4*)&entity_emb[(size_t)v*64 + c];
    else        val = make_float4(0.f, 0.f, 0.f, 0.f);
    *(float4*)&e[(size_t)v*128 + c] = val;
}

// Fused: edge degree counts (t<EP), profile counts (t<NR), WoT build (t<4096)
__global__ __launch_bounds__(256) void misc_kernel(
    const int* __restrict__ src, const int* __restrict__ dst,
    unsigned* __restrict__ cntF, unsigned* __restrict__ cntR, int EP,
    const int* __restrict__ pdst, unsigned* __restrict__ deg_p, int NR,
    const float* __restrict__ Wo, short* __restrict__ WoT)
{
    const int t = blockIdx.x*256 + threadIdx.x;
    if (t < EP) { atomicAdd(&cntF[dst[t]], 1u); atomicAdd(&cntR[src[t]], 1u); }
    if (t < NR) atomicAdd(&deg_p[pdst[t]], 1u);
    if (t < 4096) {
        const int j = t >> 6, k = t & 63;
        WoT[j*64 + k] = rtne(Wo[k*64 + j]);
    }
}

// --- 3-phase parallel exclusive scan of cntF and cntR ----------------------
#define SCAN_CHUNK 2048

__global__ __launch_bounds__(256) void scan_reduce_kernel(
    const unsigned* __restrict__ cntF, const unsigned* __restrict__ cntR,
    unsigned* __restrict__ part, int n, int NB)
{
    const int arr = blockIdx.x / NB, b = blockIdx.x % NB;
    const unsigned* cnt = arr ? cntR : cntF;
    const int base = b * SCAN_CHUNK;
    unsigned s = 0;
    #pragma unroll
    for (int i = 0; i < 8; ++i) {
        const int idx = base + i*256 + threadIdx.x;
        if (idx < n) s += cnt[idx];
    }
    #pragma unroll
    for (int off = 1; off < 64; off <<= 1) s += __shfl_xor(s, off, 64);
    __shared__ unsigned wsum[4];
    if ((threadIdx.x & 63) == 0) wsum[threadIdx.x >> 6] = s;
    __syncthreads();
    if (threadIdx.x == 0) part[arr*NB + b] = wsum[0]+wsum[1]+wsum[2]+wsum[3];
}

__global__ __launch_bounds__(1024) void scan_part_kernel(
    unsigned* __restrict__ part, int NB)
{
    __shared__ unsigned a[1024], b2[1024];
    const int t = threadIdx.x;
    a[t]  = (t < NB) ? part[t]      : 0u;
    b2[t] = (t < NB) ? part[NB + t] : 0u;
    __syncthreads();
    for (int d = 1; d < 1024; d <<= 1) {
        const unsigned xa = (t >= d) ? a[t-d] : 0u;
        const unsigned xb = (t >= d) ? b2[t-d] : 0u;
        __syncthreads();
        a[t] += xa; b2[t] += xb;
        __syncthreads();
    }
    if (t < NB) {
        part[t]      = (t > 0) ? a[t-1]  : 0u;
        part[NB + t] = (t > 0) ? b2[t-1] : 0u;
    }
}

__global__ __launch_bounds__(256) void scan_final_kernel(
    const unsigned* __restrict__ cntF, const unsigned* __restrict__ cntR,
    const unsigned* __restrict__ part,
    int* __restrict__ offF, int* __restrict__ curF,
    int* __restrict__ offR, int* __restrict__ curR, int n, int NB)
{
    const int arr = blockIdx.x / NB, b = blockIdx.x % NB;
    const unsigned* cnt = arr ? cntR : cntF;
    int* off = arr ? offR : offF;
    int* cur = arr ? curR : curF;
    __shared__ unsigned v[SCAN_CHUNK];
    __shared__ unsigned tsum[256];
    const int base = b * SCAN_CHUNK;
    const int t = threadIdx.x;
    #pragma unroll
    for (int i = 0; i < 8; ++i) {
        const int idx = base + i*256 + t;
        v[i*256 + t] = (idx < n) ? cnt[idx] : 0u;
    }
    __syncthreads();
    unsigned s = 0;
    #pragma unroll
    for (int i = 0; i < 8; ++i) s += v[t*8 + i];
    tsum[t] = s;
    __syncthreads();
    for (int d = 1; d < 256; d <<= 1) {
        const unsigned x = (t >= d) ? tsum[t-d] : 0u;
        __syncthreads();
        tsum[t] += x;
        __syncthreads();
    }
    unsigned run = ((t > 0) ? tsum[t-1] : 0u) + part[arr*NB + b];
    #pragma unroll
    for (int i = 0; i < 8; ++i) {
        const int idx = base + t*8 + i;
        if (idx < n) { off[idx] = (int)run; cur[idx] = (int)run; run += v[t*8+i]; }
    }
}

__global__ __launch_bounds__(256) void fill_csr_kernel(
    const int* __restrict__ src, const int* __restrict__ dst,
    const int* __restrict__ qid,
    int* __restrict__ curF, int* __restrict__ curR,
    int* __restrict__ fwd_src, int* __restrict__ fwd_qid,
    int* __restrict__ rev_dst, int EP)
{
    const int t = blockIdx.x*256 + threadIdx.x;
    if (t >= EP) return;
    const int s = src[t], d = dst[t];
    const int pF = atomicAdd(&curF[d], 1);
    fwd_src[pF] = s;
    fwd_qid[pF] = qid[t];
    const int pR = atomicAdd(&curR[s], 1);
    rev_dst[pR] = d;
}

// e0 finalize + fp32 -> fp16 convert in one pass; inv = 1/sqrt(deg_i).
__global__ __launch_bounds__(256) void finalize_conv_kernel(
    const float* __restrict__ eA, _Float16* __restrict__ e16,
    float* __restrict__ inv, const unsigned* __restrict__ deg_p,
    const unsigned* __restrict__ cntF, const unsigned* __restrict__ cntR, int NE)
{
    const int t = blockIdx.x*256 + threadIdx.x;
    const int v = t >> 5;
    if (v >= NE) return;
    const int c = (t & 31) * 4;
    const size_t o = (size_t)v*128 + c;
    float4 ev = *(const float4*)&eA[o];
    if (c >= 64) {
        const unsigned dp = deg_p[v];
        const float r = 1.0f / (float)(dp > 1u ? dp : 1u);
        ev.x *= r; ev.y *= r; ev.z *= r; ev.w *= r;
    }
    f32x4 f = {ev.x, ev.y, ev.z, ev.w};
    *(half4*)&e16[o] = __builtin_convertvector(f, half4);
    if (c == 0) {
        const unsigned di = cntF[v] + cntR[v];
        inv[v] = 1.0f / sqrtf((float)(di > 1u ? di : 1u));
    }
}

// qc[v] = sum_{i in F(v)} q_h[qid_i] * inv[src_i]   (upper-64 dims, fp16)
__global__ __launch_bounds__(256) void qconst_kernel(
    const float* __restrict__ q_h, const float* __restrict__ inv,
    const int* __restrict__ offF, const int* __restrict__ endF,
    const int* __restrict__ fwd_src, const int* __restrict__ fwd_qid,
    _Float16* __restrict__ qc, int NE)
{
    const int t = blockIdx.x*256 + threadIdx.x;
    const int v = t >> 4;
    if (v >= NE) return;
    const int c = (t & 15) * 4;
    f32x4 a = {0.f, 0.f, 0.f, 0.f};
    const int bF = offF[v], eF = endF[v];
    for (int i = bF; i < eF; ++i) {
        const float invs = inv[fwd_src[i]];
        const f32x4 qh = *(const f32x4*)&q_h[(size_t)fwd_qid[i]*64 + c];
        a += qh * invs;
    }
    *(half4*)&qc[(size_t)v*64 + c] = __builtin_convertvector(a, half4);
}

// acc[r] += e16[sel[r]] for the 3*B scoring rows; 16 lanes x half8 per row
__global__ __launch_bounds__(256) void gather_acc_kernel(
    const _Float16* __restrict__ e16, const int* __restrict__ users,
    const int* __restrict__ items, const int* __restrict__ negs,
    float* __restrict__ acc, int B)
{
    const int t = blockIdx.x*256 + threadIdx.x;
    const int r = t >> 4;
    if (r >= 3*B) return;
    const int c = (t & 15) * 8;
    const int which = r / B, b = r - which*B;
    const int idx = (which == 0) ? users[b] : (which == 1) ? items[b] : negs[b];
    const half8 ev = *(const half8*)&e16[(size_t)idx*128 + c];
    const f32x8 f = __builtin_convertvector(ev, f32x8);
    f32x8 a = *(const f32x8*)&acc[(size_t)r*128 + c];
    a += f;
    *(f32x8*)&acc[(size_t)r*128 + c] = a;
}

// Fused propagate+combine; 16 lanes x half8 (16B) per 256B row.
// e_nxt[v] = inv[v]*( sum_F e[src] + sum_R e[dst]*inv[dst] + qc[v](upper) )
__global__ __launch_bounds__(256) void prop_kernel(
    const _Float16* __restrict__ e_cur, const _Float16* __restrict__ qc,
    const float* __restrict__ inv,
    const int* __restrict__ offF, const int* __restrict__ endF,
    const int* __restrict__ fwd_src,
    const int* __restrict__ offR, const int* __restrict__ endR,
    const int* __restrict__ rev_dst,
    _Float16* __restrict__ e_nxt, int NE)
{
    const int t = blockIdx.x*256 + threadIdx.x;
    const int v = t >> 4;
    if (v >= NE) return;
    const int c = (t & 15) * 8;
    f32x8 a = {0.f,0.f,0.f,0.f,0.f,0.f,0.f,0.f};

    const int bF = offF[v], eF = endF[v];
    for (int i = bF; i < eF; ++i) {
        const half8 es = *(const half8*)&e_cur[(size_t)fwd_src[i]*128 + c];
        a += __builtin_convertvector(es, f32x8);
    }
    const int bR = offR[v], eR = endR[v];
    for (int i = bR; i < eR; ++i) {
        const int d = rev_dst[i];
        const half8 ed = *(const half8*)&e_cur[(size_t)d*128 + c];
        a += __builtin_convertvector(ed, f32x8) * inv[d];
    }
    if (c >= 64) {
        const half8 q = *(const half8*)&qc[(size_t)v*64 + (c - 64)];
        a += __builtin_convertvector(q, f32x8);
    }
    a *= inv[v];
    *(half8*)&e_nxt[(size_t)v*128 + c] = __builtin_convertvector(a, half8);
}

__global__ __launch_bounds__(128) void loss_kernel(
    const float* __restrict__ acc, const float* __restrict__ qb,
    float* __restrict__ out, int B, float invB)
{
    const int b = blockIdx.x, d = threadIdx.x;
    const float u = acc[(size_t)b*128 + d] * 0.25f;
    const float p = u + (d >= 64 ? qb[(size_t)b*64 + (d - 64)] : 0.f);
    const float ei = acc[(size_t)(B + b)*128 + d];
    const float en = acc[(size_t)(2*B + b)*128 + d];
    float x = p * (ei - en) * 0.25f;
    #pragma unroll
    for (int off = 1; off < 64; off <<= 1) x += __shfl_xor(x, off, 64);
    __shared__ float wred[2];
    if ((threadIdx.x & 63) == 0) wred[threadIdx.x >> 6] = x;
    __syncthreads();
    if (threadIdx.x == 0) {
        const float xx = wred[0] + wred[1];
        const float ls = fminf(xx, 0.f) - log1pf(expf(-fabsf(xx)));
        atomicAdd(out, -ls * invB);
    }
}

extern "C" void kernel_launch(void* const* d_in, const int* in_sizes, int n_in,
                              void* d_out, int out_size, void* d_ws, size_t ws_size,
                              hipStream_t stream)
{
    const float* word_emb        = (const float*)d_in[0];
    const float* entity_emb      = (const float*)d_in[1];
    const float* Wq = (const float*)d_in[2];  const float* bq = (const float*)d_in[3];
    const float* Wk = (const float*)d_in[4];  const float* bk = (const float*)d_in[5];
    const float* Wv = (const float*)d_in[6];  const float* bv = (const float*)d_in[7];
    const float* Wo = (const float*)d_in[8];  const float* bo = (const float*)d_in[9];
    const int* review_words      = (const int*)d_in[10];
    const int* query_words_graph = (const int*)d_in[11];
    const int* profile_dst       = (const int*)d_in[12];
    const int* pur_src           = (const int*)d_in[13];
    const int* pur_dst           = (const int*)d_in[14];
    const int* pur_qid           = (const int*)d_in[15];
    const int* users             = (const int*)d_in[16];
    const int* items             = (const int*)d_in[17];
    const int* negs              = (const int*)d_in[18];
    const int* query_words       = (const int*)d_in[19];

    const int NW = in_sizes[0]  / 64;
    const int NE = in_sizes[1]  / 64;
    const int NR = in_sizes[10] / 16;
    const int NQ = in_sizes[11] / 8;
    const int EP = in_sizes[13];
    const int B  = in_sizes[16];
    const int NB = CDIV(NE, SCAN_CHUNK);

    char* ws = (char*)d_ws;
    size_t off = 0;
    auto alloc = [&](size_t bytes) -> char* {
        char* q = ws + off; off += (bytes + 255) & ~(size_t)255; return q;
    };
    float*     eA      = (float*)    alloc((size_t)NE*128*4);  // fp32 e0 staging
    _Float16*  e16A    = (_Float16*) alloc((size_t)NE*128*2);  // fp16 ping
    _Float16*  e16B    = (_Float16*) alloc((size_t)NE*128*2);  // fp16 pong
    float*     q_h     = (float*)    alloc((size_t)NQ*64*4);
    float*     qb      = (float*)    alloc((size_t)B*64*4);
    float*     acc     = (float*)    alloc((size_t)3*B*128*4);
    // deg_p/cntF/cntR contiguous (NE*4 is a 256 multiple) -> single memset
    unsigned*  deg_p   = (unsigned*) alloc((size_t)NE*4);
    unsigned*  cntF    = (unsigned*) alloc((size_t)NE*4);
    unsigned*  cntR    = (unsigned*) alloc((size_t)NE*4);
    int*       offF    = (int*)      alloc((size_t)NE*4);
    int*       offR    = (int*)      alloc((size_t)NE*4);
    int*       curF    = (int*)      alloc((size_t)NE*4);
    int*       curR    = (int*)      alloc((size_t)NE*4);
    int*       fwd_src = (int*)      alloc((size_t)EP*4);
    int*       fwd_qid = (int*)      alloc((size_t)EP*4);
    int*       rev_dst = (int*)      alloc((size_t)EP*4);
    float*     inv     = (float*)    alloc((size_t)NE*4);
    unsigned*  part    = (unsigned*) alloc((size_t)2*NB*4);
    short*     WoT     = (short*)    alloc((size_t)64*64*2);

    if (off > ws_size) return;  // clean bail instead of OOB fault

    // Aliases (stream order makes each safe):
    short* WQKV = (short*)e16A;          // attn reads; overwritten by finalize_conv
    _Float16* qc = (_Float16*)eA;        // written after finalize_conv read eA

    hipMemsetAsync(deg_p, 0, (size_t)3*NE*4, stream);   // deg_p+cntF+cntR
    hipMemsetAsync(acc,   0, (size_t)3*B*128*4, stream);
    hipMemsetAsync(d_out, 0, (size_t)out_size*4, stream);

    // --- CSR build (parallel scan) + WoT ---------------------------------
    misc_kernel<<<CDIV(EP, 256), 256, 0, stream>>>(pur_src, pur_dst, cntF, cntR, EP,
        profile_dst, deg_p, NR, Wo, WoT);
    scan_reduce_kernel<<<2*NB, 256, 0, stream>>>(cntF, cntR, part, NE, NB);
    scan_part_kernel<<<1, 1024, 0, stream>>>(part, NB);
    scan_final_kernel<<<2*NB, 256, 0, stream>>>(cntF, cntR, part,
        offF, curF, offR, curR, NE, NB);
    fill_csr_kernel<<<CDIV(EP, 256), 256, 0, stream>>>(pur_src, pur_dst, pur_qid,
        curF, curR, fwd_src, fwd_qid, rev_dst, EP);

    // --- attention (per-word QKV table + gather MFMA + MFMA epilogue) -----
    prep_wqkv_kernel<<<CDIV(NW*64, 256), 256, 0, stream>>>(word_emb,
        Wq, bq, Wk, bk, Wv, bv, WQKV, NW);
    init_e_kernel<<<CDIV(NE*32, 256), 256, 0, stream>>>(eA, entity_emb, NE);
    attn_mfma<16,1><<<CDIV(NR, 16), 256, 0, stream>>>(WQKV, review_words,
        WoT, bo, NR, eA, profile_dst);
    attn_mfma<8,0><<<CDIV(NQ, 32), 256, 0, stream>>>(WQKV, query_words_graph,
        WoT, bo, NQ, q_h, nullptr);
    attn_mfma<8,0><<<CDIV(B, 32), 256, 0, stream>>>(WQKV, query_words,
        WoT, bo, B, qb, nullptr);

    // --- e0 -> fp16, inv; then iteration-invariant query term -------------
    finalize_conv_kernel<<<CDIV(NE*32, 256), 256, 0, stream>>>(eA, e16A, inv,
        deg_p, cntF, cntR, NE);
    qconst_kernel<<<CDIV(NE*16, 256), 256, 0, stream>>>(q_h, inv,
        offF, curF, fwd_src, fwd_qid, qc, NE);
    gather_acc_kernel<<<CDIV(3*B*16, 256), 256, 0, stream>>>(e16A, users, items, negs, acc, B);

    // --- K=3 propagation, ping-pong fp16 ----------------------------------
    _Float16* cur = e16A; _Float16* nxt = e16B;
    for (int k = 0; k < 3; ++k) {
        prop_kernel<<<CDIV(NE*16, 256), 256, 0, stream>>>(cur, qc, inv,
            offF, curF, fwd_src, offR, curR, rev_dst, nxt, NE);
        gather_acc_kernel<<<CDIV(3*B*16, 256), 256, 0, stream>>>(nxt, users, items, negs, acc, B);
        _Float16* tmp = cur; cur = nxt; nxt = tmp;
    }

    loss_kernel<<<B, 128, 0, stream>>>(acc, qb, (float*)d_out, B, 1.0f / (float)B);
}

// Round 8
// 771.748 us; speedup vs baseline: 9.1695x; 1.0266x over previous
//
#include <hip/hip_runtime.h>
#include <cstdint>

#define CDIV(a,b) (((a)+(b)-1)/(b))

typedef __attribute__((ext_vector_type(8))) short bf16x8;     // 8 bf16 = 4 VGPRs
typedef __attribute__((ext_vector_type(4))) float f32x4;      // MFMA accumulator
typedef __attribute__((ext_vector_type(8))) float f32x8;
typedef __attribute__((ext_vector_type(4))) _Float16 half4;
typedef __attribute__((ext_vector_type(8))) _Float16 half8;   // 16B fp16 vector
typedef __attribute__((ext_vector_type(2))) _Float16 h16x2;   // packed fp16 pair

__device__ __forceinline__ float bf2f(short s) {
    return __builtin_bit_cast(float, ((unsigned)(unsigned short)s) << 16);
}
__device__ __forceinline__ short rtne(float f) {
    const unsigned u = __builtin_bit_cast(unsigned, f);
    return (short)((u + 0x7fffu + ((u >> 16) & 1u)) >> 16);
}
__device__ __forceinline__ unsigned pack2r(float lo, float hi) {
    return (unsigned)(unsigned short)rtne(lo) | ((unsigned)(unsigned short)rtne(hi) << 16);
}

// ---------------------------------------------------------------------------
// WQKV[w][0:64]=x@Wq+bq, [64:128]=x@Wk+bk, [128:192]=x@Wv+bv as bf16 (RTNE).
// ---------------------------------------------------------------------------
__global__ __launch_bounds__(256) void prep_wqkv_kernel(
    const float* __restrict__ we,
    const float* __restrict__ Wq, const float* __restrict__ bq,
    const float* __restrict__ Wk, const float* __restrict__ bk,
    const float* __restrict__ Wv, const float* __restrict__ bv,
    short* __restrict__ WQKV, int NW)
{
    const int w = blockIdx.x*4 + (threadIdx.x >> 6);
    if (w >= NW) return;
    const int j = threadIdx.x & 63;
    float aq = bq[j], ak = bk[j], av = bv[j];
    if (w != 0) {
        const float* xr = we + (size_t)w*64;
        for (int d0 = 0; d0 < 64; d0 += 4) {
            const float x0 = xr[d0], x1 = xr[d0+1], x2 = xr[d0+2], x3 = xr[d0+3];
            aq += x0*Wq[(d0+0)*64+j] + x1*Wq[(d0+1)*64+j]
                + x2*Wq[(d0+2)*64+j] + x3*Wq[(d0+3)*64+j];
            ak += x0*Wk[(d0+0)*64+j] + x1*Wk[(d0+1)*64+j]
                + x2*Wk[(d0+2)*64+j] + x3*Wk[(d0+3)*64+j];
            av += x0*Wv[(d0+0)*64+j] + x1*Wv[(d0+1)*64+j]
                + x2*Wv[(d0+2)*64+j] + x3*Wv[(d0+3)*64+j];
        }
    }
    short* out = WQKV + (size_t)w*192;
    out[j] = rtne(aq); out[64+j] = rtne(ak); out[128+j] = rtne(av);
}

// ---------------------------------------------------------------------------
// Gather MFMA attention. No max-subtraction (|s| <= ~0.1 by input scale, exp
// cannot overflow); pbar 16-lane butterfly in packed fp16 (v_pk_add_f16).
// MODE 0: fp32 rows. MODE 1: atomicAdd into prof[sidx*64+col].
// MODE 2: fp16 rows (for q_h).
// ---------------------------------------------------------------------------
template<int L, int MODE>
__global__ __launch_bounds__(256) void attn_mfma(
    const short* __restrict__ WQKV, const int* __restrict__ words,
    const short* __restrict__ WoT,   // [64][64] bf16: WoT[j][k] = Wo[k][j]
    const float* __restrict__ bo,
    int N, void* __restrict__ outp, const int* __restrict__ sidx)
{
    constexpr int SPT = 16 / L;          // seqs per 16-token tile
    constexpr int SB  = 16 * SPT;        // seqs per block
    __shared__ short v_s[4][16*72];      // per-wave [tok][dh], stride 72
    __shared__ float pbar_s[4][64];      // per-wave [h*16+m]
    __shared__ float mo_s[SB][68];       // mean-attn out; stride 68: aligned+2way

    const int wave = threadIdx.x >> 6;
    const int lane = threadIdx.x & 63;
    const int quad = lane >> 4;
    const int lm   = lane & 15;
    const int tok_total = N * L;
    const float invL = 1.0f / (float)L;

    // preload all 4 tiles' word ids (coalesced)
    int wid[4];
    #pragma unroll
    for (int t = 0; t < 4; ++t) {
        int tg = (blockIdx.x*16 + wave*4 + t)*16 + lm;
        if (tg >= tok_total) tg = tok_total - 1;   // clamp; store-guard below
        wid[t] = words[tg];
    }

    #pragma unroll
    for (int ti = 0; ti < 4; ++ti) {
        const short* row = WQKV + (size_t)wid[ti] * 192;

        // V gather (full 128B row across 4 quads)
        const int4 v0 = *(const int4*)(row + 128 + quad*16);
        const int4 v1 = *(const int4*)(row + 128 + quad*16 + 8);
        // Q/K fragments (K=16 padded to 32: quads 2-3 zero)
        bf16x8 qf[4], kf[4];
        #pragma unroll
        for (int h = 0; h < 4; ++h) {
            if (quad < 2) {
                kf[h] = *(const bf16x8*)(row + 64 + h*16 + quad*8);
                qf[h] = *(const bf16x8*)(row +      h*16 + quad*8);
            } else {
                kf[h] = (bf16x8){0,0,0,0,0,0,0,0};
                qf[h] = (bf16x8){0,0,0,0,0,0,0,0};
            }
        }
        *(int4*)&v_s[wave][lm*72 + quad*16]     = v0;
        *(int4*)&v_s[wave][lm*72 + quad*16 + 8] = v1;

        // valid iff key-token seq (quad>>1) == query-token seq (lm>>3)
        const bool mvalid = (SPT == 1) ? true : ((quad >> 1) == ((lm >> 3) & 1));

        #pragma unroll
        for (int h = 0; h < 4; ++h) {
            // S^T[m=quad*4+r][l=lm] = sum_k K[m][k] Q[l][k]
            const f32x4 s4 = __builtin_amdgcn_mfma_f32_16x16x32_bf16(
                kf[h], qf[h], (f32x4){0.f,0.f,0.f,0.f}, 0, 0, 0);
            float sv0 = s4[0]*0.25f, sv1 = s4[1]*0.25f,
                  sv2 = s4[2]*0.25f, sv3 = s4[3]*0.25f;   // / sqrt(DH=16)
            if (!mvalid) { sv0 = sv1 = sv2 = sv3 = -3.0e38f; }
            // no max-sub: |s| <= ~0.1 by construction, exp safe
            float p0 = __expf(sv0), p1 = __expf(sv1),
                  p2 = __expf(sv2), p3 = __expf(sv3);
            float sm = p0+p1+p2+p3;
            sm += __shfl_xor(sm, 16, 64);
            sm += __shfl_xor(sm, 32, 64);
            const float rinv = __builtin_amdgcn_rcpf(sm);
            p0 *= rinv; p1 *= rinv; p2 *= rinv; p3 *= rinv;
            // pbar[m] = sum_l P^T[m][l], packed fp16 butterfly over 16 lanes
            h16x2 a01 = {(_Float16)p0, (_Float16)p1};
            h16x2 a23 = {(_Float16)p2, (_Float16)p3};
            #pragma unroll
            for (int d = 1; d < 16; d <<= 1) {
                a01 += __builtin_bit_cast(h16x2, __shfl_xor(__builtin_bit_cast(int, a01), d, 64));
                a23 += __builtin_bit_cast(h16x2, __shfl_xor(__builtin_bit_cast(int, a23), d, 64));
            }
            if (lm == 0) {
                pbar_s[wave][h*16 + quad*4 + 0] = (float)a01.x * invL;
                pbar_s[wave][h*16 + quad*4 + 1] = (float)a01.y * invL;
                pbar_s[wave][h*16 + quad*4 + 2] = (float)a23.x * invL;
                pbar_s[wave][h*16 + quad*4 + 3] = (float)a23.y * invL;
            }
        }

        // mo[dh=lane] = sum_m pbar[head(lane)*16+m] * V[m][lane]
        #pragma unroll
        for (int s = 0; s < SPT; ++s) {
            float o = 0.f;
            #pragma unroll
            for (int j2 = 0; j2 < L; ++j2) {
                const int m = s*L + j2;
                o += pbar_s[wave][quad*16 + m] * bf2f(v_s[wave][m*72 + lane]);
            }
            mo_s[(wave*4+ti)*SPT + s][lane] = o;
        }
    }
    __syncthreads();

    // --- epilogue: out[SB][64] = bo + mo@Wo via MFMA; wave owns 16 cols ----
    const int col = wave*16 + lm;
    const short* bT = WoT + col*64;
    const bf16x8 b0 = *(const bf16x8*)(bT + quad*8);
    const bf16x8 b1 = *(const bf16x8*)(bT + 32 + quad*8);
    const float boc = bo[col];
    #pragma unroll
    for (int rt = 0; rt < SPT; ++rt) {
        const float* ar = mo_s[rt*16 + lm];
        const float4 fA0 = *(const float4*)(ar + quad*8);
        const float4 fA1 = *(const float4*)(ar + quad*8 + 4);
        const float4 fA2 = *(const float4*)(ar + 32 + quad*8);
        const float4 fA3 = *(const float4*)(ar + 32 + quad*8 + 4);
        union { unsigned u[4]; bf16x8 v; } a0, a1;
        a0.u[0] = pack2r(fA0.x, fA0.y); a0.u[1] = pack2r(fA0.z, fA0.w);
        a0.u[2] = pack2r(fA1.x, fA1.y); a0.u[3] = pack2r(fA1.z, fA1.w);
        a1.u[0] = pack2r(fA2.x, fA2.y); a1.u[1] = pack2r(fA2.z, fA2.w);
        a1.u[2] = pack2r(fA3.x, fA3.y); a1.u[3] = pack2r(fA3.z, fA3.w);
        f32x4 c = {boc, boc, boc, boc};
        c = __builtin_amdgcn_mfma_f32_16x16x32_bf16(a0.v, b0, c, 0, 0, 0);
        c = __builtin_amdgcn_mfma_f32_16x16x32_bf16(a1.v, b1, c, 0, 0, 0);
        #pragma unroll
        for (int r = 0; r < 4; ++r) {
            const int seq = blockIdx.x*SB + rt*16 + quad*4 + r;
            if (seq < N) {
                if (MODE == 0)
                    ((float*)outp)[(size_t)seq*64 + col] = c[r];
                else if (MODE == 1)
                    atomicAdd(&((float*)outp)[(size_t)sidx[seq]*64 + col], c[r]);
                else
                    ((_Float16*)outp)[(size_t)seq*64 + col] = (_Float16)c[r];
            }
        }
    }
}

// Fused: cntC/cntF counts (t<EP), profile counts (t<NR), WoT build (t<4096)
__global__ __launch_bounds__(256) void misc_kernel(
    const int* __restrict__ src, const int* __restrict__ dst,
    unsigned* __restrict__ cntC, unsigned* __restrict__ cntF, int EP,
    const int* __restrict__ pdst, unsigned* __restrict__ deg_p, int NR,
    const float* __restrict__ Wo, short* __restrict__ WoT)
{
    const int t = blockIdx.x*256 + threadIdx.x;
    if (t < EP) {
        const int s = src[t], d = dst[t];
        atomicAdd(&cntC[d], 1u); atomicAdd(&cntC[s], 1u);
        atomicAdd(&cntF[d], 1u);
    }
    if (t < NR) atomicAdd(&deg_p[pdst[t]], 1u);
    if (t < 4096) {
        const int j = t >> 6, k = t & 63;
        WoT[j*64 + k] = rtne(Wo[k*64 + j]);
    }
}

// --- 3-phase parallel exclusive scan of cntC and cntF ----------------------
#define SCAN_CHUNK 2048

__global__ __launch_bounds__(256) void scan_reduce_kernel(
    const unsigned* __restrict__ cntA, const unsigned* __restrict__ cntB,
    unsigned* __restrict__ part, int n, int NB)
{
    const int arr = blockIdx.x / NB, b = blockIdx.x % NB;
    const unsigned* cnt = arr ? cntB : cntA;
    const int base = b * SCAN_CHUNK;
    unsigned s = 0;
    #pragma unroll
    for (int i = 0; i < 8; ++i) {
        const int idx = base + i*256 + threadIdx.x;
        if (idx < n) s += cnt[idx];
    }
    #pragma unroll
    for (int off = 1; off < 64; off <<= 1) s += __shfl_xor(s, off, 64);
    __shared__ unsigned wsum[4];
    if ((threadIdx.x & 63) == 0) wsum[threadIdx.x >> 6] = s;
    __syncthreads();
    if (threadIdx.x == 0) part[arr*NB + b] = wsum[0]+wsum[1]+wsum[2]+wsum[3];
}

__global__ __launch_bounds__(1024) void scan_part_kernel(
    unsigned* __restrict__ part, int NB)
{
    __shared__ unsigned a[1024], b2[1024];
    const int t = threadIdx.x;
    a[t]  = (t < NB) ? part[t]      : 0u;
    b2[t] = (t < NB) ? part[NB + t] : 0u;
    __syncthreads();
    for (int d = 1; d < 1024; d <<= 1) {
        const unsigned xa = (t >= d) ? a[t-d] : 0u;
        const unsigned xb = (t >= d) ? b2[t-d] : 0u;
        __syncthreads();
        a[t] += xa; b2[t] += xb;
        __syncthreads();
    }
    if (t < NB) {
        part[t]      = (t > 0) ? a[t-1]  : 0u;
        part[NB + t] = (t > 0) ? b2[t-1] : 0u;
    }
}

__global__ __launch_bounds__(256) void scan_final_kernel(
    const unsigned* __restrict__ cntA, const unsigned* __restrict__ cntB,
    const unsigned* __restrict__ part,
    int* __restrict__ offA, int* __restrict__ curA,
    int* __restrict__ offB, int* __restrict__ curB, int n, int NB)
{
    const int arr = blockIdx.x / NB, b = blockIdx.x % NB;
    const unsigned* cnt = arr ? cntB : cntA;
    int* off = arr ? offB : offA;
    int* cur = arr ? curB : curA;
    __shared__ unsigned v[SCAN_CHUNK];
    __shared__ unsigned tsum[256];
    const int base = b * SCAN_CHUNK;
    const int t = threadIdx.x;
    #pragma unroll
    for (int i = 0; i < 8; ++i) {
        const int idx = base + i*256 + t;
        v[i*256 + t] = (idx < n) ? cnt[idx] : 0u;
    }
    __syncthreads();
    unsigned s = 0;
    #pragma unroll
    for (int i = 0; i < 8; ++i) s += v[t*8 + i];
    tsum[t] = s;
    __syncthreads();
    for (int d = 1; d < 256; d <<= 1) {
        const unsigned x = (t >= d) ? tsum[t-d] : 0u;
        __syncthreads();
        tsum[t] += x;
        __syncthreads();
    }
    unsigned run = ((t > 0) ? tsum[t-1] : 0u) + part[arr*NB + b];
    #pragma unroll
    for (int i = 0; i < 8; ++i) {
        const int idx = base + t*8 + i;
        if (idx < n) { off[idx] = (int)run; cur[idx] = (int)run; run += v[t*8+i]; }
    }
}

// Combined list: cmb[list of v] = u (forward, weight 1) or u|0x80000000
// (reverse, weight inv[u]). Plus (src,qid) pairs for qconst at curF.
__global__ __launch_bounds__(256) void fill_csr_kernel(
    const int* __restrict__ src, const int* __restrict__ dst,
    const int* __restrict__ qid,
    int* __restrict__ curC, int* __restrict__ curF,
    int* __restrict__ cmb, int* __restrict__ fsrc, int* __restrict__ fqid,
    int EP)
{
    const int t = blockIdx.x*256 + threadIdx.x;
    if (t >= EP) return;
    const int s = src[t], d = dst[t];
    cmb[atomicAdd(&curC[d], 1)] = s;
    cmb[atomicAdd(&curC[s], 1)] = d | (int)0x80000000;
    const int pF = atomicAdd(&curF[d], 1);
    fsrc[pF] = s; fqid[pF] = qid[t];
}

// e16[v] = [entity_emb[v] | prof[v]/max(deg_p,1)] fp16; inv = 1/sqrt(cntC)
__global__ __launch_bounds__(256) void finalize_conv_kernel(
    const float* __restrict__ emb, const float* __restrict__ prof,
    _Float16* __restrict__ e16, float* __restrict__ inv,
    const unsigned* __restrict__ deg_p, const unsigned* __restrict__ cntC, int NE)
{
    const int t = blockIdx.x*256 + threadIdx.x;
    const int v = t >> 5;
    if (v >= NE) return;
    const int c = (t & 31) * 4;
    float4 ev;
    if (c < 64) {
        ev = *(const float4*)&emb[(size_t)v*64 + c];
    } else {
        ev = *(const float4*)&prof[(size_t)v*64 + (c - 64)];
        const unsigned dp = deg_p[v];
        const float r = 1.0f / (float)(dp > 1u ? dp : 1u);
        ev.x *= r; ev.y *= r; ev.z *= r; ev.w *= r;
    }
    f32x4 f = {ev.x, ev.y, ev.z, ev.w};
    *(half4*)&e16[(size_t)v*128 + c] = __builtin_convertvector(f, half4);
    if (c == 0) {
        const unsigned di = cntC[v];
        inv[v] = 1.0f / sqrtf((float)(di > 1u ? di : 1u));
    }
}

// qc[v] = sum_{i in F(v)} q_h16[qid_i] * inv[src_i]  (fp16 in/out, 8 lanes/row)
__global__ __launch_bounds__(256) void qconst_kernel(
    const _Float16* __restrict__ q_h16, const float* __restrict__ inv,
    const int* __restrict__ offF, const int* __restrict__ endF,
    const int* __restrict__ fsrc, const int* __restrict__ fqid,
    _Float16* __restrict__ qc, int NE)
{
    const int t = blockIdx.x*256 + threadIdx.x;
    const int v = t >> 3;
    if (v >= NE) return;
    const int c = (t & 7) * 8;
    f32x8 a = {0.f,0.f,0.f,0.f,0.f,0.f,0.f,0.f};
    const int bF = offF[v], eF = endF[v];
    for (int i = bF; i < eF; ++i) {
        const float invs = inv[fsrc[i]];
        const half8 qh = *(const half8*)&q_h16[(size_t)fqid[i]*64 + c];
        a += __builtin_convertvector(qh, f32x8) * invs;
    }
    *(half8*)&qc[(size_t)v*64 + c] = __builtin_convertvector(a, half8);
}

// acc[r] += e16[sel[r]] for the 3*B scoring rows; 16 lanes x half8 per row
__global__ __launch_bounds__(256) void gather_acc_kernel(
    const _Float16* __restrict__ e16, const int* __restrict__ users,
    const int* __restrict__ items, const int* __restrict__ negs,
    float* __restrict__ acc, int B)
{
    const int t = blockIdx.x*256 + threadIdx.x;
    const int r = t >> 4;
    if (r >= 3*B) return;
    const int c = (t & 15) * 8;
    const int which = r / B, b = r - which*B;
    const int idx = (which == 0) ? users[b] : (which == 1) ? items[b] : negs[b];
    const half8 ev = *(const half8*)&e16[(size_t)idx*128 + c];
    const f32x8 f = __builtin_convertvector(ev, f32x8);
    f32x8 a = *(const f32x8*)&acc[(size_t)r*128 + c];
    a += f;
    *(f32x8*)&acc[(size_t)r*128 + c] = a;
}

// Fused propagate+combine over the merged list; one-ahead index prefetch.
// e_nxt[v] = inv[v]*( sum_{cmb} e[u]*(flag?inv[u]:1) + qc[v](upper) )
__global__ __launch_bounds__(256) void prop_kernel(
    const _Float16* __restrict__ e_cur, const _Float16* __restrict__ qc,
    const float* __restrict__ inv,
    const int* __restrict__ offC, const int* __restrict__ endC,
    const int* __restrict__ cmb,
    _Float16* __restrict__ e_nxt, int NE)
{
    const int t = blockIdx.x*256 + threadIdx.x;
    const int v = t >> 4;
    if (v >= NE) return;
    const int c = (t & 15) * 8;
    f32x8 a = {0.f,0.f,0.f,0.f,0.f,0.f,0.f,0.f};
    if (c >= 64) {
        const half8 q = *(const half8*)&qc[(size_t)v*64 + (c - 64)];
        a = __builtin_convertvector(q, f32x8);
    }
    const int b0 = offC[v], e0 = endC[v];
    int un = (b0 < e0) ? cmb[b0] : 0;
    for (int i = b0; i < e0; ++i) {
        const int uc = un;
        if (i + 1 < e0) un = cmb[i + 1];
        const int u = uc & 0x7fffffff;
        const half8 es = *(const half8*)&e_cur[(size_t)u*128 + c];
        const float w = (uc < 0) ? inv[u] : 1.0f;
        a += __builtin_convertvector(es, f32x8) * w;
    }
    a *= inv[v];
    *(half8*)&e_nxt[(size_t)v*128 + c] = __builtin_convertvector(a, half8);
}

__global__ __launch_bounds__(128) void loss_kernel(
    const float* __restrict__ acc, const float* __restrict__ qb,
    float* __restrict__ out, int B, float invB)
{
    const int b = blockIdx.x, d = threadIdx.x;
    const float u = acc[(size_t)b*128 + d] * 0.25f;
    const float p = u + (d >= 64 ? qb[(size_t)b*64 + (d - 64)] : 0.f);
    const float ei = acc[(size_t)(B + b)*128 + d];
    const float en = acc[(size_t)(2*B + b)*128 + d];
    float x = p * (ei - en) * 0.25f;
    #pragma unroll
    for (int off = 1; off < 64; off <<= 1) x += __shfl_xor(x, off, 64);
    __shared__ float wred[2];
    if ((threadIdx.x & 63) == 0) wred[threadIdx.x >> 6] = x;
    __syncthreads();
    if (threadIdx.x == 0) {
        const float xx = wred[0] + wred[1];
        const float ls = fminf(xx, 0.f) - log1pf(expf(-fabsf(xx)));
        atomicAdd(out, -ls * invB);
    }
}

extern "C" void kernel_launch(void* const* d_in, const int* in_sizes, int n_in,
                              void* d_out, int out_size, void* d_ws, size_t ws_size,
                              hipStream_t stream)
{
    const float* word_emb        = (const float*)d_in[0];
    const float* entity_emb      = (const float*)d_in[1];
    const float* Wq = (const float*)d_in[2];  const float* bq = (const float*)d_in[3];
    const float* Wk = (const float*)d_in[4];  const float* bk = (const float*)d_in[5];
    const float* Wv = (const float*)d_in[6];  const float* bv = (const float*)d_in[7];
    const float* Wo = (const float*)d_in[8];  const float* bo = (const float*)d_in[9];
    const int* review_words      = (const int*)d_in[10];
    const int* query_words_graph = (const int*)d_in[11];
    const int* profile_dst       = (const int*)d_in[12];
    const int* pur_src           = (const int*)d_in[13];
    const int* pur_dst           = (const int*)d_in[14];
    const int* pur_qid           = (const int*)d_in[15];
    const int* users             = (const int*)d_in[16];
    const int* items             = (const int*)d_in[17];
    const int* negs              = (const int*)d_in[18];
    const int* query_words       = (const int*)d_in[19];

    const int NW = in_sizes[0]  / 64;
    const int NE = in_sizes[1]  / 64;
    const int NR = in_sizes[10] / 16;
    const int NQ = in_sizes[11] / 8;
    const int EP = in_sizes[13];
    const int B  = in_sizes[16];
    const int NB = CDIV(NE, SCAN_CHUNK);

    char* ws = (char*)d_ws;
    size_t off = 0;
    auto alloc = [&](size_t bytes) -> char* {
        char* q = ws + off; off += (bytes + 255) & ~(size_t)255; return q;
    };
    float*     prof    = (float*)    alloc((size_t)NE*64*4);   // review scatter
    _Float16*  e16A    = (_Float16*) alloc((size_t)NE*128*2);  // fp16 ping
    _Float16*  e16B    = (_Float16*) alloc((size_t)NE*128*2);  // fp16 pong
    _Float16*  q_h16   = (_Float16*) alloc((size_t)NQ*64*2);
    float*     qb      = (float*)    alloc((size_t)B*64*4);
    float*     acc     = (float*)    alloc((size_t)3*B*128*4);
    // deg_p/cntC/cntF contiguous (NE*4 multiple of 256) -> single memset
    unsigned*  deg_p   = (unsigned*) alloc((size_t)NE*4);
    unsigned*  cntC    = (unsigned*) alloc((size_t)NE*4);
    unsigned*  cntF    = (unsigned*) alloc((size_t)NE*4);
    int*       offC    = (int*)      alloc((size_t)NE*4);
    int*       offF    = (int*)      alloc((size_t)NE*4);
    int*       curC    = (int*)      alloc((size_t)NE*4);
    int*       curF    = (int*)      alloc((size_t)NE*4);
    int*       cmb     = (int*)      alloc((size_t)2*EP*4);
    int*       fsrc    = (int*)      alloc((size_t)EP*4);
    int*       fqid    = (int*)      alloc((size_t)EP*4);
    float*     inv     = (float*)    alloc((size_t)NE*4);
    unsigned*  part    = (unsigned*) alloc((size_t)2*NB*4);
    short*     WoT     = (short*)    alloc((size_t)64*64*2);

    if (off > ws_size) return;  // clean bail instead of OOB fault

    // Aliases (stream order makes each safe):
    short* WQKV = (short*)e16A;          // attn reads; overwritten by finalize_conv
    _Float16* qc = (_Float16*)prof;      // written after finalize_conv read prof

    hipMemsetAsync(deg_p, 0, (size_t)3*NE*4, stream);   // deg_p+cntC+cntF
    hipMemsetAsync(prof,  0, (size_t)NE*64*4, stream);
    hipMemsetAsync(acc,   0, (size_t)3*B*128*4, stream);
    hipMemsetAsync(d_out, 0, (size_t)out_size*4, stream);

    // --- CSR build (parallel scan) + WoT ---------------------------------
    misc_kernel<<<CDIV(EP, 256), 256, 0, stream>>>(pur_src, pur_dst, cntC, cntF, EP,
        profile_dst, deg_p, NR, Wo, WoT);
    scan_reduce_kernel<<<2*NB, 256, 0, stream>>>(cntC, cntF, part, NE, NB);
    scan_part_kernel<<<1, 1024, 0, stream>>>(part, NB);
    scan_final_kernel<<<2*NB, 256, 0, stream>>>(cntC, cntF, part,
        offC, curC, offF, curF, NE, NB);
    fill_csr_kernel<<<CDIV(EP, 256), 256, 0, stream>>>(pur_src, pur_dst, pur_qid,
        curC, curF, cmb, fsrc, fqid, EP);

    // --- attention (per-word QKV table + gather MFMA + MFMA epilogue) -----
    prep_wqkv_kernel<<<CDIV(NW*64, 256), 256, 0, stream>>>(word_emb,
        Wq, bq, Wk, bk, Wv, bv, WQKV, NW);
    attn_mfma<16,1><<<CDIV(NR, 16), 256, 0, stream>>>(WQKV, review_words,
        WoT, bo, NR, prof, profile_dst);
    attn_mfma<8,2><<<CDIV(NQ, 32), 256, 0, stream>>>(WQKV, query_words_graph,
        WoT, bo, NQ, q_h16, nullptr);
    attn_mfma<8,0><<<CDIV(B, 32), 256, 0, stream>>>(WQKV, query_words,
        WoT, bo, B, qb, nullptr);

    // --- e0 fp16 + inv; iteration-invariant query term --------------------
    finalize_conv_kernel<<<CDIV(NE*32, 256), 256, 0, stream>>>(entity_emb, prof,
        e16A, inv, deg_p, cntC, NE);
    qconst_kernel<<<CDIV(NE*8, 256), 256, 0, stream>>>(q_h16, inv,
        offF, curF, fsrc, fqid, qc, NE);
    gather_acc_kernel<<<CDIV(3*B*16, 256), 256, 0, stream>>>(e16A, users, items, negs, acc, B);

    // --- K=3 propagation, ping-pong fp16, merged edge list ----------------
    _Float16* cur = e16A; _Float16* nxt = e16B;
    for (int k = 0; k < 3; ++k) {
        prop_kernel<<<CDIV(NE*16, 256), 256, 0, stream>>>(cur, qc, inv,
            offC, curC, cmb, nxt, NE);
        gather_acc_kernel<<<CDIV(3*B*16, 256), 256, 0, stream>>>(nxt, users, items, negs, acc, B);
        _Float16* tmp = cur; cur = nxt; nxt = tmp;
    }

    loss_kernel<<<B, 128, 0, stream>>>(acc, qb, (float*)d_out, B, 1.0f / (float)B);
}

// Round 9
// 681.608 us; speedup vs baseline: 10.3822x; 1.1322x over previous
//
#include <hip/hip_runtime.h>
#include <cstdint>

#define CDIV(a,b) (((a)+(b)-1)/(b))

typedef __attribute__((ext_vector_type(8))) short bf16x8;     // 8 bf16 = 4 VGPRs
typedef __attribute__((ext_vector_type(4))) float f32x4;      // MFMA accumulator
typedef __attribute__((ext_vector_type(8))) float f32x8;
typedef __attribute__((ext_vector_type(4))) _Float16 half4;
typedef __attribute__((ext_vector_type(8))) _Float16 half8;   // 16B fp16 vector
typedef __attribute__((ext_vector_type(2))) _Float16 h16x2;   // packed fp16 pair

__device__ __forceinline__ float bf2f(short s) {
    return __builtin_bit_cast(float, ((unsigned)(unsigned short)s) << 16);
}
__device__ __forceinline__ short rtne(float f) {
    const unsigned u = __builtin_bit_cast(unsigned, f);
    return (short)((u + 0x7fffu + ((u >> 16) & 1u)) >> 16);
}
__device__ __forceinline__ unsigned pack2r(float lo, float hi) {
    return (unsigned)(unsigned short)rtne(lo) | ((unsigned)(unsigned short)rtne(hi) << 16);
}

// ---------------------------------------------------------------------------
// MFMA prep: WQKV[w][p*64+n] = x_w @ W_p + b_p  (bf16), x_0 = 0 (padding_idx).
// One wave holds all 24 B-frags (Wt bf16, built in misc_kernel) and does
// 4 tiles of 16 consecutive words; 24 MFMAs per tile, bias in C-init.
// ---------------------------------------------------------------------------
__global__ __launch_bounds__(256) void prep_wqkv_mfma(
    const float* __restrict__ we, const short* __restrict__ Wt,
    const float* __restrict__ bq, const float* __restrict__ bk,
    const float* __restrict__ bv, short* __restrict__ WQKV, int NW)
{
    const int wave = threadIdx.x >> 6;
    const int lane = threadIdx.x & 63;
    const int quad = lane >> 4;
    const int lm   = lane & 15;
    const int ntiles = CDIV(NW, 16);

    // B-frags: Wt[p][n][k]; frag n=lm, k=quad*8+j (+kh*32)
    bf16x8 bfr[3][4][2];
    #pragma unroll
    for (int p = 0; p < 3; ++p)
        #pragma unroll
        for (int nt = 0; nt < 4; ++nt)
            #pragma unroll
            for (int kh = 0; kh < 2; ++kh)
                bfr[p][nt][kh] = *(const bf16x8*)(Wt + ((p*64 + nt*16 + lm)*64) + kh*32 + quad*8);
    float bias[3][4];
    #pragma unroll
    for (int nt = 0; nt < 4; ++nt) {
        bias[0][nt] = bq[nt*16 + lm];
        bias[1][nt] = bk[nt*16 + lm];
        bias[2][nt] = bv[nt*16 + lm];
    }

    #pragma unroll
    for (int t = 0; t < 4; ++t) {
        const int tile = (blockIdx.x*4 + wave)*4 + t;
        if (tile >= ntiles) return;
        const int wb = tile*16;
        int w = wb + lm;
        if (w >= NW) w = NW - 1;
        const float* xr = we + (size_t)w*64;
        union { unsigned u[4]; bf16x8 v; } a0, a1;
        const float4 f0 = *(const float4*)(xr + quad*8);
        const float4 f1 = *(const float4*)(xr + quad*8 + 4);
        const float4 f2 = *(const float4*)(xr + 32 + quad*8);
        const float4 f3 = *(const float4*)(xr + 32 + quad*8 + 4);
        a0.u[0] = pack2r(f0.x, f0.y); a0.u[1] = pack2r(f0.z, f0.w);
        a0.u[2] = pack2r(f1.x, f1.y); a0.u[3] = pack2r(f1.z, f1.w);
        a1.u[0] = pack2r(f2.x, f2.y); a1.u[1] = pack2r(f2.z, f2.w);
        a1.u[2] = pack2r(f3.x, f3.y); a1.u[3] = pack2r(f3.z, f3.w);
        if (w == 0) {   // padding row -> x = 0 (output = bias)
            a0.u[0]=0u; a0.u[1]=0u; a0.u[2]=0u; a0.u[3]=0u;
            a1.u[0]=0u; a1.u[1]=0u; a1.u[2]=0u; a1.u[3]=0u;
        }
        #pragma unroll
        for (int p = 0; p < 3; ++p) {
            #pragma unroll
            for (int nt = 0; nt < 4; ++nt) {
                f32x4 c = {bias[p][nt], bias[p][nt], bias[p][nt], bias[p][nt]};
                c = __builtin_amdgcn_mfma_f32_16x16x32_bf16(a0.v, bfr[p][nt][0], c, 0, 0, 0);
                c = __builtin_amdgcn_mfma_f32_16x16x32_bf16(a1.v, bfr[p][nt][1], c, 0, 0, 0);
                #pragma unroll
                for (int r = 0; r < 4; ++r) {
                    const int w2 = wb + quad*4 + r;
                    if (w2 < NW)
                        WQKV[(size_t)w2*192 + p*64 + nt*16 + lm] = rtne(c[r]);
                }
            }
        }
    }
}

// ---------------------------------------------------------------------------
// Gather MFMA attention. No max-subtraction (|s| <= ~0.1 by input scale, exp
// cannot overflow); pbar 16-lane butterfly in packed fp16 (v_pk_add_f16).
// MODE 0: fp32 rows. MODE 1: atomicAdd into prof[sidx*64+col].
// MODE 2: fp16 rows (for q_h).
// ---------------------------------------------------------------------------
template<int L, int MODE>
__global__ __launch_bounds__(256) void attn_mfma(
    const short* __restrict__ WQKV, const int* __restrict__ words,
    const short* __restrict__ WoT,   // [64][64] bf16: WoT[j][k] = Wo[k][j]
    const float* __restrict__ bo,
    int N, void* __restrict__ outp, const int* __restrict__ sidx)
{
    constexpr int SPT = 16 / L;          // seqs per 16-token tile
    constexpr int SB  = 16 * SPT;        // seqs per block
    __shared__ short v_s[4][16*72];      // per-wave [tok][dh], stride 72
    __shared__ float pbar_s[4][64];      // per-wave [h*16+m]
    __shared__ float mo_s[SB][68];       // mean-attn out; stride 68: aligned+2way

    const int wave = threadIdx.x >> 6;
    const int lane = threadIdx.x & 63;
    const int quad = lane >> 4;
    const int lm   = lane & 15;
    const int tok_total = N * L;
    const float invL = 1.0f / (float)L;

    // preload all 4 tiles' word ids (coalesced)
    int wid[4];
    #pragma unroll
    for (int t = 0; t < 4; ++t) {
        int tg = (blockIdx.x*16 + wave*4 + t)*16 + lm;
        if (tg >= tok_total) tg = tok_total - 1;   // clamp; store-guard below
        wid[t] = words[tg];
    }

    #pragma unroll
    for (int ti = 0; ti < 4; ++ti) {
        const short* row = WQKV + (size_t)wid[ti] * 192;

        // V gather (full 128B row across 4 quads)
        const int4 v0 = *(const int4*)(row + 128 + quad*16);
        const int4 v1 = *(const int4*)(row + 128 + quad*16 + 8);
        // Q/K fragments (K=16 padded to 32: quads 2-3 zero)
        bf16x8 qf[4], kf[4];
        #pragma unroll
        for (int h = 0; h < 4; ++h) {
            if (quad < 2) {
                kf[h] = *(const bf16x8*)(row + 64 + h*16 + quad*8);
                qf[h] = *(const bf16x8*)(row +      h*16 + quad*8);
            } else {
                kf[h] = (bf16x8){0,0,0,0,0,0,0,0};
                qf[h] = (bf16x8){0,0,0,0,0,0,0,0};
            }
        }
        *(int4*)&v_s[wave][lm*72 + quad*16]     = v0;
        *(int4*)&v_s[wave][lm*72 + quad*16 + 8] = v1;

        // valid iff key-token seq (quad>>1) == query-token seq (lm>>3)
        const bool mvalid = (SPT == 1) ? true : ((quad >> 1) == ((lm >> 3) & 1));

        #pragma unroll
        for (int h = 0; h < 4; ++h) {
            // S^T[m=quad*4+r][l=lm] = sum_k K[m][k] Q[l][k]
            const f32x4 s4 = __builtin_amdgcn_mfma_f32_16x16x32_bf16(
                kf[h], qf[h], (f32x4){0.f,0.f,0.f,0.f}, 0, 0, 0);
            float sv0 = s4[0]*0.25f, sv1 = s4[1]*0.25f,
                  sv2 = s4[2]*0.25f, sv3 = s4[3]*0.25f;   // / sqrt(DH=16)
            if (!mvalid) { sv0 = sv1 = sv2 = sv3 = -3.0e38f; }
            // no max-sub: |s| <= ~0.1 by construction, exp safe
            float p0 = __expf(sv0), p1 = __expf(sv1),
                  p2 = __expf(sv2), p3 = __expf(sv3);
            float sm = p0+p1+p2+p3;
            sm += __shfl_xor(sm, 16, 64);
            sm += __shfl_xor(sm, 32, 64);
            const float rinv = __builtin_amdgcn_rcpf(sm);
            p0 *= rinv; p1 *= rinv; p2 *= rinv; p3 *= rinv;
            // pbar[m] = sum_l P^T[m][l], packed fp16 butterfly over 16 lanes
            h16x2 a01 = {(_Float16)p0, (_Float16)p1};
            h16x2 a23 = {(_Float16)p2, (_Float16)p3};
            #pragma unroll
            for (int d = 1; d < 16; d <<= 1) {
                a01 += __builtin_bit_cast(h16x2, __shfl_xor(__builtin_bit_cast(int, a01), d, 64));
                a23 += __builtin_bit_cast(h16x2, __shfl_xor(__builtin_bit_cast(int, a23), d, 64));
            }
            if (lm == 0) {
                pbar_s[wave][h*16 + quad*4 + 0] = (float)a01.x * invL;
                pbar_s[wave][h*16 + quad*4 + 1] = (float)a01.y * invL;
                pbar_s[wave][h*16 + quad*4 + 2] = (float)a23.x * invL;
                pbar_s[wave][h*16 + quad*4 + 3] = (float)a23.y * invL;
            }
        }

        // mo[dh=lane] = sum_m pbar[head(lane)*16+m] * V[m][lane]
        #pragma unroll
        for (int s = 0; s < SPT; ++s) {
            float o = 0.f;
            #pragma unroll
            for (int j2 = 0; j2 < L; ++j2) {
                const int m = s*L + j2;
                o += pbar_s[wave][quad*16 + m] * bf2f(v_s[wave][m*72 + lane]);
            }
            mo_s[(wave*4+ti)*SPT + s][lane] = o;
        }
    }
    __syncthreads();

    // --- epilogue: out[SB][64] = bo + mo@Wo via MFMA; wave owns 16 cols ----
    const int col = wave*16 + lm;
    const short* bT = WoT + col*64;
    const bf16x8 b0 = *(const bf16x8*)(bT + quad*8);
    const bf16x8 b1 = *(const bf16x8*)(bT + 32 + quad*8);
    const float boc = bo[col];
    #pragma unroll
    for (int rt = 0; rt < SPT; ++rt) {
        const float* ar = mo_s[rt*16 + lm];
        const float4 fA0 = *(const float4*)(ar + quad*8);
        const float4 fA1 = *(const float4*)(ar + quad*8 + 4);
        const float4 fA2 = *(const float4*)(ar + 32 + quad*8);
        const float4 fA3 = *(const float4*)(ar + 32 + quad*8 + 4);
        union { unsigned u[4]; bf16x8 v; } a0, a1;
        a0.u[0] = pack2r(fA0.x, fA0.y); a0.u[1] = pack2r(fA0.z, fA0.w);
        a0.u[2] = pack2r(fA1.x, fA1.y); a0.u[3] = pack2r(fA1.z, fA1.w);
        a1.u[0] = pack2r(fA2.x, fA2.y); a1.u[1] = pack2r(fA2.z, fA2.w);
        a1.u[2] = pack2r(fA3.x, fA3.y); a1.u[3] = pack2r(fA3.z, fA3.w);
        f32x4 c = {boc, boc, boc, boc};
        c = __builtin_amdgcn_mfma_f32_16x16x32_bf16(a0.v, b0, c, 0, 0, 0);
        c = __builtin_amdgcn_mfma_f32_16x16x32_bf16(a1.v, b1, c, 0, 0, 0);
        #pragma unroll
        for (int r = 0; r < 4; ++r) {
            const int seq = blockIdx.x*SB + rt*16 + quad*4 + r;
            if (seq < N) {
                if (MODE == 0)
                    ((float*)outp)[(size_t)seq*64 + col] = c[r];
                else if (MODE == 1)
                    atomicAdd(&((float*)outp)[(size_t)sidx[seq]*64 + col], c[r]);
                else
                    ((_Float16*)outp)[(size_t)seq*64 + col] = (_Float16)c[r];
            }
        }
    }
}

// Fused: cntC/cntF counts (t<EP), profile counts (t<NR), WoT+Wt builds
__global__ __launch_bounds__(256) void misc_kernel(
    const int* __restrict__ src, const int* __restrict__ dst,
    unsigned* __restrict__ cntC, unsigned* __restrict__ cntF, int EP,
    const int* __restrict__ pdst, unsigned* __restrict__ deg_p, int NR,
    const float* __restrict__ Wo, short* __restrict__ WoT,
    const float* __restrict__ Wq, const float* __restrict__ Wk,
    const float* __restrict__ Wv, short* __restrict__ Wt)
{
    const int t = blockIdx.x*256 + threadIdx.x;
    if (t < EP) {
        const int s = src[t], d = dst[t];
        atomicAdd(&cntC[d], 1u); atomicAdd(&cntC[s], 1u);
        atomicAdd(&cntF[d], 1u);
    }
    if (t < NR) atomicAdd(&deg_p[pdst[t]], 1u);
    if (t < 4096) {
        const int j = t >> 6, k = t & 63;
        WoT[j*64 + k] = rtne(Wo[k*64 + j]);
    }
    if (t < 3*4096) {
        const int p = t >> 12, n = (t >> 6) & 63, k = t & 63;
        const float* W = (p==0) ? Wq : (p==1) ? Wk : Wv;
        Wt[t] = rtne(W[k*64 + n]);
    }
}

// --- 3-phase parallel exclusive scan of cntC and cntF ----------------------
#define SCAN_CHUNK 2048

__global__ __launch_bounds__(256) void scan_reduce_kernel(
    const unsigned* __restrict__ cntA, const unsigned* __restrict__ cntB,
    unsigned* __restrict__ part, int n, int NB)
{
    const int arr = blockIdx.x / NB, b = blockIdx.x % NB;
    const unsigned* cnt = arr ? cntB : cntA;
    const int base = b * SCAN_CHUNK;
    unsigned s = 0;
    #pragma unroll
    for (int i = 0; i < 8; ++i) {
        const int idx = base + i*256 + threadIdx.x;
        if (idx < n) s += cnt[idx];
    }
    #pragma unroll
    for (int off = 1; off < 64; off <<= 1) s += __shfl_xor(s, off, 64);
    __shared__ unsigned wsum[4];
    if ((threadIdx.x & 63) == 0) wsum[threadIdx.x >> 6] = s;
    __syncthreads();
    if (threadIdx.x == 0) part[arr*NB + b] = wsum[0]+wsum[1]+wsum[2]+wsum[3];
}

__global__ __launch_bounds__(1024) void scan_part_kernel(
    unsigned* __restrict__ part, int NB)
{
    __shared__ unsigned a[1024], b2[1024];
    const int t = threadIdx.x;
    a[t]  = (t < NB) ? part[t]      : 0u;
    b2[t] = (t < NB) ? part[NB + t] : 0u;
    __syncthreads();
    for (int d = 1; d < 1024; d <<= 1) {
        const unsigned xa = (t >= d) ? a[t-d] : 0u;
        const unsigned xb = (t >= d) ? b2[t-d] : 0u;
        __syncthreads();
        a[t] += xa; b2[t] += xb;
        __syncthreads();
    }
    if (t < NB) {
        part[t]      = (t > 0) ? a[t-1]  : 0u;
        part[NB + t] = (t > 0) ? b2[t-1] : 0u;
    }
}

__global__ __launch_bounds__(256) void scan_final_kernel(
    const unsigned* __restrict__ cntA, const unsigned* __restrict__ cntB,
    const unsigned* __restrict__ part,
    int* __restrict__ offA, int* __restrict__ curA,
    int* __restrict__ offB, int* __restrict__ curB, int n, int NB)
{
    const int arr = blockIdx.x / NB, b = blockIdx.x % NB;
    const unsigned* cnt = arr ? cntB : cntA;
    int* off = arr ? offB : offA;
    int* cur = arr ? curB : curA;
    __shared__ unsigned v[SCAN_CHUNK];
    __shared__ unsigned tsum[256];
    const int base = b * SCAN_CHUNK;
    const int t = threadIdx.x;
    #pragma unroll
    for (int i = 0; i < 8; ++i) {
        const int idx = base + i*256 + t;
        v[i*256 + t] = (idx < n) ? cnt[idx] : 0u;
    }
    __syncthreads();
    unsigned s = 0;
    #pragma unroll
    for (int i = 0; i < 8; ++i) s += v[t*8 + i];
    tsum[t] = s;
    __syncthreads();
    for (int d = 1; d < 256; d <<= 1) {
        const unsigned x = (t >= d) ? tsum[t-d] : 0u;
        __syncthreads();
        tsum[t] += x;
        __syncthreads();
    }
    unsigned run = ((t > 0) ? tsum[t-1] : 0u) + part[arr*NB + b];
    #pragma unroll
    for (int i = 0; i < 8; ++i) {
        const int idx = base + t*8 + i;
        if (idx < n) { off[idx] = (int)run; cur[idx] = (int)run; run += v[t*8+i]; }
    }
}

// Combined list: cmb[list of v] = u (forward, weight 1) or u|0x80000000
// (reverse, weight inv[u]). Plus (src,qid) pairs for qconst at curF.
__global__ __launch_bounds__(256) void fill_csr_kernel(
    const int* __restrict__ src, const int* __restrict__ dst,
    const int* __restrict__ qid,
    int* __restrict__ curC, int* __restrict__ curF,
    int* __restrict__ cmb, int* __restrict__ fsrc, int* __restrict__ fqid,
    int EP)
{
    const int t = blockIdx.x*256 + threadIdx.x;
    if (t >= EP) return;
    const int s = src[t], d = dst[t];
    cmb[atomicAdd(&curC[d], 1)] = s;
    cmb[atomicAdd(&curC[s], 1)] = d | (int)0x80000000;
    const int pF = atomicAdd(&curF[d], 1);
    fsrc[pF] = s; fqid[pF] = qid[t];
}

// e16[v] = [entity_emb[v] | prof[v]/max(deg_p,1)] fp16; inv = 1/sqrt(cntC)
__global__ __launch_bounds__(256) void finalize_conv_kernel(
    const float* __restrict__ emb, const float* __restrict__ prof,
    _Float16* __restrict__ e16, float* __restrict__ inv,
    const unsigned* __restrict__ deg_p, const unsigned* __restrict__ cntC, int NE)
{
    const int t = blockIdx.x*256 + threadIdx.x;
    const int v = t >> 5;
    if (v >= NE) return;
    const int c = (t & 31) * 4;
    float4 ev;
    if (c < 64) {
        ev = *(const float4*)&emb[(size_t)v*64 + c];
    } else {
        ev = *(const float4*)&prof[(size_t)v*64 + (c - 64)];
        const unsigned dp = deg_p[v];
        const float r = 1.0f / (float)(dp > 1u ? dp : 1u);
        ev.x *= r; ev.y *= r; ev.z *= r; ev.w *= r;
    }
    f32x4 f = {ev.x, ev.y, ev.z, ev.w};
    *(half4*)&e16[(size_t)v*128 + c] = __builtin_convertvector(f, half4);
    if (c == 0) {
        const unsigned di = cntC[v];
        inv[v] = 1.0f / sqrtf((float)(di > 1u ? di : 1u));
    }
}

// qc[v] = sum_{i in F(v)} q_h16[qid_i] * inv[src_i]  (fp16 in/out, 8 lanes/row)
__global__ __launch_bounds__(256) void qconst_kernel(
    const _Float16* __restrict__ q_h16, const float* __restrict__ inv,
    const int* __restrict__ offF, const int* __restrict__ endF,
    const int* __restrict__ fsrc, const int* __restrict__ fqid,
    _Float16* __restrict__ qc, int NE)
{
    const int t = blockIdx.x*256 + threadIdx.x;
    const int v = t >> 3;
    if (v >= NE) return;
    const int c = (t & 7) * 8;
    f32x8 a = {0.f,0.f,0.f,0.f,0.f,0.f,0.f,0.f};
    const int bF = offF[v], eF = endF[v];
    for (int i = bF; i < eF; ++i) {
        const float invs = inv[fsrc[i]];
        const half8 qh = *(const half8*)&q_h16[(size_t)fqid[i]*64 + c];
        a += __builtin_convertvector(qh, f32x8) * invs;
    }
    *(half8*)&qc[(size_t)v*64 + c] = __builtin_convertvector(a, half8);
}

// acc[r] += e16[sel[r]] for the 3*B scoring rows; 16 lanes x half8 per row
__global__ __launch_bounds__(256) void gather_acc_kernel(
    const _Float16* __restrict__ e16, const int* __restrict__ users,
    const int* __restrict__ items, const int* __restrict__ negs,
    float* __restrict__ acc, int B)
{
    const int t = blockIdx.x*256 + threadIdx.x;
    const int r = t >> 4;
    if (r >= 3*B) return;
    const int c = (t & 15) * 8;
    const int which = r / B, b = r - which*B;
    const int idx = (which == 0) ? users[b] : (which == 1) ? items[b] : negs[b];
    const half8 ev = *(const half8*)&e16[(size_t)idx*128 + c];
    const f32x8 f = __builtin_convertvector(ev, f32x8);
    f32x8 a = *(const f32x8*)&acc[(size_t)r*128 + c];
    a += f;
    *(f32x8*)&acc[(size_t)r*128 + c] = a;
}

// Fused propagate+combine over the merged list; one-ahead index prefetch.
// e_nxt[v] = inv[v]*( sum_{cmb} e[u]*(flag?inv[u]:1) + qc[v](upper) )
__global__ __launch_bounds__(256) void prop_kernel(
    const _Float16* __restrict__ e_cur, const _Float16* __restrict__ qc,
    const float* __restrict__ inv,
    const int* __restrict__ offC, const int* __restrict__ endC,
    const int* __restrict__ cmb,
    _Float16* __restrict__ e_nxt, int NE)
{
    const int t = blockIdx.x*256 + threadIdx.x;
    const int v = t >> 4;
    if (v >= NE) return;
    const int c = (t & 15) * 8;
    f32x8 a = {0.f,0.f,0.f,0.f,0.f,0.f,0.f,0.f};
    if (c >= 64) {
        const half8 q = *(const half8*)&qc[(size_t)v*64 + (c - 64)];
        a = __builtin_convertvector(q, f32x8);
    }
    const int b0 = offC[v], e0 = endC[v];
    int un = (b0 < e0) ? cmb[b0] : 0;
    for (int i = b0; i < e0; ++i) {
        const int uc = un;
        if (i + 1 < e0) un = cmb[i + 1];
        const int u = uc & 0x7fffffff;
        const half8 es = *(const half8*)&e_cur[(size_t)u*128 + c];
        const float w = (uc < 0) ? inv[u] : 1.0f;
        a += __builtin_convertvector(es, f32x8) * w;
    }
    a *= inv[v];
    *(half8*)&e_nxt[(size_t)v*128 + c] = __builtin_convertvector(a, half8);
}

__global__ __launch_bounds__(128) void loss_kernel(
    const float* __restrict__ acc, const float* __restrict__ qb,
    float* __restrict__ out, int B, float invB)
{
    const int b = blockIdx.x, d = threadIdx.x;
    const float u = acc[(size_t)b*128 + d] * 0.25f;
    const float p = u + (d >= 64 ? qb[(size_t)b*64 + (d - 64)] : 0.f);
    const float ei = acc[(size_t)(B + b)*128 + d];
    const float en = acc[(size_t)(2*B + b)*128 + d];
    float x = p * (ei - en) * 0.25f;
    #pragma unroll
    for (int off = 1; off < 64; off <<= 1) x += __shfl_xor(x, off, 64);
    __shared__ float wred[2];
    if ((threadIdx.x & 63) == 0) wred[threadIdx.x >> 6] = x;
    __syncthreads();
    if (threadIdx.x == 0) {
        const float xx = wred[0] + wred[1];
        const float ls = fminf(xx, 0.f) - log1pf(expf(-fabsf(xx)));
        atomicAdd(out, -ls * invB);
    }
}

extern "C" void kernel_launch(void* const* d_in, const int* in_sizes, int n_in,
                              void* d_out, int out_size, void* d_ws, size_t ws_size,
                              hipStream_t stream)
{
    const float* word_emb        = (const float*)d_in[0];
    const float* entity_emb      = (const float*)d_in[1];
    const float* Wq = (const float*)d_in[2];  const float* bq = (const float*)d_in[3];
    const float* Wk = (const float*)d_in[4];  const float* bk = (const float*)d_in[5];
    const float* Wv = (const float*)d_in[6];  const float* bv = (const float*)d_in[7];
    const float* Wo = (const float*)d_in[8];  const float* bo = (const float*)d_in[9];
    const int* review_words      = (const int*)d_in[10];
    const int* query_words_graph = (const int*)d_in[11];
    const int* profile_dst       = (const int*)d_in[12];
    const int* pur_src           = (const int*)d_in[13];
    const int* pur_dst           = (const int*)d_in[14];
    const int* pur_qid           = (const int*)d_in[15];
    const int* users             = (const int*)d_in[16];
    const int* items             = (const int*)d_in[17];
    const int* negs              = (const int*)d_in[18];
    const int* query_words       = (const int*)d_in[19];

    const int NW = in_sizes[0]  / 64;
    const int NE = in_sizes[1]  / 64;
    const int NR = in_sizes[10] / 16;
    const int NQ = in_sizes[11] / 8;
    const int EP = in_sizes[13];
    const int B  = in_sizes[16];
    const int NB = CDIV(NE, SCAN_CHUNK);

    char* ws = (char*)d_ws;
    size_t off = 0;
    auto alloc = [&](size_t bytes) -> char* {
        char* q = ws + off; off += (bytes + 255) & ~(size_t)255; return q;
    };
    float*     prof    = (float*)    alloc((size_t)NE*64*4);   // review scatter
    _Float16*  e16A    = (_Float16*) alloc((size_t)NE*128*2);  // fp16 ping
    _Float16*  e16B    = (_Float16*) alloc((size_t)NE*128*2);  // fp16 pong
    _Float16*  q_h16   = (_Float16*) alloc((size_t)NQ*64*2);
    float*     qb      = (float*)    alloc((size_t)B*64*4);
    float*     acc     = (float*)    alloc((size_t)3*B*128*4);
    // deg_p/cntC/cntF contiguous (NE*4 multiple of 256) -> single memset
    unsigned*  deg_p   = (unsigned*) alloc((size_t)NE*4);
    unsigned*  cntC    = (unsigned*) alloc((size_t)NE*4);
    unsigned*  cntF    = (unsigned*) alloc((size_t)NE*4);
    int*       offC    = (int*)      alloc((size_t)NE*4);
    int*       offF    = (int*)      alloc((size_t)NE*4);
    int*       curC    = (int*)      alloc((size_t)NE*4);
    int*       curF    = (int*)      alloc((size_t)NE*4);
    int*       cmb     = (int*)      alloc((size_t)2*EP*4);
    int*       fsrc    = (int*)      alloc((size_t)EP*4);
    int*       fqid    = (int*)      alloc((size_t)EP*4);
    float*     inv     = (float*)    alloc((size_t)NE*4);
    unsigned*  part    = (unsigned*) alloc((size_t)2*NB*4);
    short*     WoT     = (short*)    alloc((size_t)64*64*2);
    short*     Wt      = (short*)    alloc((size_t)3*64*64*2);

    if (off > ws_size) return;  // clean bail instead of OOB fault

    // Aliases (stream order makes each safe):
    short* WQKV = (short*)e16A;          // attn reads; overwritten by finalize_conv
    _Float16* qc = (_Float16*)prof;      // written after finalize_conv read prof

    hipMemsetAsync(deg_p, 0, (size_t)3*NE*4, stream);   // deg_p+cntC+cntF
    hipMemsetAsync(prof,  0, (size_t)NE*64*4, stream);
    hipMemsetAsync(acc,   0, (size_t)3*B*128*4, stream);
    hipMemsetAsync(d_out, 0, (size_t)out_size*4, stream);

    // --- CSR build (parallel scan) + WoT/Wt ------------------------------
    misc_kernel<<<CDIV(EP, 256), 256, 0, stream>>>(pur_src, pur_dst, cntC, cntF, EP,
        profile_dst, deg_p, NR, Wo, WoT, Wq, Wk, Wv, Wt);
    scan_reduce_kernel<<<2*NB, 256, 0, stream>>>(cntC, cntF, part, NE, NB);
    scan_part_kernel<<<1, 1024, 0, stream>>>(part, NB);
    scan_final_kernel<<<2*NB, 256, 0, stream>>>(cntC, cntF, part,
        offC, curC, offF, curF, NE, NB);
    fill_csr_kernel<<<CDIV(EP, 256), 256, 0, stream>>>(pur_src, pur_dst, pur_qid,
        curC, curF, cmb, fsrc, fqid, EP);

    // --- attention (MFMA QKV table + gather MFMA + MFMA epilogue) ---------
    prep_wqkv_mfma<<<CDIV(CDIV(NW,16), 16), 256, 0, stream>>>(word_emb, Wt,
        bq, bk, bv, WQKV, NW);
    attn_mfma<16,1><<<CDIV(NR, 16), 256, 0, stream>>>(WQKV, review_words,
        WoT, bo, NR, prof, profile_dst);
    attn_mfma<8,2><<<CDIV(NQ, 32), 256, 0, stream>>>(WQKV, query_words_graph,
        WoT, bo, NQ, q_h16, nullptr);
    attn_mfma<8,0><<<CDIV(B, 32), 256, 0, stream>>>(WQKV, query_words,
        WoT, bo, B, qb, nullptr);

    // --- e0 fp16 + inv; iteration-invariant query term --------------------
    finalize_conv_kernel<<<CDIV(NE*32, 256), 256, 0, stream>>>(entity_emb, prof,
        e16A, inv, deg_p, cntC, NE);
    qconst_kernel<<<CDIV(NE*8, 256), 256, 0, stream>>>(q_h16, inv,
        offF, curF, fsrc, fqid, qc, NE);
    gather_acc_kernel<<<CDIV(3*B*16, 256), 256, 0, stream>>>(e16A, users, items, negs, acc, B);

    // --- K=3 propagation, ping-pong fp16, merged edge list ----------------
    _Float16* cur = e16A; _Float16* nxt = e16B;
    for (int k = 0; k < 3; ++k) {
        prop_kernel<<<CDIV(NE*16, 256), 256, 0, stream>>>(cur, qc, inv,
            offC, curC, cmb, nxt, NE);
        gather_acc_kernel<<<CDIV(3*B*16, 256), 256, 0, stream>>>(nxt, users, items, negs, acc, B);
        _Float16* tmp = cur; cur = nxt; nxt = tmp;
    }

    loss_kernel<<<B, 128, 0, stream>>>(acc, qb, (float*)d_out, B, 1.0f / (float)B);
}

// Round 11
// 663.989 us; speedup vs baseline: 10.6577x; 1.0265x over previous
//
#include <hip/hip_runtime.h>
#include <cstdint>

#define CDIV(a,b) (((a)+(b)-1)/(b))

typedef __attribute__((ext_vector_type(8))) short bf16x8;     // 8 bf16 = 4 VGPRs
typedef __attribute__((ext_vector_type(4))) float f32x4;      // MFMA accumulator
typedef __attribute__((ext_vector_type(8))) float f32x8;
typedef __attribute__((ext_vector_type(4))) _Float16 half4;
typedef __attribute__((ext_vector_type(8))) _Float16 half8;   // 16B fp16 vector
typedef __attribute__((ext_vector_type(2))) _Float16 h16x2;   // packed fp16 pair

__device__ __forceinline__ float bf2f(short s) {
    return __builtin_bit_cast(float, ((unsigned)(unsigned short)s) << 16);
}
__device__ __forceinline__ short rtne(float f) {
    const unsigned u = __builtin_bit_cast(unsigned, f);
    return (short)((u + 0x7fffu + ((u >> 16) & 1u)) >> 16);
}
__device__ __forceinline__ unsigned pack2r(float lo, float hi) {
    return (unsigned)(unsigned short)rtne(lo) | ((unsigned)(unsigned short)rtne(hi) << 16);
}

// ---------------------------------------------------------------------------
// MFMA prep: WQKV[w][p*64+n] = x_w @ W_p + b_p  (bf16), x_0 = 0 (padding_idx).
// ---------------------------------------------------------------------------
__global__ __launch_bounds__(256) void prep_wqkv_mfma(
    const float* __restrict__ we, const short* __restrict__ Wt,
    const float* __restrict__ bq, const float* __restrict__ bk,
    const float* __restrict__ bv, short* __restrict__ WQKV, int NW)
{
    const int wave = threadIdx.x >> 6;
    const int lane = threadIdx.x & 63;
    const int quad = lane >> 4;
    const int lm   = lane & 15;
    const int ntiles = CDIV(NW, 16);

    bf16x8 bfr[3][4][2];
    #pragma unroll
    for (int p = 0; p < 3; ++p)
        #pragma unroll
        for (int nt = 0; nt < 4; ++nt)
            #pragma unroll
            for (int kh = 0; kh < 2; ++kh)
                bfr[p][nt][kh] = *(const bf16x8*)(Wt + ((p*64 + nt*16 + lm)*64) + kh*32 + quad*8);
    float bias[3][4];
    #pragma unroll
    for (int nt = 0; nt < 4; ++nt) {
        bias[0][nt] = bq[nt*16 + lm];
        bias[1][nt] = bk[nt*16 + lm];
        bias[2][nt] = bv[nt*16 + lm];
    }

    #pragma unroll
    for (int t = 0; t < 4; ++t) {
        const int tile = (blockIdx.x*4 + wave)*4 + t;
        if (tile >= ntiles) return;
        const int wb = tile*16;
        int w = wb + lm;
        if (w >= NW) w = NW - 1;
        const float* xr = we + (size_t)w*64;
        union { unsigned u[4]; bf16x8 v; } a0, a1;
        const float4 f0 = *(const float4*)(xr + quad*8);
        const float4 f1 = *(const float4*)(xr + quad*8 + 4);
        const float4 f2 = *(const float4*)(xr + 32 + quad*8);
        const float4 f3 = *(const float4*)(xr + 32 + quad*8 + 4);
        a0.u[0] = pack2r(f0.x, f0.y); a0.u[1] = pack2r(f0.z, f0.w);
        a0.u[2] = pack2r(f1.x, f1.y); a0.u[3] = pack2r(f1.z, f1.w);
        a1.u[0] = pack2r(f2.x, f2.y); a1.u[1] = pack2r(f2.z, f2.w);
        a1.u[2] = pack2r(f3.x, f3.y); a1.u[3] = pack2r(f3.z, f3.w);
        if (w == 0) {
            a0.u[0]=0u; a0.u[1]=0u; a0.u[2]=0u; a0.u[3]=0u;
            a1.u[0]=0u; a1.u[1]=0u; a1.u[2]=0u; a1.u[3]=0u;
        }
        #pragma unroll
        for (int p = 0; p < 3; ++p) {
            #pragma unroll
            for (int nt = 0; nt < 4; ++nt) {
                f32x4 c = {bias[p][nt], bias[p][nt], bias[p][nt], bias[p][nt]};
                c = __builtin_amdgcn_mfma_f32_16x16x32_bf16(a0.v, bfr[p][nt][0], c, 0, 0, 0);
                c = __builtin_amdgcn_mfma_f32_16x16x32_bf16(a1.v, bfr[p][nt][1], c, 0, 0, 0);
                #pragma unroll
                for (int r = 0; r < 4; ++r) {
                    const int w2 = wb + quad*4 + r;
                    if (w2 < NW)
                        WQKV[(size_t)w2*192 + p*64 + nt*16 + lm] = rtne(c[r]);
                }
            }
        }
    }
}

// ---------------------------------------------------------------------------
// Gather MFMA attention (unchanged from round 9).
// ---------------------------------------------------------------------------
template<int L, int MODE>
__global__ __launch_bounds__(256) void attn_mfma(
    const short* __restrict__ WQKV, const int* __restrict__ words,
    const short* __restrict__ WoT, const float* __restrict__ bo,
    int N, void* __restrict__ outp, const int* __restrict__ sidx)
{
    constexpr int SPT = 16 / L;
    constexpr int SB  = 16 * SPT;
    __shared__ short v_s[4][16*72];
    __shared__ float pbar_s[4][64];
    __shared__ float mo_s[SB][68];

    const int wave = threadIdx.x >> 6;
    const int lane = threadIdx.x & 63;
    const int quad = lane >> 4;
    const int lm   = lane & 15;
    const int tok_total = N * L;
    const float invL = 1.0f / (float)L;

    int wid[4];
    #pragma unroll
    for (int t = 0; t < 4; ++t) {
        int tg = (blockIdx.x*16 + wave*4 + t)*16 + lm;
        if (tg >= tok_total) tg = tok_total - 1;
        wid[t] = words[tg];
    }

    #pragma unroll
    for (int ti = 0; ti < 4; ++ti) {
        const short* row = WQKV + (size_t)wid[ti] * 192;

        const int4 v0 = *(const int4*)(row + 128 + quad*16);
        const int4 v1 = *(const int4*)(row + 128 + quad*16 + 8);
        bf16x8 qf[4], kf[4];
        #pragma unroll
        for (int h = 0; h < 4; ++h) {
            if (quad < 2) {
                kf[h] = *(const bf16x8*)(row + 64 + h*16 + quad*8);
                qf[h] = *(const bf16x8*)(row +      h*16 + quad*8);
            } else {
                kf[h] = (bf16x8){0,0,0,0,0,0,0,0};
                qf[h] = (bf16x8){0,0,0,0,0,0,0,0};
            }
        }
        *(int4*)&v_s[wave][lm*72 + quad*16]     = v0;
        *(int4*)&v_s[wave][lm*72 + quad*16 + 8] = v1;

        const bool mvalid = (SPT == 1) ? true : ((quad >> 1) == ((lm >> 3) & 1));

        #pragma unroll
        for (int h = 0; h < 4; ++h) {
            const f32x4 s4 = __builtin_amdgcn_mfma_f32_16x16x32_bf16(
                kf[h], qf[h], (f32x4){0.f,0.f,0.f,0.f}, 0, 0, 0);
            float sv0 = s4[0]*0.25f, sv1 = s4[1]*0.25f,
                  sv2 = s4[2]*0.25f, sv3 = s4[3]*0.25f;
            if (!mvalid) { sv0 = sv1 = sv2 = sv3 = -3.0e38f; }
            float p0 = __expf(sv0), p1 = __expf(sv1),
                  p2 = __expf(sv2), p3 = __expf(sv3);
            float sm = p0+p1+p2+p3;
            sm += __shfl_xor(sm, 16, 64);
            sm += __shfl_xor(sm, 32, 64);
            const float rinv = __builtin_amdgcn_rcpf(sm);
            p0 *= rinv; p1 *= rinv; p2 *= rinv; p3 *= rinv;
            h16x2 a01 = {(_Float16)p0, (_Float16)p1};
            h16x2 a23 = {(_Float16)p2, (_Float16)p3};
            #pragma unroll
            for (int d = 1; d < 16; d <<= 1) {
                a01 += __builtin_bit_cast(h16x2, __shfl_xor(__builtin_bit_cast(int, a01), d, 64));
                a23 += __builtin_bit_cast(h16x2, __shfl_xor(__builtin_bit_cast(int, a23), d, 64));
            }
            if (lm == 0) {
                pbar_s[wave][h*16 + quad*4 + 0] = (float)a01.x * invL;
                pbar_s[wave][h*16 + quad*4 + 1] = (float)a01.y * invL;
                pbar_s[wave][h*16 + quad*4 + 2] = (float)a23.x * invL;
                pbar_s[wave][h*16 + quad*4 + 3] = (float)a23.y * invL;
            }
        }

        #pragma unroll
        for (int s = 0; s < SPT; ++s) {
            float o = 0.f;
            #pragma unroll
            for (int j2 = 0; j2 < L; ++j2) {
                const int m = s*L + j2;
                o += pbar_s[wave][quad*16 + m] * bf2f(v_s[wave][m*72 + lane]);
            }
            mo_s[(wave*4+ti)*SPT + s][lane] = o;
        }
    }
    __syncthreads();

    const int col = wave*16 + lm;
    const short* bT = WoT + col*64;
    const bf16x8 b0 = *(const bf16x8*)(bT + quad*8);
    const bf16x8 b1 = *(const bf16x8*)(bT + 32 + quad*8);
    const float boc = bo[col];
    #pragma unroll
    for (int rt = 0; rt < SPT; ++rt) {
        const float* ar = mo_s[rt*16 + lm];
        const float4 fA0 = *(const float4*)(ar + quad*8);
        const float4 fA1 = *(const float4*)(ar + quad*8 + 4);
        const float4 fA2 = *(const float4*)(ar + 32 + quad*8);
        const float4 fA3 = *(const float4*)(ar + 32 + quad*8 + 4);
        union { unsigned u[4]; bf16x8 v; } a0, a1;
        a0.u[0] = pack2r(fA0.x, fA0.y); a0.u[1] = pack2r(fA0.z, fA0.w);
        a0.u[2] = pack2r(fA1.x, fA1.y); a0.u[3] = pack2r(fA1.z, fA1.w);
        a1.u[0] = pack2r(fA2.x, fA2.y); a1.u[1] = pack2r(fA2.z, fA2.w);
        a1.u[2] = pack2r(fA3.x, fA3.y); a1.u[3] = pack2r(fA3.z, fA3.w);
        f32x4 c = {boc, boc, boc, boc};
        c = __builtin_amdgcn_mfma_f32_16x16x32_bf16(a0.v, b0, c, 0, 0, 0);
        c = __builtin_amdgcn_mfma_f32_16x16x32_bf16(a1.v, b1, c, 0, 0, 0);
        #pragma unroll
        for (int r = 0; r < 4; ++r) {
            const int seq = blockIdx.x*SB + rt*16 + quad*4 + r;
            if (seq < N) {
                if (MODE == 0)
                    ((float*)outp)[(size_t)seq*64 + col] = c[r];
                else if (MODE == 1)
                    atomicAdd(&((float*)outp)[(size_t)sidx[seq]*64 + col], c[r]);
                else
                    ((_Float16*)outp)[(size_t)seq*64 + col] = (_Float16)c[r];
            }
        }
    }
}

// Fused: cntC/cntF counts (t<EP), profile counts (t<NR), WoT+Wt builds
__global__ __launch_bounds__(256) void misc_kernel(
    const int* __restrict__ src, const int* __restrict__ dst,
    unsigned* __restrict__ cntC, unsigned* __restrict__ cntF, int EP,
    const int* __restrict__ pdst, unsigned* __restrict__ deg_p, int NR,
    const float* __restrict__ Wo, short* __restrict__ WoT,
    const float* __restrict__ Wq, const float* __restrict__ Wk,
    const float* __restrict__ Wv, short* __restrict__ Wt)
{
    const int t = blockIdx.x*256 + threadIdx.x;
    if (t < EP) {
        const int s = src[t], d = dst[t];
        atomicAdd(&cntC[d], 1u); atomicAdd(&cntC[s], 1u);
        atomicAdd(&cntF[d], 1u);
    }
    if (t < NR) atomicAdd(&deg_p[pdst[t]], 1u);
    if (t < 4096) {
        const int j = t >> 6, k = t & 63;
        WoT[j*64 + k] = rtne(Wo[k*64 + j]);
    }
    if (t < 3*4096) {
        const int p = t >> 12, n = (t >> 6) & 63, k = t & 63;
        const float* W = (p==0) ? Wq : (p==1) ? Wk : Wv;
        Wt[t] = rtne(W[k*64 + n]);
    }
}

// --- 3-phase parallel exclusive scan of cntC and cntF ----------------------
#define SCAN_CHUNK 2048

__global__ __launch_bounds__(256) void scan_reduce_kernel(
    const unsigned* __restrict__ cntA, const unsigned* __restrict__ cntB,
    unsigned* __restrict__ part, int n, int NB)
{
    const int arr = blockIdx.x / NB, b = blockIdx.x % NB;
    const unsigned* cnt = arr ? cntB : cntA;
    const int base = b * SCAN_CHUNK;
    unsigned s = 0;
    #pragma unroll
    for (int i = 0; i < 8; ++i) {
        const int idx = base + i*256 + threadIdx.x;
        if (idx < n) s += cnt[idx];
    }
    #pragma unroll
    for (int off = 1; off < 64; off <<= 1) s += __shfl_xor(s, off, 64);
    __shared__ unsigned wsum[4];
    if ((threadIdx.x & 63) == 0) wsum[threadIdx.x >> 6] = s;
    __syncthreads();
    if (threadIdx.x == 0) part[arr*NB + b] = wsum[0]+wsum[1]+wsum[2]+wsum[3];
}

__global__ __launch_bounds__(1024) void scan_part_kernel(
    unsigned* __restrict__ part, int NB)
{
    __shared__ unsigned a[1024], b2[1024];
    const int t = threadIdx.x;
    a[t]  = (t < NB) ? part[t]      : 0u;
    b2[t] = (t < NB) ? part[NB + t] : 0u;
    __syncthreads();
    for (int d = 1; d < 1024; d <<= 1) {
        const unsigned xa = (t >= d) ? a[t-d] : 0u;
        const unsigned xb = (t >= d) ? b2[t-d] : 0u;
        __syncthreads();
        a[t] += xa; b2[t] += xb;
        __syncthreads();
    }
    if (t < NB) {
        part[t]      = (t > 0) ? a[t-1]  : 0u;
        part[NB + t] = (t > 0) ? b2[t-1] : 0u;
    }
}

__global__ __launch_bounds__(256) void scan_final_kernel(
    const unsigned* __restrict__ cntA, const unsigned* __restrict__ cntB,
    const unsigned* __restrict__ part,
    int* __restrict__ offA, int* __restrict__ curA,
    int* __restrict__ offB, int* __restrict__ curB, int n, int NB)
{
    const int arr = blockIdx.x / NB, b = blockIdx.x % NB;
    const unsigned* cnt = arr ? cntB : cntA;
    int* off = arr ? offB : offA;
    int* cur = arr ? curB : curA;
    __shared__ unsigned v[SCAN_CHUNK];
    __shared__ unsigned tsum[256];
    const int base = b * SCAN_CHUNK;
    const int t = threadIdx.x;
    #pragma unroll
    for (int i = 0; i < 8; ++i) {
        const int idx = base + i*256 + t;
        v[i*256 + t] = (idx < n) ? cnt[idx] : 0u;
    }
    __syncthreads();
    unsigned s = 0;
    #pragma unroll
    for (int i = 0; i < 8; ++i) s += v[t*8 + i];
    tsum[t] = s;
    __syncthreads();
    for (int d = 1; d < 256; d <<= 1) {
        const unsigned x = (t >= d) ? tsum[t-d] : 0u;
        __syncthreads();
        tsum[t] += x;
        __syncthreads();
    }
    unsigned run = ((t > 0) ? tsum[t-1] : 0u) + part[arr*NB + b];
    #pragma unroll
    for (int i = 0; i < 8; ++i) {
        const int idx = base + t*8 + i;
        if (idx < n) { off[idx] = (int)run; cur[idx] = (int)run; run += v[t*8+i]; }
    }
}

__global__ __launch_bounds__(256) void fill_csr_kernel(
    const int* __restrict__ src, const int* __restrict__ dst,
    const int* __restrict__ qid,
    int* __restrict__ curC, int* __restrict__ curF,
    int* __restrict__ cmb, int* __restrict__ fsrc, int* __restrict__ fqid,
    int EP)
{
    const int t = blockIdx.x*256 + threadIdx.x;
    if (t >= EP) return;
    const int s = src[t], d = dst[t];
    cmb[atomicAdd(&curC[d], 1)] = s;
    cmb[atomicAdd(&curC[s], 1)] = d | (int)0x80000000;
    const int pF = atomicAdd(&curF[d], 1);
    fsrc[pF] = s; fqid[pF] = qid[t];
}

// e16[v] = [entity_emb[v] | prof[v]/max(deg_p,1)] fp16; inv = 1/sqrt(cntC)
__global__ __launch_bounds__(256) void finalize_conv_kernel(
    const float* __restrict__ emb, const float* __restrict__ prof,
    _Float16* __restrict__ e16, float* __restrict__ inv,
    const unsigned* __restrict__ deg_p, const unsigned* __restrict__ cntC, int NE)
{
    const int t = blockIdx.x*256 + threadIdx.x;
    const int v = t >> 5;
    if (v >= NE) return;
    const int c = (t & 31) * 4;
    float4 ev;
    if (c < 64) {
        ev = *(const float4*)&emb[(size_t)v*64 + c];
    } else {
        ev = *(const float4*)&prof[(size_t)v*64 + (c - 64)];
        const unsigned dp = deg_p[v];
        const float r = 1.0f / (float)(dp > 1u ? dp : 1u);
        ev.x *= r; ev.y *= r; ev.z *= r; ev.w *= r;
    }
    f32x4 f = {ev.x, ev.y, ev.z, ev.w};
    *(half4*)&e16[(size_t)v*128 + c] = __builtin_convertvector(f, half4);
    if (c == 0) {
        const unsigned di = cntC[v];
        inv[v] = 1.0f / sqrtf((float)(di > 1u ? di : 1u));
    }
}

// --- backward-reachability frontier: S (lev 3) ⊆ S2 (lev>=2) ⊆ S1 (lev>=1) --
__global__ __launch_bounds__(256) void mark_kernel(
    const int* __restrict__ users, const int* __restrict__ items,
    const int* __restrict__ negs, int B, unsigned* __restrict__ lev,
    int* __restrict__ listS, int* __restrict__ list2, int* __restrict__ list1,
    int* __restrict__ nS, int* __restrict__ n2, int* __restrict__ n1)
{
    const int t = blockIdx.x*256 + threadIdx.x;
    if (t >= 3*B) return;
    const int which = t / B, b = t - which*B;
    const int v = (which == 0) ? users[b] : (which == 1) ? items[b] : negs[b];
    const unsigned old = atomicMax(&lev[v], 3u);
    if (old < 3u) {
        listS[atomicAdd(nS, 1)] = v;
        list2[atomicAdd(n2, 1)] = v;
        list1[atomicAdd(n1, 1)] = v;
    }
}

// expand slist's neighborhoods to level targ; append new verts to dl1 (+dl2)
__global__ __launch_bounds__(256) void expand_kernel(
    unsigned targ, const int* __restrict__ slist, const int* __restrict__ pn,
    const int* __restrict__ offC, const int* __restrict__ endC,
    const int* __restrict__ cmb, unsigned* __restrict__ lev,
    int* __restrict__ dl1, int* __restrict__ dn1,
    int* __restrict__ dl2, int* __restrict__ dn2)
{
    const int n = *pn;
    const int stride = gridDim.x * 256;
    for (int t = blockIdx.x*256 + threadIdx.x; t < n; t += stride) {
        const int v = slist[t];
        const int b0 = offC[v], e0 = endC[v];
        for (int i = b0; i < e0; ++i) {
            const int u = cmb[i] & 0x7fffffff;
            const unsigned old = atomicMax(&lev[u], targ);
            if (old < targ) {
                dl1[atomicAdd(dn1, 1)] = u;
                if (dl2) dl2[atomicAdd(dn2, 1)] = u;
            }
        }
    }
}

// qc[v] = sum_{i in F(v)} q_h16[qid_i] * inv[src_i], v from list1 only
__global__ __launch_bounds__(256) void qconst_list_kernel(
    const _Float16* __restrict__ q_h16, const float* __restrict__ inv,
    const int* __restrict__ offF, const int* __restrict__ endF,
    const int* __restrict__ fsrc, const int* __restrict__ fqid,
    const int* __restrict__ list, const int* __restrict__ pn,
    _Float16* __restrict__ qc)
{
    const int n = *pn;
    const int stride = gridDim.x * 256;
    for (int t = blockIdx.x*256 + threadIdx.x; (t >> 3) < n; t += stride) {
        const int v = list[t >> 3];
        const int c = (t & 7) * 8;
        f32x8 a = {0.f,0.f,0.f,0.f,0.f,0.f,0.f,0.f};
        const int bF = offF[v], eF = endF[v];
        for (int i = bF; i < eF; ++i) {
            const float invs = inv[fsrc[i]];
            const half8 qh = *(const half8*)&q_h16[(size_t)fqid[i]*64 + c];
            a += __builtin_convertvector(qh, f32x8) * invs;
        }
        *(half8*)&qc[(size_t)v*64 + c] = __builtin_convertvector(a, half8);
    }
}

// acc[r] += e16[sel[r]]; 16 lanes x half8 per row
__global__ __launch_bounds__(256) void gather_acc_kernel(
    const _Float16* __restrict__ e16, const int* __restrict__ users,
    const int* __restrict__ items, const int* __restrict__ negs,
    float* __restrict__ acc, int B)
{
    const int t = blockIdx.x*256 + threadIdx.x;
    const int r = t >> 4;
    if (r >= 3*B) return;
    const int c = (t & 15) * 8;
    const int which = r / B, b = r - which*B;
    const int idx = (which == 0) ? users[b] : (which == 1) ? items[b] : negs[b];
    const half8 ev = *(const half8*)&e16[(size_t)idx*128 + c];
    const f32x8 f = __builtin_convertvector(ev, f32x8);
    f32x8 a = *(const f32x8*)&acc[(size_t)r*128 + c];
    a += f;
    *(f32x8*)&acc[(size_t)r*128 + c] = a;
}

// Propagate+combine over the merged list, restricted to vertices in `list`.
__global__ __launch_bounds__(256) void prop_list_kernel(
    const _Float16* __restrict__ e_cur, const _Float16* __restrict__ qc,
    const float* __restrict__ inv,
    const int* __restrict__ offC, const int* __restrict__ endC,
    const int* __restrict__ cmb,
    const int* __restrict__ list, const int* __restrict__ pn,
    _Float16* __restrict__ e_nxt)
{
    const int n = *pn;
    const int stride = gridDim.x * 256;
    for (int t = blockIdx.x*256 + threadIdx.x; (t >> 4) < n; t += stride) {
        const int v = list[t >> 4];
        const int c = (t & 15) * 8;
        f32x8 a = {0.f,0.f,0.f,0.f,0.f,0.f,0.f,0.f};
        if (c >= 64) {
            const half8 q = *(const half8*)&qc[(size_t)v*64 + (c - 64)];
            a = __builtin_convertvector(q, f32x8);
        }
        const int b0 = offC[v], e0 = endC[v];
        int un = (b0 < e0) ? cmb[b0] : 0;
        for (int i = b0; i < e0; ++i) {
            const int uc = un;
            if (i + 1 < e0) un = cmb[i + 1];
            const int u = uc & 0x7fffffff;
            const half8 es = *(const half8*)&e_cur[(size_t)u*128 + c];
            const float w = (uc < 0) ? inv[u] : 1.0f;
            a += __builtin_convertvector(es, f32x8) * w;
        }
        a *= inv[v];
        *(half8*)&e_nxt[(size_t)v*128 + c] = __builtin_convertvector(a, half8);
    }
}

// Final hop fused into acc: acc[r] += e3[sel[r]] computed on the fly from e2.
__global__ __launch_bounds__(256) void prop_batch_kernel(
    const _Float16* __restrict__ e_cur, const _Float16* __restrict__ qc,
    const float* __restrict__ inv,
    const int* __restrict__ offC, const int* __restrict__ endC,
    const int* __restrict__ cmb,
    const int* __restrict__ users, const int* __restrict__ items,
    const int* __restrict__ negs, float* __restrict__ acc, int B)
{
    const int t = blockIdx.x*256 + threadIdx.x;
    const int r = t >> 4;
    if (r >= 3*B) return;
    const int c = (t & 15) * 8;
    const int which = r / B, b = r - which*B;
    const int v = (which == 0) ? users[b] : (which == 1) ? items[b] : negs[b];
    f32x8 a = {0.f,0.f,0.f,0.f,0.f,0.f,0.f,0.f};
    if (c >= 64) {
        const half8 q = *(const half8*)&qc[(size_t)v*64 + (c - 64)];
        a = __builtin_convertvector(q, f32x8);
    }
    const int b0 = offC[v], e0 = endC[v];
    int un = (b0 < e0) ? cmb[b0] : 0;
    for (int i = b0; i < e0; ++i) {
        const int uc = un;
        if (i + 1 < e0) un = cmb[i + 1];
        const int u = uc & 0x7fffffff;
        const half8 es = *(const half8*)&e_cur[(size_t)u*128 + c];
        const float w = (uc < 0) ? inv[u] : 1.0f;
        a += __builtin_convertvector(es, f32x8) * w;
    }
    a *= inv[v];
    f32x8 ac = *(const f32x8*)&acc[(size_t)r*128 + c];
    ac += a;
    *(f32x8*)&acc[(size_t)r*128 + c] = ac;
}

__global__ __launch_bounds__(128) void loss_kernel(
    const float* __restrict__ acc, const float* __restrict__ qb,
    float* __restrict__ out, int B, float invB)
{
    const int b = blockIdx.x, d = threadIdx.x;
    const float u = acc[(size_t)b*128 + d] * 0.25f;
    const float p = u + (d >= 64 ? qb[(size_t)b*64 + (d - 64)] : 0.f);
    const float ei = acc[(size_t)(B + b)*128 + d];
    const float en = acc[(size_t)(2*B + b)*128 + d];
    float x = p * (ei - en) * 0.25f;
    #pragma unroll
    for (int off = 1; off < 64; off <<= 1) x += __shfl_xor(x, off, 64);
    __shared__ float wred[2];
    if ((threadIdx.x & 63) == 0) wred[threadIdx.x >> 6] = x;
    __syncthreads();
    if (threadIdx.x == 0) {
        const float xx = wred[0] + wred[1];
        const float ls = fminf(xx, 0.f) - log1pf(expf(-fabsf(xx)));
        atomicAdd(out, -ls * invB);
    }
}

extern "C" void kernel_launch(void* const* d_in, const int* in_sizes, int n_in,
                              void* d_out, int out_size, void* d_ws, size_t ws_size,
                              hipStream_t stream)
{
    const float* word_emb        = (const float*)d_in[0];
    const float* entity_emb      = (const float*)d_in[1];
    const float* Wq = (const float*)d_in[2];  const float* bq = (const float*)d_in[3];
    const float* Wk = (const float*)d_in[4];  const float* bk = (const float*)d_in[5];
    const float* Wv = (const float*)d_in[6];  const float* bv = (const float*)d_in[7];
    const float* Wo = (const float*)d_in[8];  const float* bo = (const float*)d_in[9];
    const int* review_words      = (const int*)d_in[10];
    const int* query_words_graph = (const int*)d_in[11];
    const int* profile_dst       = (const int*)d_in[12];
    const int* pur_src           = (const int*)d_in[13];
    const int* pur_dst           = (const int*)d_in[14];
    const int* pur_qid           = (const int*)d_in[15];
    const int* users             = (const int*)d_in[16];
    const int* items             = (const int*)d_in[17];
    const int* negs              = (const int*)d_in[18];
    const int* query_words       = (const int*)d_in[19];

    const int NW = in_sizes[0]  / 64;
    const int NE = in_sizes[1]  / 64;
    const int NR = in_sizes[10] / 16;
    const int NQ = in_sizes[11] / 8;
    const int EP = in_sizes[13];
    const int B  = in_sizes[16];
    const int NB = CDIV(NE, SCAN_CHUNK);

    char* ws = (char*)d_ws;
    size_t off = 0;
    auto alloc = [&](size_t bytes) -> char* {
        char* q = ws + off; off += (bytes + 255) & ~(size_t)255; return q;
    };
    float*     prof    = (float*)    alloc((size_t)NE*64*4);   // review scatter
    _Float16*  e16A    = (_Float16*) alloc((size_t)NE*128*2);  // fp16 ping
    _Float16*  e16B    = (_Float16*) alloc((size_t)NE*128*2);  // fp16 pong
    _Float16*  q_h16   = (_Float16*) alloc((size_t)NQ*64*2);
    float*     qb      = (float*)    alloc((size_t)B*64*4);
    float*     acc     = (float*)    alloc((size_t)3*B*128*4);
    // deg_p/cntC/cntF/lev contiguous -> single memset (4*NE*4 + 256 for cnts)
    unsigned*  deg_p   = (unsigned*) alloc((size_t)NE*4);
    unsigned*  cntC    = (unsigned*) alloc((size_t)NE*4);
    unsigned*  cntF    = (unsigned*) alloc((size_t)NE*4);
    unsigned*  lev     = (unsigned*) alloc((size_t)NE*4);
    int*       fcnt    = (int*)      alloc(256);               // nS, n2, n1
    int*       offC    = (int*)      alloc((size_t)NE*4);
    int*       offF    = (int*)      alloc((size_t)NE*4);
    int*       curC    = (int*)      alloc((size_t)NE*4);
    int*       curF    = (int*)      alloc((size_t)NE*4);
    int*       cmb     = (int*)      alloc((size_t)2*EP*4);
    int*       fsrc    = (int*)      alloc((size_t)EP*4);
    int*       fqid    = (int*)      alloc((size_t)EP*4);
    int*       listS   = (int*)      alloc((size_t)3*B*4);
    int*       list2   = (int*)      alloc((size_t)NE*4);
    int*       list1   = (int*)      alloc((size_t)NE*4);
    float*     inv     = (float*)    alloc((size_t)NE*4);
    unsigned*  part    = (unsigned*) alloc((size_t)2*NB*4);
    short*     WoT     = (short*)    alloc((size_t)64*64*2);
    short*     Wt      = (short*)    alloc((size_t)3*64*64*2);

    if (off > ws_size) return;  // clean bail instead of OOB fault

    // Aliases (stream order makes each safe):
    short* WQKV = (short*)e16A;          // attn reads; overwritten by finalize_conv
    _Float16* qc = (_Float16*)prof;      // written after finalize_conv read prof
    int* nS = fcnt; int* n2 = fcnt + 1; int* n1 = fcnt + 2;

    hipMemsetAsync(deg_p, 0, (size_t)4*NE*4 + 256, stream); // deg_p..lev + fcnt
    hipMemsetAsync(prof,  0, (size_t)NE*64*4, stream);
    hipMemsetAsync(acc,   0, (size_t)3*B*128*4, stream);
    hipMemsetAsync(d_out, 0, (size_t)out_size*4, stream);

    // --- CSR build (parallel scan) + WoT/Wt ------------------------------
    misc_kernel<<<CDIV(EP, 256), 256, 0, stream>>>(pur_src, pur_dst, cntC, cntF, EP,
        profile_dst, deg_p, NR, Wo, WoT, Wq, Wk, Wv, Wt);
    scan_reduce_kernel<<<2*NB, 256, 0, stream>>>(cntC, cntF, part, NE, NB);
    scan_part_kernel<<<1, 1024, 0, stream>>>(part, NB);
    scan_final_kernel<<<2*NB, 256, 0, stream>>>(cntC, cntF, part,
        offC, curC, offF, curF, NE, NB);
    fill_csr_kernel<<<CDIV(EP, 256), 256, 0, stream>>>(pur_src, pur_dst, pur_qid,
        curC, curF, cmb, fsrc, fqid, EP);

    // --- backward frontier: S -> S2 -> S1 ---------------------------------
    mark_kernel<<<CDIV(3*B, 256), 256, 0, stream>>>(users, items, negs, B,
        lev, listS, list2, list1, nS, n2, n1);
    expand_kernel<<<64, 256, 0, stream>>>(2u, listS, nS, offC, curC, cmb, lev,
        list2, n2, list1, n1);
    expand_kernel<<<256, 256, 0, stream>>>(1u, list2, n2, offC, curC, cmb, lev,
        list1, n1, nullptr, nullptr);

    // --- attention (MFMA QKV table + gather MFMA + MFMA epilogue) ---------
    prep_wqkv_mfma<<<CDIV(CDIV(NW,16), 16), 256, 0, stream>>>(word_emb, Wt,
        bq, bk, bv, WQKV, NW);
    attn_mfma<16,1><<<CDIV(NR, 16), 256, 0, stream>>>(WQKV, review_words,
        WoT, bo, NR, prof, profile_dst);
    attn_mfma<8,2><<<CDIV(NQ, 32), 256, 0, stream>>>(WQKV, query_words_graph,
        WoT, bo, NQ, q_h16, nullptr);
    attn_mfma<8,0><<<CDIV(B, 32), 256, 0, stream>>>(WQKV, query_words,
        WoT, bo, B, qb, nullptr);

    // --- e0 fp16 + inv; query term only where needed (S1) -----------------
    finalize_conv_kernel<<<CDIV(NE*32, 256), 256, 0, stream>>>(entity_emb, prof,
        e16A, inv, deg_p, cntC, NE);
    qconst_list_kernel<<<512, 256, 0, stream>>>(q_h16, inv,
        offF, curF, fsrc, fqid, list1, n1, qc);
    gather_acc_kernel<<<CDIV(3*B*16, 256), 256, 0, stream>>>(e16A, users, items, negs, acc, B);

    // --- K=3 propagation, frontier-restricted -----------------------------
    prop_list_kernel<<<2048, 256, 0, stream>>>(e16A, qc, inv,
        offC, curC, cmb, list1, n1, e16B);                       // e1 at S1
    gather_acc_kernel<<<CDIV(3*B*16, 256), 256, 0, stream>>>(e16B, users, items, negs, acc, B);
    prop_list_kernel<<<512, 256, 0, stream>>>(e16B, qc, inv,
        offC, curC, cmb, list2, n2, e16A);                       // e2 at S2
    gather_acc_kernel<<<CDIV(3*B*16, 256), 256, 0, stream>>>(e16A, users, items, negs, acc, B);
    prop_batch_kernel<<<CDIV(3*B*16, 256), 256, 0, stream>>>(e16A, qc, inv,
        offC, curC, cmb, users, items, negs, acc, B);            // e3 at S -> acc

    loss_kernel<<<B, 128, 0, stream>>>(acc, qb, (float*)d_out, B, 1.0f / (float)B);
}